// Round 1
// 1009.515 us; speedup vs baseline: 1.0319x; 1.0319x over previous
//
#include <hip/hip_runtime.h>
#include <stdint.h>

#define DIMM 1024
#define NSEQ 1024
#define BB 2
#define HEADSN 16
#define MLPD 4096
#define DEPTHN 4
#define MROWS (BB*NSEQ)  // 2048
#define VSTR 10240       // canonical per-layer vec stride (elements)

typedef __bf16 bf16x8 __attribute__((ext_vector_type(8)));
typedef float f32x4 __attribute__((ext_vector_type(4)));

__device__ __forceinline__ float bf2f(unsigned short u) {
    union { uint32_t i; float f; } x; x.i = ((uint32_t)u) << 16; return x.f;
}
__device__ __forceinline__ unsigned short f2bf(float f) {
    union { uint32_t i; float f; } x; x.f = f;
    uint32_t r = x.i + 0x7fffu + ((x.i >> 16) & 1u);
    return (unsigned short)(r >> 16);
}
__device__ __forceinline__ float loadf(const void* p, size_t i, int f32) {
    return f32 ? ((const float*)p)[i] : bf2f(((const unsigned short*)p)[i]);
}
// packed f32x2 -> bf16x2 (RNE), single HW instruction on gfx950
__device__ __forceinline__ uint32_t cvt_pk_bf16(float lo, float hi) {
    uint32_t r;
    asm("v_cvt_pk_bf16_f32 %0, %1, %2" : "=v"(r) : "v"(lo), "v"(hi));
    return r;
}

// async global->LDS, 16B per lane; LDS dest = wave-uniform base + lane*16
__device__ __forceinline__ void gl_lds16(const unsigned short* g, unsigned short* l) {
    __builtin_amdgcn_global_load_lds(
        (const __attribute__((address_space(1))) uint32_t*)g,
        (__attribute__((address_space(3))) uint32_t*)l,
        16, 0, 0);
}

// ---------------- dtype sniff ----------------
__global__ __launch_bounds__(256) void sniff_kernel(const unsigned short* __restrict__ x,
                                                    int* __restrict__ flag) {
    __shared__ int cnt[256];
    int tid = threadIdx.x;
    int c = 0;
    for (int i = tid * 2; i < 65536; i += 512) {
        int e = (x[i] >> 7) & 0xFF;
        if (e >= 0x8A) c++;
    }
    cnt[tid] = c;
    __syncthreads();
    for (int s = 128; s > 0; s >>= 1) {
        if (tid < s) cnt[tid] += cnt[tid + s];
        __syncthreads();
    }
    if (tid == 0) flag[0] = (cnt[0] > 32) ? 1 : 0;
}

// ---------------- converts ----------------
__global__ __launch_bounds__(256) void cvt_x(const void* __restrict__ x, float* __restrict__ xf,
                                             const int* __restrict__ flag) {
    int f = flag[0];
    int i = blockIdx.x * 256 + threadIdx.x;
    xf[i] = loadf(x, i, f);
}
__global__ __launch_bounds__(256) void store_out(const float* __restrict__ xf, void* __restrict__ out,
                                                 const int* __restrict__ flag) {
    int f = flag[0];
    int i = blockIdx.x * 256 + threadIdx.x;
    float v = xf[i];
    if (f) ((float*)out)[i] = v;
    else   ((unsigned short*)out)[i] = f2bf(v);
}
// all 7 small vectors in one launch; grid (64, 7)
__global__ __launch_bounds__(256) void conv_all(const void* s0, const void* s1, const void* s2,
                                                const void* s3, const void* s4, const void* s5,
                                                const void* s6, unsigned short* __restrict__ dst,
                                                const int* __restrict__ flag) {
    int f = flag[0];
    const void* src; int len, off;
    switch (blockIdx.y) {
        case 0: src = s0; len = 1024; off = 0;    break;
        case 1: src = s1; len = 1024; off = 1024; break;
        case 2: src = s2; len = 1024; off = 2048; break;
        case 3: src = s3; len = 1024; off = 3072; break;
        case 4: src = s4; len = 1024; off = 4096; break;
        case 5: src = s5; len = 1024; off = 5120; break;
        default: src = s6; len = 4096; off = 6144; break;
    }
    int i = blockIdx.x * 256 + threadIdx.x;
    if (i < DEPTHN * len) {
        int l = i / len, o = i - l * len;
        dst[l * VSTR + off + o] = f2bf(loadf(src, i, f));
    }
}

// ---------------- transpose+convert: src[srcOffE + k*N + n] -> bf16 out[n*K + k] ----------------
__global__ __launch_bounds__(256) void transpose_conv(const void* __restrict__ in, size_t srcOffE,
                                                      unsigned short* __restrict__ out,
                                                      int K, int N, const int* __restrict__ flag) {
    int f = flag[0];
    __shared__ unsigned short t[32][33];
    int n0 = blockIdx.x * 32, k0 = blockIdx.y * 32;
    int tx = threadIdx.x, ty = threadIdx.y;  // 32 x 8
#pragma unroll
    for (int i = 0; i < 4; i++) {
        int k = k0 + ty + i * 8;
        t[ty + i * 8][tx] = f2bf(loadf(in, srcOffE + (size_t)k * N + n0 + tx, f));
    }
    __syncthreads();
#pragma unroll
    for (int i = 0; i < 4; i++) {
        int n = n0 + ty + i * 8;
        out[(size_t)n * K + k0 + tx] = t[tx][ty + i * 8];
    }
}

// ---------------- V^T per layer ----------------
__global__ __launch_bounds__(256) void vt_kernel(const unsigned short* __restrict__ qkv,
                                                 unsigned short* __restrict__ vt) {
    __shared__ unsigned short t[32][33];
    int b = blockIdx.z;
    int c0 = blockIdx.x * 32, k0 = blockIdx.y * 32;
    int tx = threadIdx.x, ty = threadIdx.y;  // 32 x 8
#pragma unroll
    for (int i = 0; i < 4; i++) {
        int k = k0 + ty + i * 8;
        t[ty + i * 8][tx] = qkv[(size_t)(b * 1024 + k) * 3072 + 2048 + c0 + tx];
    }
    __syncthreads();
#pragma unroll
    for (int i = 0; i < 4; i++) {
        int c = c0 + ty + i * 8;
        vt[(size_t)(b * 1024 + c) * 1024 + k0 + tx] = t[tx][ty + i * 8];
    }
}

// ---------------- mask -> bitmask u64 words ----------------
__global__ __launch_bounds__(256) void mask_pack(const int* __restrict__ mask,
                                                 unsigned long long* __restrict__ bits) {
    int wid = (blockIdx.x * 256 + threadIdx.x) >> 6;
    int lane = threadIdx.x & 63;
#pragma unroll
    for (int i = 0; i < 16; i++) {
        int w = wid * 16 + i;
        int mv = mask[(size_t)w * 64 + lane];
        unsigned long long bl = __ballot(mv != 0);
        if (lane == 0) bits[w] = bl;
    }
}

// ---------------- LayerNorm (standalone; only for the first pre-attn LN) ----------------
__global__ __launch_bounds__(256) void ln_kernel(const float* __restrict__ x,
                                                 const unsigned short* __restrict__ g,
                                                 const unsigned short* __restrict__ bta,
                                                 unsigned short* __restrict__ out) {
    int row = blockIdx.x, tid = threadIdx.x;
    const float* xr = x + (size_t)row * DIMM;
    float v[4]; float s = 0.f, s2 = 0.f;
#pragma unroll
    for (int i = 0; i < 4; i++) { v[i] = xr[tid + i * 256]; s += v[i]; s2 += v[i] * v[i]; }
#pragma unroll
    for (int off = 32; off >= 1; off >>= 1) {
        s  += __shfl_down(s, off, 64);
        s2 += __shfl_down(s2, off, 64);
    }
    __shared__ float rs[4], rs2[4];
    int wv = tid >> 6;
    if ((tid & 63) == 0) { rs[wv] = s; rs2[wv] = s2; }
    __syncthreads();
    s  = rs[0] + rs[1] + rs[2] + rs[3];
    s2 = rs2[0] + rs2[1] + rs2[2] + rs2[3];
    float mu  = s * (1.f / DIMM);
    float var = s2 * (1.f / DIMM) - mu * mu;
    float rr  = rsqrtf(var + 1e-5f);
#pragma unroll
    for (int i = 0; i < 4; i++) {
        int c = tid + i * 256;
        float y = (v[i] - mu) * rr * bf2f(g[c]) + bf2f(bta[c]);
        out[(size_t)row * DIMM + c] = f2bf(y);
    }
}

// ---------------- split-K slab reduce + residual update (+ optional fused LN) ----------------
// xf[row] += bias + sum_z slab[z][row]; optionally LayerNorm(result) -> out (bf16).
template <int S, int HAS_LN>
__global__ __launch_bounds__(256) void reduce_ln(const float* __restrict__ slab,
                                                 const unsigned short* __restrict__ bias,
                                                 float* __restrict__ xf,
                                                 const unsigned short* __restrict__ g,
                                                 const unsigned short* __restrict__ bta,
                                                 unsigned short* __restrict__ out) {
    const size_t SL = (size_t)MROWS * DIMM;
    int row = blockIdx.x, tid = threadIdx.x;
    float v[4]; float s = 0.f, s2 = 0.f;
#pragma unroll
    for (int i = 0; i < 4; i++) {
        int c = tid + i * 256;
        size_t idx = (size_t)row * DIMM + c;
        float t = xf[idx] + bf2f(bias[c]);
#pragma unroll
        for (int z = 0; z < S; z++) t += slab[z * SL + idx];
        xf[idx] = t;
        v[i] = t; s += t; s2 += t * t;
    }
    if (HAS_LN) {
#pragma unroll
        for (int off = 32; off >= 1; off >>= 1) {
            s  += __shfl_down(s, off, 64);
            s2 += __shfl_down(s2, off, 64);
        }
        __shared__ float rs[4], rs2[4];
        int wv = tid >> 6;
        if ((tid & 63) == 0) { rs[wv] = s; rs2[wv] = s2; }
        __syncthreads();
        s  = rs[0] + rs[1] + rs[2] + rs[3];
        s2 = rs2[0] + rs2[1] + rs2[2] + rs2[3];
        float mu  = s * (1.f / DIMM);
        float var = s2 * (1.f / DIMM) - mu * mu;
        float rr  = rsqrtf(var + 1e-5f);
#pragma unroll
        for (int i = 0; i < 4; i++) {
            int c = tid + i * 256;
            float y = (v[i] - mu) * rr * bf2f(g[c]) + bf2f(bta[c]);
            out[(size_t)row * DIMM + c] = f2bf(y);
        }
    }
}

// ---------------- GEMM (single-buffer async staging, R4 structure) ----------------
// MODE 0: store bf16 C       MODE 1: Cres(fp32) atomic += acc(+bias@z0)  [fallback]
// MODE 2: bf16 gelu(acc+bias) MODE 3: slab[z] = acc (fp32, pure stores)
template <int MODE, int SPLITK>
__global__ __launch_bounds__(256) void gemm_bt(const unsigned short* __restrict__ A,
                                               const unsigned short* __restrict__ Bt,
                                               const unsigned short* __restrict__ bias,
                                               unsigned short* __restrict__ Cbf,
                                               float* __restrict__ Cres,
                                               int M, int N, int K) {
    __shared__ __align__(16) unsigned short As[128 * 32];
    __shared__ __align__(16) unsigned short Bs[128 * 32];
    const int tid = threadIdx.x;
    const int mBase = blockIdx.y * 128, nBase = blockIdx.x * 128;
    const int w = tid >> 6, lane = tid & 63;
    const int wm = (w >> 1) * 64, wn = (w & 1) * 64;
    const int quad = lane >> 4, l16 = lane & 15;
    const int kLen = K / SPLITK;
    const int kStart = (SPLITK > 1) ? blockIdx.z * kLen : 0;

    f32x4 acc[4][4];
#pragma unroll
    for (int i = 0; i < 4; i++)
#pragma unroll
        for (int j = 0; j < 4; j++) acc[i][j] = (f32x4){0.f, 0.f, 0.f, 0.f};

    // staging: wave w stages rows [w*32, w*32+32) of both tiles as 2 chunks of 16 rows; 16B/lane.
    const int lr = lane >> 2, lc = (lane & 3) * 8;
    const unsigned short* Ag = A  + (size_t)(mBase + w * 32 + lr) * K + kStart + lc;
    const unsigned short* Bg = Bt + (size_t)(nBase + w * 32 + lr) * K + kStart + lc;
    unsigned short* Al0 = &As[(w * 32) * 32];
    unsigned short* Al1 = &As[(w * 32 + 16) * 32];
    unsigned short* Bl0 = &Bs[(w * 32) * 32];
    unsigned short* Bl1 = &Bs[(w * 32 + 16) * 32];
    const size_t rstep = (size_t)16 * K;

    for (int k0 = 0; k0 < kLen; k0 += 32) {
        __syncthreads();
        gl_lds16(Ag + k0,         Al0);
        gl_lds16(Ag + k0 + rstep, Al1);
        gl_lds16(Bg + k0,         Bl0);
        gl_lds16(Bg + k0 + rstep, Bl1);
        __syncthreads();  // drains vmcnt before LDS reads

        bf16x8 af[4], bfv[4];
#pragma unroll
        for (int i = 0; i < 4; i++)
            af[i] = *(const bf16x8*)&As[(wm + i * 16 + l16) * 32 + quad * 8];
#pragma unroll
        for (int j = 0; j < 4; j++)
            bfv[j] = *(const bf16x8*)&Bs[(wn + j * 16 + l16) * 32 + quad * 8];
#pragma unroll
        for (int i = 0; i < 4; i++)
#pragma unroll
            for (int j = 0; j < 4; j++)
                acc[i][j] = __builtin_amdgcn_mfma_f32_16x16x32_bf16(af[i], bfv[j], acc[i][j], 0, 0, 0);
    }

    const size_t slabOff = (MODE == 3) ? (size_t)blockIdx.z * M * N : 0;
#pragma unroll
    for (int i = 0; i < 4; i++) {
#pragma unroll
        for (int j = 0; j < 4; j++) {
#pragma unroll
            for (int r = 0; r < 4; r++) {
                int m = mBase + wm + i * 16 + quad * 4 + r;
                int n = nBase + wn + j * 16 + l16;
                float v = acc[i][j][r];
                size_t idx = (size_t)m * N + n;
                if (MODE == 0) {
                    Cbf[idx] = f2bf(v);
                } else if (MODE == 1) {
                    if (SPLITK > 1) {
                        if (blockIdx.z == 0) v += bf2f(bias[n]);
                        atomicAdd(&Cres[idx], v);
                    } else {
                        Cres[idx] += v + bf2f(bias[n]);
                    }
                } else if (MODE == 2) {
                    float t2 = v + bf2f(bias[n]);
                    float gg = 0.5f * t2 * (1.f + erff(t2 * 0.70710678118f));
                    Cbf[idx] = f2bf(gg);
                } else {
                    Cres[slabOff + idx] = v;
                }
            }
        }
    }
}

// ---------------- MFMA flash attention (swapped-QK, in-register P) ----------------
// S^T = mfma(K_frag, Q_frag): each lane owns ONE q-row (q = w*16 + l16) and holds
// 16 scores of the 64-key tile: k = j*16 + quad*4 + r.  Row softmax is therefore
// 15 in-lane ops + 2 shfl_xor (across quads) instead of 16 serial shuffles.
// PV uses a k-permutation sigma(8q+e) = 16*(e/4) + 4q + e%4 applied to BOTH operands:
// the A-fragment is the lane's own p-values packed in-register (no cross-lane moves,
// no Ps LDS round trip), and V is read as two ds_read_b64 per fragment at
// k = 32ks+4*quad and +16 (uniform 2 dwords/bank -> conflict-free).
__global__ __launch_bounds__(256) void attn_mfma(const unsigned short* __restrict__ qkv,
                                                 const unsigned short* __restrict__ vt,
                                                 const unsigned long long* __restrict__ mbits,
                                                 unsigned short* __restrict__ o) {
    __shared__ __align__(16) unsigned short Ks[64 * 72];
    __shared__ __align__(16) unsigned short Vs[64 * 72];

    const int tid = threadIdx.x, w = tid >> 6, lane = tid & 63;
    const int quad = lane >> 4, l16 = lane & 15;
    const int qt = blockIdx.x, h = blockIdx.y, b = blockIdx.z;

    // Q fragment = B-operand of S^T: lane holds Q[q=l16][d = ks*32 + quad*8 + e]
    const size_t qrow = (size_t)(b * NSEQ + qt * 64 + w * 16 + l16) * 3072 + h * 64;
    bf16x8 qf[2];
    qf[0] = *(const bf16x8*)(qkv + qrow + quad * 8);
    qf[1] = *(const bf16x8*)(qkv + qrow + 32 + quad * 8);

    const int srow = tid >> 2, scol = (tid & 3) * 16;
    const unsigned short* kg_base = qkv + (size_t)(b * NSEQ) * 3072 + 1024 + h * 64;
    const unsigned short* vg_base = vt + (size_t)((b * HEADSN + h) * 64 + srow) * 1024;

    f32x4 oacc[4];
#pragma unroll
    for (int j = 0; j < 4; j++) oacc[j] = (f32x4){0.f, 0.f, 0.f, 0.f};
    // per-lane row state for q = w*16 + l16 (replicated across the 4 quads)
    float m_run = -1e30f, l_run = 0.f;

    // one mask word per kt: bits 0..63 = keep flags for this lane's q-row
    const unsigned long long* mb = mbits + ((size_t)(b * NSEQ + qt * 64 + w * 16 + l16)) * 16;

    for (int kt = 0; kt < 16; kt++) {
        __syncthreads();
        {
            const unsigned short* kg = kg_base + (size_t)(kt * 64 + srow) * 3072 + scol;
            uint4 k0 = *(const uint4*)kg;
            uint4 k1 = *(const uint4*)(kg + 8);
            const unsigned short* vg = vg_base + kt * 64 + scol;
            uint4 v0 = *(const uint4*)vg;
            uint4 v1 = *(const uint4*)(vg + 8);
            *(uint4*)&Ks[srow * 72 + scol]     = k0;
            *(uint4*)&Ks[srow * 72 + scol + 8] = k1;
            *(uint4*)&Vs[srow * 72 + scol]     = v0;
            *(uint4*)&Vs[srow * 72 + scol + 8] = v1;
        }
        __syncthreads();

        // S^T: sacc[j][r] = S[q=l16][k = j*16 + quad*4 + r]
        f32x4 sacc[4];
#pragma unroll
        for (int j = 0; j < 4; j++) sacc[j] = (f32x4){0.f, 0.f, 0.f, 0.f};
#pragma unroll
        for (int ks = 0; ks < 2; ks++) {
#pragma unroll
            for (int j = 0; j < 4; j++) {
                bf16x8 kf = *(const bf16x8*)&Ks[(j * 16 + l16) * 72 + ks * 32 + quad * 8];
                sacc[j] = __builtin_amdgcn_mfma_f32_16x16x32_bf16(kf, qf[ks], sacc[j], 0, 0, 0);
            }
        }

        const unsigned long long mw = mb[kt];

        // masked, scaled scores + in-lane max
        float t[4][4];
        float mxj[4];
#pragma unroll
        for (int j = 0; j < 4; j++) {
            unsigned nib = (unsigned)(mw >> (quad * 4 + j * 16)) & 0xFu;
#pragma unroll
            for (int r = 0; r < 4; r++) {
                float s = sacc[j][r] * 0.125f;
                t[j][r] = ((nib >> r) & 1u) ? s : -1e30f;
            }
            mxj[j] = fmaxf(fmaxf(t[j][0], t[j][1]), fmaxf(t[j][2], t[j][3]));
        }
        float mx = fmaxf(fmaxf(mxj[0], mxj[1]), fmaxf(mxj[2], mxj[3]));
        // row max across the 4 quads holding this q-row
        mx = fmaxf(mx, __shfl_xor(mx, 16, 64));
        mx = fmaxf(mx, __shfl_xor(mx, 32, 64));

        // defer-max: only rescale O when some row's max actually grew (T13)
        if (!__all(mx <= m_run)) {
            float m_new = fmaxf(m_run, mx);
            float alpha = __expf(m_run - m_new);
            m_run = m_new;
            l_run *= alpha;
            // alpha lives in the l16 frame; oacc rows are q = quad*4 + r
            float al[4];
#pragma unroll
            for (int r = 0; r < 4; r++) al[r] = __shfl(alpha, quad * 4 + r, 64);
#pragma unroll
            for (int j = 0; j < 4; j++)
#pragma unroll
                for (int r = 0; r < 4; r++) oacc[j][r] *= al[r];
        }

        // p = exp(t - m), row-sum, pack into A-fragment (sigma order = own regs!)
        float p[4][4];
        float psj[4];
#pragma unroll
        for (int j = 0; j < 4; j++) {
#pragma unroll
            for (int r = 0; r < 4; r++) p[j][r] = __expf(t[j][r] - m_run);
            psj[j] = (p[j][0] + p[j][1]) + (p[j][2] + p[j][3]);
        }
        float ps = (psj[0] + psj[1]) + (psj[2] + psj[3]);
        ps += __shfl_xor(ps, 16, 64);
        ps += __shfl_xor(ps, 32, 64);
        l_run += ps;

        union { uint32_t u[4]; bf16x8 v; } pa[2];
#pragma unroll
        for (int ks = 0; ks < 2; ks++) {
            pa[ks].u[0] = cvt_pk_bf16(p[2 * ks][0],     p[2 * ks][1]);
            pa[ks].u[1] = cvt_pk_bf16(p[2 * ks][2],     p[2 * ks][3]);
            pa[ks].u[2] = cvt_pk_bf16(p[2 * ks + 1][0], p[2 * ks + 1][1]);
            pa[ks].u[3] = cvt_pk_bf16(p[2 * ks + 1][2], p[2 * ks + 1][3]);
        }

        // PV with sigma-permuted V reads: element e of B-frag = V[32ks + 16*(e/4) + 4*quad + e%4][d]
#pragma unroll
        for (int ks = 0; ks < 2; ks++) {
#pragma unroll
            for (int j = 0; j < 4; j++) {
                union { ushort4 u[2]; bf16x8 v; } vf;
                const unsigned short* vp = &Vs[(j * 16 + l16) * 72 + ks * 32 + quad * 4];
                vf.u[0] = *(const ushort4*)vp;
                vf.u[1] = *(const ushort4*)(vp + 16);
                oacc[j] = __builtin_amdgcn_mfma_f32_16x16x32_bf16(pa[ks].v, vf.v, oacc[j], 0, 0, 0);
            }
        }
    }

    // l_run lives in the l16 frame; output rows are q = quad*4 + r
    float inv[4];
#pragma unroll
    for (int r = 0; r < 4; r++) {
        float lr = __shfl(l_run, quad * 4 + r, 64);
        inv[r] = 1.f / lr;
    }
#pragma unroll
    for (int j = 0; j < 4; j++) {
#pragma unroll
        for (int r = 0; r < 4; r++) {
            size_t row = (size_t)(b * NSEQ + qt * 64 + w * 16 + quad * 4 + r);
            o[row * 1024 + h * 64 + j * 16 + l16] = f2bf(oacc[j][r] * inv[r]);
        }
    }
}

extern "C" void kernel_launch(void* const* d_in, const int* in_sizes, int n_in,
                              void* d_out, int out_size, void* d_ws, size_t ws_size,
                              hipStream_t stream) {
    const void* x     = d_in[0];
    const int*  mask  = (const int*)d_in[1];
    const void* ln1_g = d_in[2];
    const void* ln1_b = d_in[3];
    const void* qkv_w = d_in[4];
    const void* out_w = d_in[5];
    const void* out_b = d_in[6];
    const void* ln2_g = d_in[7];
    const void* ln2_b = d_in[8];
    const void* ff1_w = d_in[9];
    const void* ff1_b = d_in[10];
    const void* ff2_w = d_in[11];
    const void* ff2_b = d_in[12];

    char* ws = (char*)d_ws;
    float*          xf     = (float*)ws;                            // 8 MB fp32 residual
    unsigned short* h_bf   = (unsigned short*)(ws + (8u  << 20));   // 4 MB LN out
    unsigned short* qkv_bf = (unsigned short*)(ws + (12u << 20));   // 12 MB (attn half)
    unsigned short* ff_bf  = (unsigned short*)(ws + (12u << 20));   // 16 MB (ff half, reuses qkv+vt)
    unsigned short* vt_bf  = (unsigned short*)(ws + (24u << 20));   // 4 MB V^T (attn half)
    unsigned short* o_bf   = (unsigned short*)(ws + (28u << 20));   // 4 MB
    unsigned short* wT     = (unsigned short*)(ws + (32u << 20));   // 8 MB transposed weight
    unsigned short* vecs   = (unsigned short*)(ws + (40u << 20));   // 80 KB canonical vecs
    int*            flag   = (int*)(ws + (40u << 20) + (128u << 10));
    unsigned long long* mbits = (unsigned long long*)(ws + (40u << 20) + (192u << 10)); // 256 KB
    float*          slab   = (float*)(ws + (41u << 20));            // up to 32 MB split-K slabs

    const bool slabs_ok = ws_size >= (74ull << 20);

    sniff_kernel<<<1, 256, 0, stream>>>((const unsigned short*)x, flag);

    conv_all<<<dim3(64, 7), 256, 0, stream>>>(ln1_g, ln1_b, out_b, ln2_g, ln2_b, ff2_b, ff1_b,
                                              vecs, flag);
    mask_pack<<<512, 256, 0, stream>>>(mask, mbits);

    const int nx = MROWS * DIMM;  // 2M
    cvt_x<<<nx / 256, 256, 0, stream>>>(x, xf, flag);

    for (int l = 0; l < DEPTHN; l++) {
        const unsigned short* lv = vecs + l * VSTR;
        const unsigned short* lvn = vecs + (l + 1) * VSTR;  // next layer's vecs (l<3)

        // --- attention half ---
        if (l == 0)  // layers 1..3 get ln1 fused into the previous FF2 reduce
            ln_kernel<<<MROWS, 256, 0, stream>>>(xf, lv + 0, lv + 1024, h_bf);
        transpose_conv<<<dim3(3072 / 32, 1024 / 32), dim3(32, 8), 0, stream>>>(
            qkv_w, (size_t)l * 1024 * 3072, wT, 1024, 3072, flag);
        gemm_bt<0, 1><<<dim3(3072 / 128, MROWS / 128), 256, 0, stream>>>(
            h_bf, wT, nullptr, qkv_bf, nullptr, MROWS, 3072, 1024);
        vt_kernel<<<dim3(32, 32, BB), dim3(32, 8), 0, stream>>>(qkv_bf, vt_bf);
        attn_mfma<<<dim3(NSEQ / 64, HEADSN, BB), 256, 0, stream>>>(qkv_bf, vt_bf, mbits, o_bf);
        transpose_conv<<<dim3(1024 / 32, 1024 / 32), dim3(32, 8), 0, stream>>>(
            out_w, (size_t)l * 1024 * 1024, wT, 1024, 1024, flag);
        if (slabs_ok) {
            gemm_bt<3, 2><<<dim3(1024 / 128, MROWS / 128, 2), 256, 0, stream>>>(
                o_bf, wT, nullptr, nullptr, slab, MROWS, 1024, 1024);
            reduce_ln<2, 1><<<MROWS, 256, 0, stream>>>(
                slab, lv + 2048, xf, lv + 3072, lv + 4096, h_bf);
        } else {
            gemm_bt<1, 2><<<dim3(1024 / 128, MROWS / 128, 2), 256, 0, stream>>>(
                o_bf, wT, lv + 2048, nullptr, xf, MROWS, 1024, 1024);
            ln_kernel<<<MROWS, 256, 0, stream>>>(xf, lv + 3072, lv + 4096, h_bf);
        }

        // --- feedforward half ---
        transpose_conv<<<dim3(4096 / 32, 1024 / 32), dim3(32, 8), 0, stream>>>(
            ff1_w, (size_t)l * 1024 * 4096, wT, 1024, 4096, flag);
        gemm_bt<2, 1><<<dim3(4096 / 128, MROWS / 128), 256, 0, stream>>>(
            h_bf, wT, lv + 6144, ff_bf, nullptr, MROWS, 4096, 1024);
        transpose_conv<<<dim3(1024 / 32, 4096 / 32), dim3(32, 8), 0, stream>>>(
            ff2_w, (size_t)l * 4096 * 1024, wT, 4096, 1024, flag);
        if (slabs_ok) {
            gemm_bt<3, 4><<<dim3(1024 / 128, MROWS / 128, 4), 256, 0, stream>>>(
                ff_bf, wT, nullptr, nullptr, slab, MROWS, 1024, 4096);
            if (l < DEPTHN - 1)
                reduce_ln<4, 1><<<MROWS, 256, 0, stream>>>(
                    slab, lv + 5120, xf, lvn + 0, lvn + 1024, h_bf);
            else
                reduce_ln<4, 0><<<MROWS, 256, 0, stream>>>(
                    slab, lv + 5120, xf, nullptr, nullptr, nullptr);
        } else {
            gemm_bt<1, 4><<<dim3(1024 / 128, MROWS / 128, 4), 256, 0, stream>>>(
                ff_bf, wT, lv + 5120, nullptr, xf, MROWS, 1024, 4096);
            if (l < DEPTHN - 1)
                ln_kernel<<<MROWS, 256, 0, stream>>>(xf, lvn + 0, lvn + 1024, h_bf);
        }
    }

    store_out<<<nx / 256, 256, 0, stream>>>(xf, d_out, flag);
}

// Round 2
// 936.141 us; speedup vs baseline: 1.1128x; 1.0784x over previous
//
#include <hip/hip_runtime.h>
#include <stdint.h>

#define DIMM 1024
#define NSEQ 1024
#define BB 2
#define HEADSN 16
#define MLPD 4096
#define DEPTHN 4
#define MROWS (BB*NSEQ)  // 2048
#define VSTR 10240       // canonical per-layer vec stride (elements)

typedef __bf16 bf16x8 __attribute__((ext_vector_type(8)));
typedef float f32x4 __attribute__((ext_vector_type(4)));

__device__ __forceinline__ float bf2f(unsigned short u) {
    union { uint32_t i; float f; } x; x.i = ((uint32_t)u) << 16; return x.f;
}
__device__ __forceinline__ unsigned short f2bf(float f) {
    union { uint32_t i; float f; } x; x.f = f;
    uint32_t r = x.i + 0x7fffu + ((x.i >> 16) & 1u);
    return (unsigned short)(r >> 16);
}
__device__ __forceinline__ float loadf(const void* p, size_t i, int f32) {
    return f32 ? ((const float*)p)[i] : bf2f(((const unsigned short*)p)[i]);
}
// packed f32x2 -> bf16x2 (RNE), single HW instruction on gfx950
__device__ __forceinline__ uint32_t cvt_pk_bf16(float lo, float hi) {
    uint32_t r;
    asm("v_cvt_pk_bf16_f32 %0, %1, %2" : "=v"(r) : "v"(lo), "v"(hi));
    return r;
}

// async global->LDS, 16B per lane; LDS dest = wave-uniform base + lane*16
__device__ __forceinline__ void gl_lds16(const unsigned short* g, unsigned short* l) {
    __builtin_amdgcn_global_load_lds(
        (const __attribute__((address_space(1))) uint32_t*)g,
        (__attribute__((address_space(3))) uint32_t*)l,
        16, 0, 0);
}

// ---------------- dtype sniff ----------------
__global__ __launch_bounds__(256) void sniff_kernel(const unsigned short* __restrict__ x,
                                                    int* __restrict__ flag) {
    __shared__ int cnt[256];
    int tid = threadIdx.x;
    int c = 0;
    for (int i = tid * 2; i < 65536; i += 512) {
        int e = (x[i] >> 7) & 0xFF;
        if (e >= 0x8A) c++;
    }
    cnt[tid] = c;
    __syncthreads();
    for (int s = 128; s > 0; s >>= 1) {
        if (tid < s) cnt[tid] += cnt[tid + s];
        __syncthreads();
    }
    if (tid == 0) flag[0] = (cnt[0] > 32) ? 1 : 0;
}

// ---------------- converts ----------------
__global__ __launch_bounds__(256) void cvt_x(const void* __restrict__ x, float* __restrict__ xf,
                                             const int* __restrict__ flag) {
    int f = flag[0];
    int i = blockIdx.x * 256 + threadIdx.x;
    xf[i] = loadf(x, i, f);
}
__global__ __launch_bounds__(256) void store_out(const float* __restrict__ xf, void* __restrict__ out,
                                                 const int* __restrict__ flag) {
    int f = flag[0];
    int i = blockIdx.x * 256 + threadIdx.x;
    float v = xf[i];
    if (f) ((float*)out)[i] = v;
    else   ((unsigned short*)out)[i] = f2bf(v);
}
// all 7 small vectors in one launch; grid (64, 7)
__global__ __launch_bounds__(256) void conv_all(const void* s0, const void* s1, const void* s2,
                                                const void* s3, const void* s4, const void* s5,
                                                const void* s6, unsigned short* __restrict__ dst,
                                                const int* __restrict__ flag) {
    int f = flag[0];
    const void* src; int len, off;
    switch (blockIdx.y) {
        case 0: src = s0; len = 1024; off = 0;    break;
        case 1: src = s1; len = 1024; off = 1024; break;
        case 2: src = s2; len = 1024; off = 2048; break;
        case 3: src = s3; len = 1024; off = 3072; break;
        case 4: src = s4; len = 1024; off = 4096; break;
        case 5: src = s5; len = 1024; off = 5120; break;
        default: src = s6; len = 4096; off = 6144; break;
    }
    int i = blockIdx.x * 256 + threadIdx.x;
    if (i < DEPTHN * len) {
        int l = i / len, o = i - l * len;
        dst[l * VSTR + off + o] = f2bf(loadf(src, i, f));
    }
}

// ---------------- transpose+convert: src[srcOffE + k*N + n] -> bf16 out[n*K + k] ----------------
__global__ __launch_bounds__(256) void transpose_conv(const void* __restrict__ in, size_t srcOffE,
                                                      unsigned short* __restrict__ out,
                                                      int K, int N, const int* __restrict__ flag) {
    int f = flag[0];
    __shared__ unsigned short t[32][33];
    int n0 = blockIdx.x * 32, k0 = blockIdx.y * 32;
    int tx = threadIdx.x, ty = threadIdx.y;  // 32 x 8
#pragma unroll
    for (int i = 0; i < 4; i++) {
        int k = k0 + ty + i * 8;
        t[ty + i * 8][tx] = f2bf(loadf(in, srcOffE + (size_t)k * N + n0 + tx, f));
    }
    __syncthreads();
#pragma unroll
    for (int i = 0; i < 4; i++) {
        int n = n0 + ty + i * 8;
        out[(size_t)n * K + k0 + tx] = t[tx][ty + i * 8];
    }
}

// ---------------- V^T per layer ----------------
__global__ __launch_bounds__(256) void vt_kernel(const unsigned short* __restrict__ qkv,
                                                 unsigned short* __restrict__ vt) {
    __shared__ unsigned short t[32][33];
    int b = blockIdx.z;
    int c0 = blockIdx.x * 32, k0 = blockIdx.y * 32;
    int tx = threadIdx.x, ty = threadIdx.y;  // 32 x 8
#pragma unroll
    for (int i = 0; i < 4; i++) {
        int k = k0 + ty + i * 8;
        t[ty + i * 8][tx] = qkv[(size_t)(b * 1024 + k) * 3072 + 2048 + c0 + tx];
    }
    __syncthreads();
#pragma unroll
    for (int i = 0; i < 4; i++) {
        int c = c0 + ty + i * 8;
        vt[(size_t)(b * 1024 + c) * 1024 + k0 + tx] = t[tx][ty + i * 8];
    }
}

// ---------------- mask -> bitmask u64 words ----------------
__global__ __launch_bounds__(256) void mask_pack(const int* __restrict__ mask,
                                                 unsigned long long* __restrict__ bits) {
    int wid = (blockIdx.x * 256 + threadIdx.x) >> 6;
    int lane = threadIdx.x & 63;
#pragma unroll
    for (int i = 0; i < 16; i++) {
        int w = wid * 16 + i;
        int mv = mask[(size_t)w * 64 + lane];
        unsigned long long bl = __ballot(mv != 0);
        if (lane == 0) bits[w] = bl;
    }
}

// ---------------- LayerNorm (standalone; only for the first pre-attn LN) ----------------
__global__ __launch_bounds__(256) void ln_kernel(const float* __restrict__ x,
                                                 const unsigned short* __restrict__ g,
                                                 const unsigned short* __restrict__ bta,
                                                 unsigned short* __restrict__ out) {
    int row = blockIdx.x, tid = threadIdx.x;
    const float* xr = x + (size_t)row * DIMM;
    float v[4]; float s = 0.f, s2 = 0.f;
#pragma unroll
    for (int i = 0; i < 4; i++) { v[i] = xr[tid + i * 256]; s += v[i]; s2 += v[i] * v[i]; }
#pragma unroll
    for (int off = 32; off >= 1; off >>= 1) {
        s  += __shfl_down(s, off, 64);
        s2 += __shfl_down(s2, off, 64);
    }
    __shared__ float rs[4], rs2[4];
    int wv = tid >> 6;
    if ((tid & 63) == 0) { rs[wv] = s; rs2[wv] = s2; }
    __syncthreads();
    s  = rs[0] + rs[1] + rs[2] + rs[3];
    s2 = rs2[0] + rs2[1] + rs2[2] + rs2[3];
    float mu  = s * (1.f / DIMM);
    float var = s2 * (1.f / DIMM) - mu * mu;
    float rr  = rsqrtf(var + 1e-5f);
#pragma unroll
    for (int i = 0; i < 4; i++) {
        int c = tid + i * 256;
        float y = (v[i] - mu) * rr * bf2f(g[c]) + bf2f(bta[c]);
        out[(size_t)row * DIMM + c] = f2bf(y);
    }
}

// ---------------- split-K slab reduce + residual update (+ optional fused LN) ----------------
// xf[row] += bias + sum_z slab[z][row]; optionally LayerNorm(result) -> out (bf16).
template <int S, int HAS_LN>
__global__ __launch_bounds__(256) void reduce_ln(const float* __restrict__ slab,
                                                 const unsigned short* __restrict__ bias,
                                                 float* __restrict__ xf,
                                                 const unsigned short* __restrict__ g,
                                                 const unsigned short* __restrict__ bta,
                                                 unsigned short* __restrict__ out) {
    const size_t SL = (size_t)MROWS * DIMM;
    int row = blockIdx.x, tid = threadIdx.x;
    float v[4]; float s = 0.f, s2 = 0.f;
#pragma unroll
    for (int i = 0; i < 4; i++) {
        int c = tid + i * 256;
        size_t idx = (size_t)row * DIMM + c;
        float t = xf[idx] + bf2f(bias[c]);
#pragma unroll
        for (int z = 0; z < S; z++) t += slab[z * SL + idx];
        xf[idx] = t;
        v[i] = t; s += t; s2 += t * t;
    }
    if (HAS_LN) {
#pragma unroll
        for (int off = 32; off >= 1; off >>= 1) {
            s  += __shfl_down(s, off, 64);
            s2 += __shfl_down(s2, off, 64);
        }
        __shared__ float rs[4], rs2[4];
        int wv = tid >> 6;
        if ((tid & 63) == 0) { rs[wv] = s; rs2[wv] = s2; }
        __syncthreads();
        s  = rs[0] + rs[1] + rs[2] + rs[3];
        s2 = rs2[0] + rs2[1] + rs2[2] + rs2[3];
        float mu  = s * (1.f / DIMM);
        float var = s2 * (1.f / DIMM) - mu * mu;
        float rr  = rsqrtf(var + 1e-5f);
#pragma unroll
        for (int i = 0; i < 4; i++) {
            int c = tid + i * 256;
            float y = (v[i] - mu) * rr * bf2f(g[c]) + bf2f(bta[c]);
            out[(size_t)row * DIMM + c] = f2bf(y);
        }
    }
}

// ---------------- GEMM (8-wave 128x128 tile, swizzled LDS, async staging) ----------------
// 512 threads = 8 waves; wave-tile 64x32 (wm=(w>>2)*64, wn=(w&3)*32).
// Staging: waves 0-3 stage A rows [w*32,w*32+32), waves 4-7 stage B; 2x gl_lds16 each.
// LDS XOR swizzle (both-sides, linear gl_lds dest): column-block cb' = cb ^ ((row>>1)&3),
// applied as pre-swizzled GLOBAL source column on the write and the same XOR on the
// fragment read -> each 16-lane read phase covers all 32 banks at 2 dwords/bank (free).
// MODE 0: store bf16 C       MODE 1: Cres(fp32) atomic += acc(+bias@z0)  [fallback]
// MODE 2: bf16 gelu(acc+bias) MODE 3: slab[z] = acc (fp32, pure stores)
template <int MODE, int SPLITK>
__global__ __launch_bounds__(512) void gemm_bt(const unsigned short* __restrict__ A,
                                               const unsigned short* __restrict__ Bt,
                                               const unsigned short* __restrict__ bias,
                                               unsigned short* __restrict__ Cbf,
                                               float* __restrict__ Cres,
                                               int M, int N, int K) {
    __shared__ __align__(16) unsigned short As[128 * 32];
    __shared__ __align__(16) unsigned short Bs[128 * 32];
    const int tid = threadIdx.x;
    const int mBase = blockIdx.y * 128, nBase = blockIdx.x * 128;
    const int w = tid >> 6, lane = tid & 63;
    const int wm = (w >> 2) * 64, wn = (w & 3) * 32;
    const int quad = lane >> 4, l16 = lane & 15;
    const int kLen = K / SPLITK;
    const int kStart = (SPLITK > 1) ? blockIdx.z * kLen : 0;

    f32x4 acc[4][2];
#pragma unroll
    for (int i = 0; i < 4; i++)
#pragma unroll
        for (int j = 0; j < 2; j++) acc[i][j] = (f32x4){0.f, 0.f, 0.f, 0.f};

    // staging: 16B/lane, LDS dest linear (base + lane*16); source column pre-swizzled.
    const int lr = lane >> 2;
    const int lc = ((lane & 3) ^ ((lr >> 1) & 3)) * 8;  // swizzled source col (elements)
    const int wb = w & 3;
    const unsigned short* G = (w < 4 ? A  + (size_t)(mBase + wb * 32 + lr) * K
                                     : Bt + (size_t)(nBase + wb * 32 + lr) * K)
                              + kStart + lc;
    unsigned short* L0 = (w < 4 ? &As[(wb * 32) * 32] : &Bs[(wb * 32) * 32]);
    unsigned short* L1 = L0 + 16 * 32;
    const size_t rstep = (size_t)16 * K;

    const int rcb = (quad ^ ((l16 >> 1) & 3)) * 8;  // swizzled read col (elements)

    for (int k0 = 0; k0 < kLen; k0 += 32) {
        __syncthreads();
        gl_lds16(G + k0,         L0);
        gl_lds16(G + k0 + rstep, L1);
        __syncthreads();  // drains vmcnt before LDS reads

        bf16x8 af[4], bfv[2];
#pragma unroll
        for (int i = 0; i < 4; i++)
            af[i] = *(const bf16x8*)&As[(wm + i * 16 + l16) * 32 + rcb];
#pragma unroll
        for (int j = 0; j < 2; j++)
            bfv[j] = *(const bf16x8*)&Bs[(wn + j * 16 + l16) * 32 + rcb];
#pragma unroll
        for (int i = 0; i < 4; i++)
#pragma unroll
            for (int j = 0; j < 2; j++)
                acc[i][j] = __builtin_amdgcn_mfma_f32_16x16x32_bf16(af[i], bfv[j], acc[i][j], 0, 0, 0);
    }

    const size_t slabOff = (MODE == 3) ? (size_t)blockIdx.z * M * N : 0;
#pragma unroll
    for (int i = 0; i < 4; i++) {
#pragma unroll
        for (int j = 0; j < 2; j++) {
#pragma unroll
            for (int r = 0; r < 4; r++) {
                int m = mBase + wm + i * 16 + quad * 4 + r;
                int n = nBase + wn + j * 16 + l16;
                float v = acc[i][j][r];
                size_t idx = (size_t)m * N + n;
                if (MODE == 0) {
                    Cbf[idx] = f2bf(v);
                } else if (MODE == 1) {
                    if (SPLITK > 1) {
                        if (blockIdx.z == 0) v += bf2f(bias[n]);
                        atomicAdd(&Cres[idx], v);
                    } else {
                        Cres[idx] += v + bf2f(bias[n]);
                    }
                } else if (MODE == 2) {
                    float t2 = v + bf2f(bias[n]);
                    float gg = 0.5f * t2 * (1.f + erff(t2 * 0.70710678118f));
                    Cbf[idx] = f2bf(gg);
                } else {
                    Cres[slabOff + idx] = v;
                }
            }
        }
    }
}

// ---------------- MFMA flash attention (swapped-QK, in-register P) ----------------
// S^T = mfma(K_frag, Q_frag): each lane owns ONE q-row (q = w*16 + l16) and holds
// 16 scores of the 64-key tile: k = j*16 + quad*4 + r.  Row softmax is therefore
// 15 in-lane ops + 2 shfl_xor (across quads) instead of 16 serial shuffles.
// PV uses a k-permutation sigma(8q+e) = 16*(e/4) + 4q + e%4 applied to BOTH operands:
// the A-fragment is the lane's own p-values packed in-register (no cross-lane moves,
// no Ps LDS round trip), and V is read as two ds_read_b64 per fragment at
// k = 32ks+4*quad and +16 (uniform 2 dwords/bank -> conflict-free).
__global__ __launch_bounds__(256) void attn_mfma(const unsigned short* __restrict__ qkv,
                                                 const unsigned short* __restrict__ vt,
                                                 const unsigned long long* __restrict__ mbits,
                                                 unsigned short* __restrict__ o) {
    __shared__ __align__(16) unsigned short Ks[64 * 72];
    __shared__ __align__(16) unsigned short Vs[64 * 72];

    const int tid = threadIdx.x, w = tid >> 6, lane = tid & 63;
    const int quad = lane >> 4, l16 = lane & 15;
    const int qt = blockIdx.x, h = blockIdx.y, b = blockIdx.z;

    // Q fragment = B-operand of S^T: lane holds Q[q=l16][d = ks*32 + quad*8 + e]
    const size_t qrow = (size_t)(b * NSEQ + qt * 64 + w * 16 + l16) * 3072 + h * 64;
    bf16x8 qf[2];
    qf[0] = *(const bf16x8*)(qkv + qrow + quad * 8);
    qf[1] = *(const bf16x8*)(qkv + qrow + 32 + quad * 8);

    const int srow = tid >> 2, scol = (tid & 3) * 16;
    const unsigned short* kg_base = qkv + (size_t)(b * NSEQ) * 3072 + 1024 + h * 64;
    const unsigned short* vg_base = vt + (size_t)((b * HEADSN + h) * 64 + srow) * 1024;

    f32x4 oacc[4];
#pragma unroll
    for (int j = 0; j < 4; j++) oacc[j] = (f32x4){0.f, 0.f, 0.f, 0.f};
    // per-lane row state for q = w*16 + l16 (replicated across the 4 quads)
    float m_run = -1e30f, l_run = 0.f;

    // one mask word per kt: bits 0..63 = keep flags for this lane's q-row
    const unsigned long long* mb = mbits + ((size_t)(b * NSEQ + qt * 64 + w * 16 + l16)) * 16;

    for (int kt = 0; kt < 16; kt++) {
        __syncthreads();
        {
            const unsigned short* kg = kg_base + (size_t)(kt * 64 + srow) * 3072 + scol;
            uint4 k0 = *(const uint4*)kg;
            uint4 k1 = *(const uint4*)(kg + 8);
            const unsigned short* vg = vg_base + kt * 64 + scol;
            uint4 v0 = *(const uint4*)vg;
            uint4 v1 = *(const uint4*)(vg + 8);
            *(uint4*)&Ks[srow * 72 + scol]     = k0;
            *(uint4*)&Ks[srow * 72 + scol + 8] = k1;
            *(uint4*)&Vs[srow * 72 + scol]     = v0;
            *(uint4*)&Vs[srow * 72 + scol + 8] = v1;
        }
        __syncthreads();

        // S^T: sacc[j][r] = S[q=l16][k = j*16 + quad*4 + r]
        f32x4 sacc[4];
#pragma unroll
        for (int j = 0; j < 4; j++) sacc[j] = (f32x4){0.f, 0.f, 0.f, 0.f};
#pragma unroll
        for (int ks = 0; ks < 2; ks++) {
#pragma unroll
            for (int j = 0; j < 4; j++) {
                bf16x8 kf = *(const bf16x8*)&Ks[(j * 16 + l16) * 72 + ks * 32 + quad * 8];
                sacc[j] = __builtin_amdgcn_mfma_f32_16x16x32_bf16(kf, qf[ks], sacc[j], 0, 0, 0);
            }
        }

        const unsigned long long mw = mb[kt];

        // masked, scaled scores + in-lane max
        float t[4][4];
        float mxj[4];
#pragma unroll
        for (int j = 0; j < 4; j++) {
            unsigned nib = (unsigned)(mw >> (quad * 4 + j * 16)) & 0xFu;
#pragma unroll
            for (int r = 0; r < 4; r++) {
                float s = sacc[j][r] * 0.125f;
                t[j][r] = ((nib >> r) & 1u) ? s : -1e30f;
            }
            mxj[j] = fmaxf(fmaxf(t[j][0], t[j][1]), fmaxf(t[j][2], t[j][3]));
        }
        float mx = fmaxf(fmaxf(mxj[0], mxj[1]), fmaxf(mxj[2], mxj[3]));
        // row max across the 4 quads holding this q-row
        mx = fmaxf(mx, __shfl_xor(mx, 16, 64));
        mx = fmaxf(mx, __shfl_xor(mx, 32, 64));

        // defer-max: only rescale O when some row's max actually grew (T13)
        if (!__all(mx <= m_run)) {
            float m_new = fmaxf(m_run, mx);
            float alpha = __expf(m_run - m_new);
            m_run = m_new;
            l_run *= alpha;
            // alpha lives in the l16 frame; oacc rows are q = quad*4 + r
            float al[4];
#pragma unroll
            for (int r = 0; r < 4; r++) al[r] = __shfl(alpha, quad * 4 + r, 64);
#pragma unroll
            for (int j = 0; j < 4; j++)
#pragma unroll
                for (int r = 0; r < 4; r++) oacc[j][r] *= al[r];
        }

        // p = exp(t - m), row-sum, pack into A-fragment (sigma order = own regs!)
        float p[4][4];
        float psj[4];
#pragma unroll
        for (int j = 0; j < 4; j++) {
#pragma unroll
            for (int r = 0; r < 4; r++) p[j][r] = __expf(t[j][r] - m_run);
            psj[j] = (p[j][0] + p[j][1]) + (p[j][2] + p[j][3]);
        }
        float ps = (psj[0] + psj[1]) + (psj[2] + psj[3]);
        ps += __shfl_xor(ps, 16, 64);
        ps += __shfl_xor(ps, 32, 64);
        l_run += ps;

        union { uint32_t u[4]; bf16x8 v; } pa[2];
#pragma unroll
        for (int ks = 0; ks < 2; ks++) {
            pa[ks].u[0] = cvt_pk_bf16(p[2 * ks][0],     p[2 * ks][1]);
            pa[ks].u[1] = cvt_pk_bf16(p[2 * ks][2],     p[2 * ks][3]);
            pa[ks].u[2] = cvt_pk_bf16(p[2 * ks + 1][0], p[2 * ks + 1][1]);
            pa[ks].u[3] = cvt_pk_bf16(p[2 * ks + 1][2], p[2 * ks + 1][3]);
        }

        // PV with sigma-permuted V reads: element e of B-frag = V[32ks + 16*(e/4) + 4*quad + e%4][d]
#pragma unroll
        for (int ks = 0; ks < 2; ks++) {
#pragma unroll
            for (int j = 0; j < 4; j++) {
                union { ushort4 u[2]; bf16x8 v; } vf;
                const unsigned short* vp = &Vs[(j * 16 + l16) * 72 + ks * 32 + quad * 4];
                vf.u[0] = *(const ushort4*)vp;
                vf.u[1] = *(const ushort4*)(vp + 16);
                oacc[j] = __builtin_amdgcn_mfma_f32_16x16x32_bf16(pa[ks].v, vf.v, oacc[j], 0, 0, 0);
            }
        }
    }

    // l_run lives in the l16 frame; output rows are q = quad*4 + r
    float inv[4];
#pragma unroll
    for (int r = 0; r < 4; r++) {
        float lr = __shfl(l_run, quad * 4 + r, 64);
        inv[r] = 1.f / lr;
    }
#pragma unroll
    for (int j = 0; j < 4; j++) {
#pragma unroll
        for (int r = 0; r < 4; r++) {
            size_t row = (size_t)(b * NSEQ + qt * 64 + w * 16 + quad * 4 + r);
            o[row * 1024 + h * 64 + j * 16 + l16] = f2bf(oacc[j][r] * inv[r]);
        }
    }
}

extern "C" void kernel_launch(void* const* d_in, const int* in_sizes, int n_in,
                              void* d_out, int out_size, void* d_ws, size_t ws_size,
                              hipStream_t stream) {
    const void* x     = d_in[0];
    const int*  mask  = (const int*)d_in[1];
    const void* ln1_g = d_in[2];
    const void* ln1_b = d_in[3];
    const void* qkv_w = d_in[4];
    const void* out_w = d_in[5];
    const void* out_b = d_in[6];
    const void* ln2_g = d_in[7];
    const void* ln2_b = d_in[8];
    const void* ff1_w = d_in[9];
    const void* ff1_b = d_in[10];
    const void* ff2_w = d_in[11];
    const void* ff2_b = d_in[12];

    char* ws = (char*)d_ws;
    float*          xf     = (float*)ws;                            // 8 MB fp32 residual
    unsigned short* h_bf   = (unsigned short*)(ws + (8u  << 20));   // 4 MB LN out
    unsigned short* qkv_bf = (unsigned short*)(ws + (12u << 20));   // 12 MB (attn half)
    unsigned short* ff_bf  = (unsigned short*)(ws + (12u << 20));   // 16 MB (ff half, reuses qkv+vt)
    unsigned short* vt_bf  = (unsigned short*)(ws + (24u << 20));   // 4 MB V^T (attn half)
    unsigned short* o_bf   = (unsigned short*)(ws + (28u << 20));   // 4 MB
    unsigned short* wT     = (unsigned short*)(ws + (32u << 20));   // 8 MB transposed weight
    unsigned short* vecs   = (unsigned short*)(ws + (40u << 20));   // 80 KB canonical vecs
    int*            flag   = (int*)(ws + (40u << 20) + (128u << 10));
    unsigned long long* mbits = (unsigned long long*)(ws + (40u << 20) + (192u << 10)); // 256 KB
    float*          slab   = (float*)(ws + (41u << 20));            // up to 32 MB split-K slabs

    const bool slabs_ok = ws_size >= (74ull << 20);

    sniff_kernel<<<1, 256, 0, stream>>>((const unsigned short*)x, flag);

    conv_all<<<dim3(64, 7), 256, 0, stream>>>(ln1_g, ln1_b, out_b, ln2_g, ln2_b, ff2_b, ff1_b,
                                              vecs, flag);
    mask_pack<<<512, 256, 0, stream>>>(mask, mbits);

    const int nx = MROWS * DIMM;  // 2M
    cvt_x<<<nx / 256, 256, 0, stream>>>(x, xf, flag);

    for (int l = 0; l < DEPTHN; l++) {
        const unsigned short* lv = vecs + l * VSTR;
        const unsigned short* lvn = vecs + (l + 1) * VSTR;  // next layer's vecs (l<3)

        // --- attention half ---
        if (l == 0)  // layers 1..3 get ln1 fused into the previous FF2 reduce
            ln_kernel<<<MROWS, 256, 0, stream>>>(xf, lv + 0, lv + 1024, h_bf);
        transpose_conv<<<dim3(3072 / 32, 1024 / 32), dim3(32, 8), 0, stream>>>(
            qkv_w, (size_t)l * 1024 * 3072, wT, 1024, 3072, flag);
        gemm_bt<0, 1><<<dim3(3072 / 128, MROWS / 128), 512, 0, stream>>>(
            h_bf, wT, nullptr, qkv_bf, nullptr, MROWS, 3072, 1024);
        vt_kernel<<<dim3(32, 32, BB), dim3(32, 8), 0, stream>>>(qkv_bf, vt_bf);
        attn_mfma<<<dim3(NSEQ / 64, HEADSN, BB), 256, 0, stream>>>(qkv_bf, vt_bf, mbits, o_bf);
        transpose_conv<<<dim3(1024 / 32, 1024 / 32), dim3(32, 8), 0, stream>>>(
            out_w, (size_t)l * 1024 * 1024, wT, 1024, 1024, flag);
        if (slabs_ok) {
            gemm_bt<3, 2><<<dim3(1024 / 128, MROWS / 128, 2), 512, 0, stream>>>(
                o_bf, wT, nullptr, nullptr, slab, MROWS, 1024, 1024);
            reduce_ln<2, 1><<<MROWS, 256, 0, stream>>>(
                slab, lv + 2048, xf, lv + 3072, lv + 4096, h_bf);
        } else {
            gemm_bt<1, 2><<<dim3(1024 / 128, MROWS / 128, 2), 512, 0, stream>>>(
                o_bf, wT, lv + 2048, nullptr, xf, MROWS, 1024, 1024);
            ln_kernel<<<MROWS, 256, 0, stream>>>(xf, lv + 3072, lv + 4096, h_bf);
        }

        // --- feedforward half ---
        transpose_conv<<<dim3(4096 / 32, 1024 / 32), dim3(32, 8), 0, stream>>>(
            ff1_w, (size_t)l * 1024 * 4096, wT, 1024, 4096, flag);
        gemm_bt<2, 1><<<dim3(4096 / 128, MROWS / 128), 512, 0, stream>>>(
            h_bf, wT, lv + 6144, ff_bf, nullptr, MROWS, 4096, 1024);
        transpose_conv<<<dim3(1024 / 32, 4096 / 32), dim3(32, 8), 0, stream>>>(
            ff2_w, (size_t)l * 4096 * 1024, wT, 4096, 1024, flag);
        if (slabs_ok) {
            gemm_bt<3, 4><<<dim3(1024 / 128, MROWS / 128, 4), 512, 0, stream>>>(
                ff_bf, wT, nullptr, nullptr, slab, MROWS, 1024, 4096);
            if (l < DEPTHN - 1)
                reduce_ln<4, 1><<<MROWS, 256, 0, stream>>>(
                    slab, lv + 5120, xf, lvn + 0, lvn + 1024, h_bf);
            else
                reduce_ln<4, 0><<<MROWS, 256, 0, stream>>>(
                    slab, lv + 5120, xf, nullptr, nullptr, nullptr);
        } else {
            gemm_bt<1, 4><<<dim3(1024 / 128, MROWS / 128, 4), 512, 0, stream>>>(
                ff_bf, wT, lv + 5120, nullptr, xf, MROWS, 1024, 4096);
            if (l < DEPTHN - 1)
                ln_kernel<<<MROWS, 256, 0, stream>>>(xf, lvn + 0, lvn + 1024, h_bf);
        }
    }

    store_out<<<nx / 256, 256, 0, stream>>>(xf, d_out, flag);
}

// Round 3
// 888.238 us; speedup vs baseline: 1.1728x; 1.0539x over previous
//
#include <hip/hip_runtime.h>
#include <stdint.h>

#define DIMM 1024
#define NSEQ 1024
#define BB 2
#define HEADSN 16
#define MLPD 4096
#define DEPTHN 4
#define MROWS (BB*NSEQ)  // 2048
#define VSTR 10240       // canonical per-layer vec stride (elements)

typedef __bf16 bf16x8 __attribute__((ext_vector_type(8)));
typedef float f32x4 __attribute__((ext_vector_type(4)));

__device__ __forceinline__ float bf2f(unsigned short u) {
    union { uint32_t i; float f; } x; x.i = ((uint32_t)u) << 16; return x.f;
}
__device__ __forceinline__ unsigned short f2bf(float f) {
    union { uint32_t i; float f; } x; x.f = f;
    uint32_t r = x.i + 0x7fffu + ((x.i >> 16) & 1u);
    return (unsigned short)(r >> 16);
}
__device__ __forceinline__ float loadf(const void* p, size_t i, int f32) {
    return f32 ? ((const float*)p)[i] : bf2f(((const unsigned short*)p)[i]);
}
// packed f32x2 -> bf16x2 (RNE), single HW instruction on gfx950
__device__ __forceinline__ uint32_t cvt_pk_bf16(float lo, float hi) {
    uint32_t r;
    asm("v_cvt_pk_bf16_f32 %0, %1, %2" : "=v"(r) : "v"(lo), "v"(hi));
    return r;
}

// async global->LDS, 16B per lane; LDS dest = wave-uniform base + lane*16
__device__ __forceinline__ void gl_lds16(const unsigned short* g, unsigned short* l) {
    __builtin_amdgcn_global_load_lds(
        (const __attribute__((address_space(1))) uint32_t*)g,
        (__attribute__((address_space(3))) uint32_t*)l,
        16, 0, 0);
}

// counted vmcnt waits (keep next-tile loads in flight across barriers)
__device__ __forceinline__ void wait_vm2() { asm volatile("s_waitcnt vmcnt(2)" ::: "memory"); }
__device__ __forceinline__ void wait_vm0() { asm volatile("s_waitcnt vmcnt(0)" ::: "memory"); }
// raw barrier fenced so the compiler can't move LDS reads across it
__device__ __forceinline__ void barrier_sync() {
    asm volatile("" ::: "memory");
    __builtin_amdgcn_s_barrier();
    asm volatile("" ::: "memory");
}

// ---------------- dtype sniff ----------------
__global__ __launch_bounds__(256) void sniff_kernel(const unsigned short* __restrict__ x,
                                                    int* __restrict__ flag) {
    __shared__ int cnt[256];
    int tid = threadIdx.x;
    int c = 0;
    for (int i = tid * 2; i < 65536; i += 512) {
        int e = (x[i] >> 7) & 0xFF;
        if (e >= 0x8A) c++;
    }
    cnt[tid] = c;
    __syncthreads();
    for (int s = 128; s > 0; s >>= 1) {
        if (tid < s) cnt[tid] += cnt[tid + s];
        __syncthreads();
    }
    if (tid == 0) flag[0] = (cnt[0] > 32) ? 1 : 0;
}

// ---------------- converts ----------------
__global__ __launch_bounds__(256) void cvt_x(const void* __restrict__ x, float* __restrict__ xf,
                                             const int* __restrict__ flag) {
    int f = flag[0];
    int i = blockIdx.x * 256 + threadIdx.x;
    xf[i] = loadf(x, i, f);
}
__global__ __launch_bounds__(256) void store_out(const float* __restrict__ xf, void* __restrict__ out,
                                                 const int* __restrict__ flag) {
    int f = flag[0];
    int i = blockIdx.x * 256 + threadIdx.x;
    float v = xf[i];
    if (f) ((float*)out)[i] = v;
    else   ((unsigned short*)out)[i] = f2bf(v);
}
// all 7 small vectors in one launch; grid (64, 7)
__global__ __launch_bounds__(256) void conv_all(const void* s0, const void* s1, const void* s2,
                                                const void* s3, const void* s4, const void* s5,
                                                const void* s6, unsigned short* __restrict__ dst,
                                                const int* __restrict__ flag) {
    int f = flag[0];
    const void* src; int len, off;
    switch (blockIdx.y) {
        case 0: src = s0; len = 1024; off = 0;    break;
        case 1: src = s1; len = 1024; off = 1024; break;
        case 2: src = s2; len = 1024; off = 2048; break;
        case 3: src = s3; len = 1024; off = 3072; break;
        case 4: src = s4; len = 1024; off = 4096; break;
        case 5: src = s5; len = 1024; off = 5120; break;
        default: src = s6; len = 4096; off = 6144; break;
    }
    int i = blockIdx.x * 256 + threadIdx.x;
    if (i < DEPTHN * len) {
        int l = i / len, o = i - l * len;
        dst[l * VSTR + off + o] = f2bf(loadf(src, i, f));
    }
}

// ---------------- transpose+convert: src[srcOffE + k*N + n] -> bf16 out[n*K + k] ----------------
__global__ __launch_bounds__(256) void transpose_conv(const void* __restrict__ in, size_t srcOffE,
                                                      unsigned short* __restrict__ out,
                                                      int K, int N, const int* __restrict__ flag) {
    int f = flag[0];
    __shared__ unsigned short t[32][33];
    int n0 = blockIdx.x * 32, k0 = blockIdx.y * 32;
    int tx = threadIdx.x, ty = threadIdx.y;  // 32 x 8
#pragma unroll
    for (int i = 0; i < 4; i++) {
        int k = k0 + ty + i * 8;
        t[ty + i * 8][tx] = f2bf(loadf(in, srcOffE + (size_t)k * N + n0 + tx, f));
    }
    __syncthreads();
#pragma unroll
    for (int i = 0; i < 4; i++) {
        int n = n0 + ty + i * 8;
        out[(size_t)n * K + k0 + tx] = t[tx][ty + i * 8];
    }
}

// ---------------- V^T per layer ----------------
__global__ __launch_bounds__(256) void vt_kernel(const unsigned short* __restrict__ qkv,
                                                 unsigned short* __restrict__ vt) {
    __shared__ unsigned short t[32][33];
    int b = blockIdx.z;
    int c0 = blockIdx.x * 32, k0 = blockIdx.y * 32;
    int tx = threadIdx.x, ty = threadIdx.y;  // 32 x 8
#pragma unroll
    for (int i = 0; i < 4; i++) {
        int k = k0 + ty + i * 8;
        t[ty + i * 8][tx] = qkv[(size_t)(b * 1024 + k) * 3072 + 2048 + c0 + tx];
    }
    __syncthreads();
#pragma unroll
    for (int i = 0; i < 4; i++) {
        int c = c0 + ty + i * 8;
        vt[(size_t)(b * 1024 + c) * 1024 + k0 + tx] = t[tx][ty + i * 8];
    }
}

// ---------------- mask -> bitmask u64 words ----------------
__global__ __launch_bounds__(256) void mask_pack(const int* __restrict__ mask,
                                                 unsigned long long* __restrict__ bits) {
    int wid = (blockIdx.x * 256 + threadIdx.x) >> 6;
    int lane = threadIdx.x & 63;
#pragma unroll
    for (int i = 0; i < 16; i++) {
        int w = wid * 16 + i;
        int mv = mask[(size_t)w * 64 + lane];
        unsigned long long bl = __ballot(mv != 0);
        if (lane == 0) bits[w] = bl;
    }
}

// ---------------- LayerNorm (standalone; only for the first pre-attn LN) ----------------
__global__ __launch_bounds__(256) void ln_kernel(const float* __restrict__ x,
                                                 const unsigned short* __restrict__ g,
                                                 const unsigned short* __restrict__ bta,
                                                 unsigned short* __restrict__ out) {
    int row = blockIdx.x, tid = threadIdx.x;
    const float* xr = x + (size_t)row * DIMM;
    float v[4]; float s = 0.f, s2 = 0.f;
#pragma unroll
    for (int i = 0; i < 4; i++) { v[i] = xr[tid + i * 256]; s += v[i]; s2 += v[i] * v[i]; }
#pragma unroll
    for (int off = 32; off >= 1; off >>= 1) {
        s  += __shfl_down(s, off, 64);
        s2 += __shfl_down(s2, off, 64);
    }
    __shared__ float rs[4], rs2[4];
    int wv = tid >> 6;
    if ((tid & 63) == 0) { rs[wv] = s; rs2[wv] = s2; }
    __syncthreads();
    s  = rs[0] + rs[1] + rs[2] + rs[3];
    s2 = rs2[0] + rs2[1] + rs2[2] + rs2[3];
    float mu  = s * (1.f / DIMM);
    float var = s2 * (1.f / DIMM) - mu * mu;
    float rr  = rsqrtf(var + 1e-5f);
#pragma unroll
    for (int i = 0; i < 4; i++) {
        int c = tid + i * 256;
        float y = (v[i] - mu) * rr * bf2f(g[c]) + bf2f(bta[c]);
        out[(size_t)row * DIMM + c] = f2bf(y);
    }
}

// ---------------- split-K slab reduce + residual update (+ optional fused LN) ----------------
// xf[row] += bias + sum_z slab[z][row]; optionally LayerNorm(result) -> out (bf16).
template <int S, int HAS_LN>
__global__ __launch_bounds__(256) void reduce_ln(const float* __restrict__ slab,
                                                 const unsigned short* __restrict__ bias,
                                                 float* __restrict__ xf,
                                                 const unsigned short* __restrict__ g,
                                                 const unsigned short* __restrict__ bta,
                                                 unsigned short* __restrict__ out) {
    const size_t SL = (size_t)MROWS * DIMM;
    int row = blockIdx.x, tid = threadIdx.x;
    float v[4]; float s = 0.f, s2 = 0.f;
#pragma unroll
    for (int i = 0; i < 4; i++) {
        int c = tid + i * 256;
        size_t idx = (size_t)row * DIMM + c;
        float t = xf[idx] + bf2f(bias[c]);
#pragma unroll
        for (int z = 0; z < S; z++) t += slab[z * SL + idx];
        xf[idx] = t;
        v[i] = t; s += t; s2 += t * t;
    }
    if (HAS_LN) {
#pragma unroll
        for (int off = 32; off >= 1; off >>= 1) {
            s  += __shfl_down(s, off, 64);
            s2 += __shfl_down(s2, off, 64);
        }
        __shared__ float rs[4], rs2[4];
        int wv = tid >> 6;
        if ((tid & 63) == 0) { rs[wv] = s; rs2[wv] = s2; }
        __syncthreads();
        s  = rs[0] + rs[1] + rs[2] + rs[3];
        s2 = rs2[0] + rs2[1] + rs2[2] + rs2[3];
        float mu  = s * (1.f / DIMM);
        float var = s2 * (1.f / DIMM) - mu * mu;
        float rr  = rsqrtf(var + 1e-5f);
#pragma unroll
        for (int i = 0; i < 4; i++) {
            int c = tid + i * 256;
            float y = (v[i] - mu) * rr * bf2f(g[c]) + bf2f(bta[c]);
            out[(size_t)row * DIMM + c] = f2bf(y);
        }
    }
}

// ---------------- GEMM (8-wave 128x128 tile, swizzled LDS, double-buffered pipeline) ----------------
// 512 threads = 8 waves; wave-tile 64x32 (wm=(w>>2)*64, wn=(w&3)*32).
// Staging: waves 0-3 stage A rows, waves 4-7 stage B; 2x gl_lds16 (= 2 vmem ops) per wave per tile.
// Double-buffered K-loop with COUNTED vmcnt (T3+T4): stage(t+1) issues before compute(t);
// s_waitcnt vmcnt(2) waits only for tile t's loads (the 2 newest outstanding = tile t+1's),
// raw s_barrier (no vmcnt(0) drain).  Barrier #1 = tile-ready, barrier #2 = reads-done
// (so next stage may overwrite).  LDS XOR swizzle unchanged from R1 (both-sides, linear dest).
// MODE 0: store bf16 C       MODE 1: Cres(fp32) atomic += acc(+bias@z0)  [fallback]
// MODE 2: bf16 gelu(acc+bias) MODE 3: slab[z] = acc (fp32, pure stores)
template <int MODE, int SPLITK>
__global__ __launch_bounds__(512) void gemm_bt(const unsigned short* __restrict__ A,
                                               const unsigned short* __restrict__ Bt,
                                               const unsigned short* __restrict__ bias,
                                               unsigned short* __restrict__ Cbf,
                                               float* __restrict__ Cres,
                                               int M, int N, int K) {
    __shared__ __align__(16) unsigned short As0[128 * 32];
    __shared__ __align__(16) unsigned short As1[128 * 32];
    __shared__ __align__(16) unsigned short Bs0[128 * 32];
    __shared__ __align__(16) unsigned short Bs1[128 * 32];
    const int tid = threadIdx.x;
    const int mBase = blockIdx.y * 128, nBase = blockIdx.x * 128;
    const int w = tid >> 6, lane = tid & 63;
    const int wm = (w >> 2) * 64, wn = (w & 3) * 32;
    const int quad = lane >> 4, l16 = lane & 15;
    const int kLen = K / SPLITK;
    const int kStart = (SPLITK > 1) ? blockIdx.z * kLen : 0;
    const int NT = kLen / 32;  // always even here (8/16/32)

    f32x4 acc[4][2];
#pragma unroll
    for (int i = 0; i < 4; i++)
#pragma unroll
        for (int j = 0; j < 2; j++) acc[i][j] = (f32x4){0.f, 0.f, 0.f, 0.f};

    // staging: 16B/lane, LDS dest linear (base + lane*16); source column pre-swizzled.
    const int lr = lane >> 2;
    const int lc = ((lane & 3) ^ ((lr >> 1) & 3)) * 8;  // swizzled source col (elements)
    const int wb = w & 3;
    const unsigned short* G = (w < 4 ? A  + (size_t)(mBase + wb * 32 + lr) * K
                                     : Bt + (size_t)(nBase + wb * 32 + lr) * K)
                              + kStart + lc;
    unsigned short* L0a = (w < 4 ? &As0[(wb * 32) * 32] : &Bs0[(wb * 32) * 32]);
    unsigned short* L1a = L0a + 16 * 32;
    unsigned short* L0b = (w < 4 ? &As1[(wb * 32) * 32] : &Bs1[(wb * 32) * 32]);
    unsigned short* L1b = L0b + 16 * 32;
    const size_t rstep = (size_t)16 * K;

    const int rcb = (quad ^ ((l16 >> 1) & 3)) * 8;  // swizzled read col (elements)

    auto compute_t = [&](const unsigned short* Asb, const unsigned short* Bsb) {
        bf16x8 af[4], bfv[2];
#pragma unroll
        for (int i = 0; i < 4; i++)
            af[i] = *(const bf16x8*)&Asb[(wm + i * 16 + l16) * 32 + rcb];
#pragma unroll
        for (int j = 0; j < 2; j++)
            bfv[j] = *(const bf16x8*)&Bsb[(wn + j * 16 + l16) * 32 + rcb];
#pragma unroll
        for (int i = 0; i < 4; i++)
#pragma unroll
            for (int j = 0; j < 2; j++)
                acc[i][j] = __builtin_amdgcn_mfma_f32_16x16x32_bf16(af[i], bfv[j], acc[i][j], 0, 0, 0);
    };

    // prologue: stage tile 0 -> buf0
    gl_lds16(G, L0a);
    gl_lds16(G + rstep, L1a);

    for (int t = 0; t < NT; t += 2) {
        // phase 0: stage t+1 -> buf1, compute buf0   (t+1 < NT always: NT even)
        gl_lds16(G + (size_t)(t + 1) * 32,         L0b);
        gl_lds16(G + (size_t)(t + 1) * 32 + rstep, L1b);
        wait_vm2();       // my tile-t loads landed (2 newest = tile t+1, still in flight)
        barrier_sync();   // everyone's tile-t loads landed
        compute_t(As0, Bs0);
        barrier_sync();   // all reads of buf0 done -> buf0 may be overwritten
        // phase 1: stage t+2 -> buf0 (if any), compute buf1
        if (t + 2 < NT) {
            gl_lds16(G + (size_t)(t + 2) * 32,         L0a);
            gl_lds16(G + (size_t)(t + 2) * 32 + rstep, L1a);
            wait_vm2();
        } else {
            wait_vm0();
        }
        barrier_sync();
        compute_t(As1, Bs1);
        barrier_sync();
    }

    const size_t slabOff = (MODE == 3) ? (size_t)blockIdx.z * M * N : 0;
#pragma unroll
    for (int i = 0; i < 4; i++) {
#pragma unroll
        for (int j = 0; j < 2; j++) {
#pragma unroll
            for (int r = 0; r < 4; r++) {
                int m = mBase + wm + i * 16 + quad * 4 + r;
                int n = nBase + wn + j * 16 + l16;
                float v = acc[i][j][r];
                size_t idx = (size_t)m * N + n;
                if (MODE == 0) {
                    Cbf[idx] = f2bf(v);
                } else if (MODE == 1) {
                    if (SPLITK > 1) {
                        if (blockIdx.z == 0) v += bf2f(bias[n]);
                        atomicAdd(&Cres[idx], v);
                    } else {
                        Cres[idx] += v + bf2f(bias[n]);
                    }
                } else if (MODE == 2) {
                    float t2 = v + bf2f(bias[n]);
                    float gg = 0.5f * t2 * (1.f + erff(t2 * 0.70710678118f));
                    Cbf[idx] = f2bf(gg);
                } else {
                    Cres[slabOff + idx] = v;
                }
            }
        }
    }
}

// ---------------- MFMA flash attention (swapped-QK, in-register P) ----------------
// S^T = mfma(K_frag, Q_frag): each lane owns ONE q-row (q = w*16 + l16) and holds
// 16 scores of the 64-key tile: k = j*16 + quad*4 + r.  Row softmax is therefore
// 15 in-lane ops + 2 shfl_xor (across quads) instead of 16 serial shuffles.
// PV uses a k-permutation sigma(8q+e) = 16*(e/4) + 4q + e%4 applied to BOTH operands:
// the A-fragment is the lane's own p-values packed in-register (no cross-lane moves,
// no Ps LDS round trip), and V is read as two ds_read_b64 per fragment at
// k = 32ks+4*quad and +16 (uniform 2 dwords/bank -> conflict-free).
__global__ __launch_bounds__(256) void attn_mfma(const unsigned short* __restrict__ qkv,
                                                 const unsigned short* __restrict__ vt,
                                                 const unsigned long long* __restrict__ mbits,
                                                 unsigned short* __restrict__ o) {
    __shared__ __align__(16) unsigned short Ks[64 * 72];
    __shared__ __align__(16) unsigned short Vs[64 * 72];

    const int tid = threadIdx.x, w = tid >> 6, lane = tid & 63;
    const int quad = lane >> 4, l16 = lane & 15;
    const int qt = blockIdx.x, h = blockIdx.y, b = blockIdx.z;

    // Q fragment = B-operand of S^T: lane holds Q[q=l16][d = ks*32 + quad*8 + e]
    const size_t qrow = (size_t)(b * NSEQ + qt * 64 + w * 16 + l16) * 3072 + h * 64;
    bf16x8 qf[2];
    qf[0] = *(const bf16x8*)(qkv + qrow + quad * 8);
    qf[1] = *(const bf16x8*)(qkv + qrow + 32 + quad * 8);

    const int srow = tid >> 2, scol = (tid & 3) * 16;
    const unsigned short* kg_base = qkv + (size_t)(b * NSEQ) * 3072 + 1024 + h * 64;
    const unsigned short* vg_base = vt + (size_t)((b * HEADSN + h) * 64 + srow) * 1024;

    f32x4 oacc[4];
#pragma unroll
    for (int j = 0; j < 4; j++) oacc[j] = (f32x4){0.f, 0.f, 0.f, 0.f};
    // per-lane row state for q = w*16 + l16 (replicated across the 4 quads)
    float m_run = -1e30f, l_run = 0.f;

    // one mask word per kt: bits 0..63 = keep flags for this lane's q-row
    const unsigned long long* mb = mbits + ((size_t)(b * NSEQ + qt * 64 + w * 16 + l16)) * 16;

    for (int kt = 0; kt < 16; kt++) {
        __syncthreads();
        {
            const unsigned short* kg = kg_base + (size_t)(kt * 64 + srow) * 3072 + scol;
            uint4 k0 = *(const uint4*)kg;
            uint4 k1 = *(const uint4*)(kg + 8);
            const unsigned short* vg = vg_base + kt * 64 + scol;
            uint4 v0 = *(const uint4*)vg;
            uint4 v1 = *(const uint4*)(vg + 8);
            *(uint4*)&Ks[srow * 72 + scol]     = k0;
            *(uint4*)&Ks[srow * 72 + scol + 8] = k1;
            *(uint4*)&Vs[srow * 72 + scol]     = v0;
            *(uint4*)&Vs[srow * 72 + scol + 8] = v1;
        }
        __syncthreads();

        // S^T: sacc[j][r] = S[q=l16][k = j*16 + quad*4 + r]
        f32x4 sacc[4];
#pragma unroll
        for (int j = 0; j < 4; j++) sacc[j] = (f32x4){0.f, 0.f, 0.f, 0.f};
#pragma unroll
        for (int ks = 0; ks < 2; ks++) {
#pragma unroll
            for (int j = 0; j < 4; j++) {
                bf16x8 kf = *(const bf16x8*)&Ks[(j * 16 + l16) * 72 + ks * 32 + quad * 8];
                sacc[j] = __builtin_amdgcn_mfma_f32_16x16x32_bf16(kf, qf[ks], sacc[j], 0, 0, 0);
            }
        }

        const unsigned long long mw = mb[kt];

        // masked, scaled scores + in-lane max
        float t[4][4];
        float mxj[4];
#pragma unroll
        for (int j = 0; j < 4; j++) {
            unsigned nib = (unsigned)(mw >> (quad * 4 + j * 16)) & 0xFu;
#pragma unroll
            for (int r = 0; r < 4; r++) {
                float s = sacc[j][r] * 0.125f;
                t[j][r] = ((nib >> r) & 1u) ? s : -1e30f;
            }
            mxj[j] = fmaxf(fmaxf(t[j][0], t[j][1]), fmaxf(t[j][2], t[j][3]));
        }
        float mx = fmaxf(fmaxf(mxj[0], mxj[1]), fmaxf(mxj[2], mxj[3]));
        // row max across the 4 quads holding this q-row
        mx = fmaxf(mx, __shfl_xor(mx, 16, 64));
        mx = fmaxf(mx, __shfl_xor(mx, 32, 64));

        // defer-max: only rescale O when some row's max actually grew (T13)
        if (!__all(mx <= m_run)) {
            float m_new = fmaxf(m_run, mx);
            float alpha = __expf(m_run - m_new);
            m_run = m_new;
            l_run *= alpha;
            // alpha lives in the l16 frame; oacc rows are q = quad*4 + r
            float al[4];
#pragma unroll
            for (int r = 0; r < 4; r++) al[r] = __shfl(alpha, quad * 4 + r, 64);
#pragma unroll
            for (int j = 0; j < 4; j++)
#pragma unroll
                for (int r = 0; r < 4; r++) oacc[j][r] *= al[r];
        }

        // p = exp(t - m), row-sum, pack into A-fragment (sigma order = own regs!)
        float p[4][4];
        float psj[4];
#pragma unroll
        for (int j = 0; j < 4; j++) {
#pragma unroll
            for (int r = 0; r < 4; r++) p[j][r] = __expf(t[j][r] - m_run);
            psj[j] = (p[j][0] + p[j][1]) + (p[j][2] + p[j][3]);
        }
        float ps = (psj[0] + psj[1]) + (psj[2] + psj[3]);
        ps += __shfl_xor(ps, 16, 64);
        ps += __shfl_xor(ps, 32, 64);
        l_run += ps;

        union { uint32_t u[4]; bf16x8 v; } pa[2];
#pragma unroll
        for (int ks = 0; ks < 2; ks++) {
            pa[ks].u[0] = cvt_pk_bf16(p[2 * ks][0],     p[2 * ks][1]);
            pa[ks].u[1] = cvt_pk_bf16(p[2 * ks][2],     p[2 * ks][3]);
            pa[ks].u[2] = cvt_pk_bf16(p[2 * ks + 1][0], p[2 * ks + 1][1]);
            pa[ks].u[3] = cvt_pk_bf16(p[2 * ks + 1][2], p[2 * ks + 1][3]);
        }

        // PV with sigma-permuted V reads: element e of B-frag = V[32ks + 16*(e/4) + 4*quad + e%4][d]
#pragma unroll
        for (int ks = 0; ks < 2; ks++) {
#pragma unroll
            for (int j = 0; j < 4; j++) {
                union { ushort4 u[2]; bf16x8 v; } vf;
                const unsigned short* vp = &Vs[(j * 16 + l16) * 72 + ks * 32 + quad * 4];
                vf.u[0] = *(const ushort4*)vp;
                vf.u[1] = *(const ushort4*)(vp + 16);
                oacc[j] = __builtin_amdgcn_mfma_f32_16x16x32_bf16(pa[ks].v, vf.v, oacc[j], 0, 0, 0);
            }
        }
    }

    // l_run lives in the l16 frame; output rows are q = quad*4 + r
    float inv[4];
#pragma unroll
    for (int r = 0; r < 4; r++) {
        float lr = __shfl(l_run, quad * 4 + r, 64);
        inv[r] = 1.f / lr;
    }
#pragma unroll
    for (int j = 0; j < 4; j++) {
#pragma unroll
        for (int r = 0; r < 4; r++) {
            size_t row = (size_t)(b * NSEQ + qt * 64 + w * 16 + quad * 4 + r);
            o[row * 1024 + h * 64 + j * 16 + l16] = f2bf(oacc[j][r] * inv[r]);
        }
    }
}

extern "C" void kernel_launch(void* const* d_in, const int* in_sizes, int n_in,
                              void* d_out, int out_size, void* d_ws, size_t ws_size,
                              hipStream_t stream) {
    const void* x     = d_in[0];
    const int*  mask  = (const int*)d_in[1];
    const void* ln1_g = d_in[2];
    const void* ln1_b = d_in[3];
    const void* qkv_w = d_in[4];
    const void* out_w = d_in[5];
    const void* out_b = d_in[6];
    const void* ln2_g = d_in[7];
    const void* ln2_b = d_in[8];
    const void* ff1_w = d_in[9];
    const void* ff1_b = d_in[10];
    const void* ff2_w = d_in[11];
    const void* ff2_b = d_in[12];

    char* ws = (char*)d_ws;
    float*          xf     = (float*)ws;                            // 8 MB fp32 residual
    unsigned short* h_bf   = (unsigned short*)(ws + (8u  << 20));   // 4 MB LN out
    unsigned short* qkv_bf = (unsigned short*)(ws + (12u << 20));   // 12 MB (attn half)
    unsigned short* ff_bf  = (unsigned short*)(ws + (12u << 20));   // 16 MB (ff half, reuses qkv+vt)
    unsigned short* vt_bf  = (unsigned short*)(ws + (24u << 20));   // 4 MB V^T (attn half)
    unsigned short* o_bf   = (unsigned short*)(ws + (28u << 20));   // 4 MB
    unsigned short* wT     = (unsigned short*)(ws + (32u << 20));   // 8 MB transposed weight
    unsigned short* vecs   = (unsigned short*)(ws + (40u << 20));   // 80 KB canonical vecs
    int*            flag   = (int*)(ws + (40u << 20) + (128u << 10));
    unsigned long long* mbits = (unsigned long long*)(ws + (40u << 20) + (192u << 10)); // 256 KB
    float*          slab   = (float*)(ws + (41u << 20));            // up to 32 MB split-K slabs

    const bool slabs_ok = ws_size >= (74ull << 20);

    sniff_kernel<<<1, 256, 0, stream>>>((const unsigned short*)x, flag);

    conv_all<<<dim3(64, 7), 256, 0, stream>>>(ln1_g, ln1_b, out_b, ln2_g, ln2_b, ff2_b, ff1_b,
                                              vecs, flag);
    mask_pack<<<512, 256, 0, stream>>>(mask, mbits);

    const int nx = MROWS * DIMM;  // 2M
    cvt_x<<<nx / 256, 256, 0, stream>>>(x, xf, flag);

    for (int l = 0; l < DEPTHN; l++) {
        const unsigned short* lv = vecs + l * VSTR;
        const unsigned short* lvn = vecs + (l + 1) * VSTR;  // next layer's vecs (l<3)

        // --- attention half ---
        if (l == 0)  // layers 1..3 get ln1 fused into the previous FF2 reduce
            ln_kernel<<<MROWS, 256, 0, stream>>>(xf, lv + 0, lv + 1024, h_bf);
        transpose_conv<<<dim3(3072 / 32, 1024 / 32), dim3(32, 8), 0, stream>>>(
            qkv_w, (size_t)l * 1024 * 3072, wT, 1024, 3072, flag);
        gemm_bt<0, 1><<<dim3(3072 / 128, MROWS / 128), 512, 0, stream>>>(
            h_bf, wT, nullptr, qkv_bf, nullptr, MROWS, 3072, 1024);
        vt_kernel<<<dim3(32, 32, BB), dim3(32, 8), 0, stream>>>(qkv_bf, vt_bf);
        attn_mfma<<<dim3(NSEQ / 64, HEADSN, BB), 256, 0, stream>>>(qkv_bf, vt_bf, mbits, o_bf);
        transpose_conv<<<dim3(1024 / 32, 1024 / 32), dim3(32, 8), 0, stream>>>(
            out_w, (size_t)l * 1024 * 1024, wT, 1024, 1024, flag);
        if (slabs_ok) {
            gemm_bt<3, 2><<<dim3(1024 / 128, MROWS / 128, 2), 512, 0, stream>>>(
                o_bf, wT, nullptr, nullptr, slab, MROWS, 1024, 1024);
            reduce_ln<2, 1><<<MROWS, 256, 0, stream>>>(
                slab, lv + 2048, xf, lv + 3072, lv + 4096, h_bf);
        } else {
            gemm_bt<1, 2><<<dim3(1024 / 128, MROWS / 128, 2), 512, 0, stream>>>(
                o_bf, wT, lv + 2048, nullptr, xf, MROWS, 1024, 1024);
            ln_kernel<<<MROWS, 256, 0, stream>>>(xf, lv + 3072, lv + 4096, h_bf);
        }

        // --- feedforward half ---
        transpose_conv<<<dim3(4096 / 32, 1024 / 32), dim3(32, 8), 0, stream>>>(
            ff1_w, (size_t)l * 1024 * 4096, wT, 1024, 4096, flag);
        gemm_bt<2, 1><<<dim3(4096 / 128, MROWS / 128), 512, 0, stream>>>(
            h_bf, wT, lv + 6144, ff_bf, nullptr, MROWS, 4096, 1024);
        transpose_conv<<<dim3(1024 / 32, 4096 / 32), dim3(32, 8), 0, stream>>>(
            ff2_w, (size_t)l * 4096 * 1024, wT, 4096, 1024, flag);
        if (slabs_ok) {
            gemm_bt<3, 4><<<dim3(1024 / 128, MROWS / 128, 4), 512, 0, stream>>>(
                ff_bf, wT, nullptr, nullptr, slab, MROWS, 1024, 4096);
            if (l < DEPTHN - 1)
                reduce_ln<4, 1><<<MROWS, 256, 0, stream>>>(
                    slab, lv + 5120, xf, lvn + 0, lvn + 1024, h_bf);
            else
                reduce_ln<4, 0><<<MROWS, 256, 0, stream>>>(
                    slab, lv + 5120, xf, nullptr, nullptr, nullptr);
        } else {
            gemm_bt<1, 4><<<dim3(1024 / 128, MROWS / 128, 4), 512, 0, stream>>>(
                ff_bf, wT, lv + 5120, nullptr, xf, MROWS, 1024, 4096);
            if (l < DEPTHN - 1)
                ln_kernel<<<MROWS, 256, 0, stream>>>(xf, lvn + 0, lvn + 1024, h_bf);
        }
    }

    store_out<<<nx / 256, 256, 0, stream>>>(xf, d_out, flag);
}

// Round 4
// 843.409 us; speedup vs baseline: 1.2351x; 1.0532x over previous
//
#include <hip/hip_runtime.h>
#include <stdint.h>

#define DIMM 1024
#define NSEQ 1024
#define BB 2
#define HEADSN 16
#define MLPD 4096
#define DEPTHN 4
#define MROWS (BB*NSEQ)  // 2048
#define VSTR 10240       // canonical per-layer vec stride (elements)

typedef __bf16 bf16x8 __attribute__((ext_vector_type(8)));
typedef float f32x4 __attribute__((ext_vector_type(4)));

__device__ __forceinline__ float bf2f(unsigned short u) {
    union { uint32_t i; float f; } x; x.i = ((uint32_t)u) << 16; return x.f;
}
__device__ __forceinline__ unsigned short f2bf(float f) {
    union { uint32_t i; float f; } x; x.f = f;
    uint32_t r = x.i + 0x7fffu + ((x.i >> 16) & 1u);
    return (unsigned short)(r >> 16);
}
__device__ __forceinline__ float loadf(const void* p, size_t i, int f32) {
    return f32 ? ((const float*)p)[i] : bf2f(((const unsigned short*)p)[i]);
}
// packed f32x2 -> bf16x2 (RNE), single HW instruction on gfx950
__device__ __forceinline__ uint32_t cvt_pk_bf16(float lo, float hi) {
    uint32_t r;
    asm("v_cvt_pk_bf16_f32 %0, %1, %2" : "=v"(r) : "v"(lo), "v"(hi));
    return r;
}

// async global->LDS, 16B per lane; LDS dest = wave-uniform base + lane*16
__device__ __forceinline__ void gl_lds16(const unsigned short* g, unsigned short* l) {
    __builtin_amdgcn_global_load_lds(
        (const __attribute__((address_space(1))) uint32_t*)g,
        (__attribute__((address_space(3))) uint32_t*)l,
        16, 0, 0);
}

// counted vmcnt waits (keep next-tile loads in flight across barriers)
__device__ __forceinline__ void wait_vm4() { asm volatile("s_waitcnt vmcnt(4)" ::: "memory"); }
__device__ __forceinline__ void wait_vm0() { asm volatile("s_waitcnt vmcnt(0)" ::: "memory"); }
// raw barrier fenced so the compiler can't move LDS ops across it
__device__ __forceinline__ void barrier_sync() {
    asm volatile("" ::: "memory");
    __builtin_amdgcn_s_barrier();
    asm volatile("" ::: "memory");
}

// ---------------- dtype sniff ----------------
__global__ __launch_bounds__(256) void sniff_kernel(const unsigned short* __restrict__ x,
                                                    int* __restrict__ flag) {
    __shared__ int cnt[256];
    int tid = threadIdx.x;
    int c = 0;
    for (int i = tid * 2; i < 65536; i += 512) {
        int e = (x[i] >> 7) & 0xFF;
        if (e >= 0x8A) c++;
    }
    cnt[tid] = c;
    __syncthreads();
    for (int s = 128; s > 0; s >>= 1) {
        if (tid < s) cnt[tid] += cnt[tid + s];
        __syncthreads();
    }
    if (tid == 0) flag[0] = (cnt[0] > 32) ? 1 : 0;
}

// ---------------- converts ----------------
__global__ __launch_bounds__(256) void store_out(const float* __restrict__ xf, void* __restrict__ out,
                                                 const int* __restrict__ flag) {
    int f = flag[0];
    int i = blockIdx.x * 256 + threadIdx.x;
    float v = xf[i];
    if (f) ((float*)out)[i] = v;
    else   ((unsigned short*)out)[i] = f2bf(v);
}
// all 7 small vectors in one launch; grid (64, 7)
__global__ __launch_bounds__(256) void conv_all(const void* s0, const void* s1, const void* s2,
                                                const void* s3, const void* s4, const void* s5,
                                                const void* s6, unsigned short* __restrict__ dst,
                                                const int* __restrict__ flag) {
    int f = flag[0];
    const void* src; int len, off;
    switch (blockIdx.y) {
        case 0: src = s0; len = 1024; off = 0;    break;
        case 1: src = s1; len = 1024; off = 1024; break;
        case 2: src = s2; len = 1024; off = 2048; break;
        case 3: src = s3; len = 1024; off = 3072; break;
        case 4: src = s4; len = 1024; off = 4096; break;
        case 5: src = s5; len = 1024; off = 5120; break;
        default: src = s6; len = 4096; off = 6144; break;
    }
    int i = blockIdx.x * 256 + threadIdx.x;
    if (i < DEPTHN * len) {
        int l = i / len, o = i - l * len;
        dst[l * VSTR + off + o] = f2bf(loadf(src, i, f));
    }
}

// ---------------- transpose+convert: src[srcOffE + k*N + n] -> bf16 out[n*K + k] ----------------
__global__ __launch_bounds__(256) void transpose_conv(const void* __restrict__ in, size_t srcOffE,
                                                      unsigned short* __restrict__ out,
                                                      int K, int N, const int* __restrict__ flag) {
    int f = flag[0];
    __shared__ unsigned short t[32][33];
    int n0 = blockIdx.x * 32, k0 = blockIdx.y * 32;
    int tx = threadIdx.x, ty = threadIdx.y;  // 32 x 8
#pragma unroll
    for (int i = 0; i < 4; i++) {
        int k = k0 + ty + i * 8;
        t[ty + i * 8][tx] = f2bf(loadf(in, srcOffE + (size_t)k * N + n0 + tx, f));
    }
    __syncthreads();
#pragma unroll
    for (int i = 0; i < 4; i++) {
        int n = n0 + ty + i * 8;
        out[(size_t)n * K + k0 + tx] = t[tx][ty + i * 8];
    }
}

// ---------------- batched attn-half transpose: qkv_w AND out_w in one launch ----------------
// grid.x = 3072 + 1024 = 4096 blocks of (32,8); qkv -> wT[0..3M), out -> wT[3M..4M)
__global__ __launch_bounds__(256) void transpose_attn(const void* __restrict__ qkvw,
                                                      const void* __restrict__ outw,
                                                      int layer, unsigned short* __restrict__ wT,
                                                      const int* __restrict__ flag) {
    int f = flag[0];
    __shared__ unsigned short t[32][33];
    int id = blockIdx.x;
    const void* src; int N; size_t soff; unsigned short* dst; int bx, by;
    if (id < 3072) {
        N = 3072; bx = id % 96; by = id / 96;
        src = qkvw; soff = (size_t)layer * 1024 * 3072; dst = wT;
    } else {
        id -= 3072; N = 1024; bx = id % 32; by = id / 32;
        src = outw; soff = (size_t)layer * 1024 * 1024; dst = wT + 3 * 1024 * 1024;
    }
    int n0 = bx * 32, k0 = by * 32;
    int tx = threadIdx.x, ty = threadIdx.y;  // 32 x 8
#pragma unroll
    for (int i = 0; i < 4; i++) {
        int k = k0 + ty + i * 8;
        t[ty + i * 8][tx] = f2bf(loadf(src, soff + (size_t)k * N + n0 + tx, f));
    }
    __syncthreads();
#pragma unroll
    for (int i = 0; i < 4; i++) {
        int n = n0 + ty + i * 8;
        dst[(size_t)n * 1024 + k0 + tx] = t[tx][ty + i * 8];
    }
}

// ---------------- V^T per layer ----------------
__global__ __launch_bounds__(256) void vt_kernel(const unsigned short* __restrict__ qkv,
                                                 unsigned short* __restrict__ vt) {
    __shared__ unsigned short t[32][33];
    int b = blockIdx.z;
    int c0 = blockIdx.x * 32, k0 = blockIdx.y * 32;
    int tx = threadIdx.x, ty = threadIdx.y;  // 32 x 8
#pragma unroll
    for (int i = 0; i < 4; i++) {
        int k = k0 + ty + i * 8;
        t[ty + i * 8][tx] = qkv[(size_t)(b * 1024 + k) * 3072 + 2048 + c0 + tx];
    }
    __syncthreads();
#pragma unroll
    for (int i = 0; i < 4; i++) {
        int c = c0 + ty + i * 8;
        vt[(size_t)(b * 1024 + c) * 1024 + k0 + tx] = t[tx][ty + i * 8];
    }
}

// ---------------- mask -> bitmask u64 words ----------------
__global__ __launch_bounds__(256) void mask_pack(const int* __restrict__ mask,
                                                 unsigned long long* __restrict__ bits) {
    int wid = (blockIdx.x * 256 + threadIdx.x) >> 6;
    int lane = threadIdx.x & 63;
#pragma unroll
    for (int i = 0; i < 16; i++) {
        int w = wid * 16 + i;
        int mv = mask[(size_t)w * 64 + lane];
        unsigned long long bl = __ballot(mv != 0);
        if (lane == 0) bits[w] = bl;
    }
}

// ---------------- fused cvt + LayerNorm from raw x (first pre-attn LN) ----------------
__global__ __launch_bounds__(256) void ln_raw(const void* __restrict__ x, float* __restrict__ xf,
                                              const unsigned short* __restrict__ g,
                                              const unsigned short* __restrict__ bta,
                                              unsigned short* __restrict__ out,
                                              const int* __restrict__ flag) {
    int f = flag[0];
    int row = blockIdx.x, tid = threadIdx.x;
    size_t base = (size_t)row * DIMM;
    float v[4]; float s = 0.f, s2 = 0.f;
#pragma unroll
    for (int i = 0; i < 4; i++) {
        int c = tid + i * 256;
        v[i] = loadf(x, base + c, f);
        xf[base + c] = v[i];
        s += v[i]; s2 += v[i] * v[i];
    }
#pragma unroll
    for (int off = 32; off >= 1; off >>= 1) {
        s  += __shfl_down(s, off, 64);
        s2 += __shfl_down(s2, off, 64);
    }
    __shared__ float rs[4], rs2[4];
    int wv = tid >> 6;
    if ((tid & 63) == 0) { rs[wv] = s; rs2[wv] = s2; }
    __syncthreads();
    s  = rs[0] + rs[1] + rs[2] + rs[3];
    s2 = rs2[0] + rs2[1] + rs2[2] + rs2[3];
    float mu  = s * (1.f / DIMM);
    float var = s2 * (1.f / DIMM) - mu * mu;
    float rr  = rsqrtf(var + 1e-5f);
#pragma unroll
    for (int i = 0; i < 4; i++) {
        int c = tid + i * 256;
        float y = (v[i] - mu) * rr * bf2f(g[c]) + bf2f(bta[c]);
        out[base + c] = f2bf(y);
    }
}

// ---------------- LayerNorm (standalone fallback) ----------------
__global__ __launch_bounds__(256) void ln_kernel(const float* __restrict__ x,
                                                 const unsigned short* __restrict__ g,
                                                 const unsigned short* __restrict__ bta,
                                                 unsigned short* __restrict__ out) {
    int row = blockIdx.x, tid = threadIdx.x;
    const float* xr = x + (size_t)row * DIMM;
    float v[4]; float s = 0.f, s2 = 0.f;
#pragma unroll
    for (int i = 0; i < 4; i++) { v[i] = xr[tid + i * 256]; s += v[i]; s2 += v[i] * v[i]; }
#pragma unroll
    for (int off = 32; off >= 1; off >>= 1) {
        s  += __shfl_down(s, off, 64);
        s2 += __shfl_down(s2, off, 64);
    }
    __shared__ float rs[4], rs2[4];
    int wv = tid >> 6;
    if ((tid & 63) == 0) { rs[wv] = s; rs2[wv] = s2; }
    __syncthreads();
    s  = rs[0] + rs[1] + rs[2] + rs[3];
    s2 = rs2[0] + rs2[1] + rs2[2] + rs2[3];
    float mu  = s * (1.f / DIMM);
    float var = s2 * (1.f / DIMM) - mu * mu;
    float rr  = rsqrtf(var + 1e-5f);
#pragma unroll
    for (int i = 0; i < 4; i++) {
        int c = tid + i * 256;
        float y = (v[i] - mu) * rr * bf2f(g[c]) + bf2f(bta[c]);
        out[(size_t)row * DIMM + c] = f2bf(y);
    }
}

// ---------------- split-K slab reduce + residual update (+ optional fused LN) ----------------
template <int S, int HAS_LN>
__global__ __launch_bounds__(256) void reduce_ln(const float* __restrict__ slab,
                                                 const unsigned short* __restrict__ bias,
                                                 float* __restrict__ xf,
                                                 const unsigned short* __restrict__ g,
                                                 const unsigned short* __restrict__ bta,
                                                 unsigned short* __restrict__ out) {
    const size_t SL = (size_t)MROWS * DIMM;
    int row = blockIdx.x, tid = threadIdx.x;
    float v[4]; float s = 0.f, s2 = 0.f;
#pragma unroll
    for (int i = 0; i < 4; i++) {
        int c = tid + i * 256;
        size_t idx = (size_t)row * DIMM + c;
        float t = xf[idx] + bf2f(bias[c]);
#pragma unroll
        for (int z = 0; z < S; z++) t += slab[z * SL + idx];
        xf[idx] = t;
        v[i] = t; s += t; s2 += t * t;
    }
    if (HAS_LN) {
#pragma unroll
        for (int off = 32; off >= 1; off >>= 1) {
            s  += __shfl_down(s, off, 64);
            s2 += __shfl_down(s2, off, 64);
        }
        __shared__ float rs[4], rs2[4];
        int wv = tid >> 6;
        if ((tid & 63) == 0) { rs[wv] = s; rs2[wv] = s2; }
        __syncthreads();
        s  = rs[0] + rs[1] + rs[2] + rs[3];
        s2 = rs2[0] + rs2[1] + rs2[2] + rs2[3];
        float mu  = s * (1.f / DIMM);
        float var = s2 * (1.f / DIMM) - mu * mu;
        float rr  = rsqrtf(var + 1e-5f);
#pragma unroll
        for (int i = 0; i < 4; i++) {
            int c = tid + i * 256;
            float y = (v[i] - mu) * rr * bf2f(g[c]) + bf2f(bta[c]);
            out[(size_t)row * DIMM + c] = f2bf(y);
        }
    }
}

// ---------------- GEMM (8-wave 128x128 tile, BK=64, dbuf + counted vmcnt) ----------------
// 512 threads = 8 waves; wave-tile 64x32 (wm=(w>>2)*64, wn=(w&3)*32).
// K-step = 64: per wave per tile = 4x gl_lds16 stage + 12 ds_read_b128 + 16 MFMA.
// LDS rows are 64 el (128 B = all 32 banks); swizzle: 16B-granule g' = g ^ (row&7),
// applied as pre-swizzled GLOBAL source (linear gl_lds dest) + same XOR on reads.
// Each 16-lane read phase then covers all 32 banks at exactly 2 dwords/bank (free).
// Double-buffered with counted vmcnt(4): stage(t+1) issued before compute(t); the wait
// lets tile t+1's 4 loads stay in flight across both barriers.
// MODE 0: store bf16 C       MODE 1: Cres(fp32) atomic += acc(+bias@z0)  [fallback]
// MODE 2: bf16 gelu(acc+bias) MODE 3: slab[z] = acc (fp32, pure stores)
template <int MODE, int SPLITK>
__global__ __launch_bounds__(512) void gemm_bt(const unsigned short* __restrict__ A,
                                               const unsigned short* __restrict__ Bt,
                                               const unsigned short* __restrict__ bias,
                                               unsigned short* __restrict__ Cbf,
                                               float* __restrict__ Cres,
                                               int M, int N, int K) {
    __shared__ __align__(16) unsigned short As0[128 * 64];
    __shared__ __align__(16) unsigned short Bs0[128 * 64];
    __shared__ __align__(16) unsigned short As1[128 * 64];
    __shared__ __align__(16) unsigned short Bs1[128 * 64];
    const int tid = threadIdx.x;
    const int mBase = blockIdx.y * 128, nBase = blockIdx.x * 128;
    const int w = tid >> 6, lane = tid & 63;
    const int wm = (w >> 2) * 64, wn = (w & 3) * 32;
    const int quad = lane >> 4, l16 = lane & 15;
    const int kLen = K / SPLITK;
    const int kStart = (SPLITK > 1) ? blockIdx.z * kLen : 0;
    const int NT = kLen / 64;  // 8/16 here, always even

    f32x4 acc[4][2];
#pragma unroll
    for (int i = 0; i < 4; i++)
#pragma unroll
        for (int j = 0; j < 2; j++) acc[i][j] = (f32x4){0.f, 0.f, 0.f, 0.f};

    // staging: waves 0-3 stage A rows [wb*32,wb*32+32), waves 4-7 stage B.
    // each gl_lds16 covers 8 rows (lane>>3) x 8 granules (lane&7); source granule
    // pre-swizzled by row&7 so the linear LDS dest ends up XOR-swizzled.
    const int wb = w & 3;
    const int lr8 = lane >> 3;                 // row within 8-row chunk
    const int sgran = (lane & 7) ^ lr8;        // swizzled source 16B-granule
    const unsigned short* G = (w < 4 ? A  + (size_t)(mBase + wb * 32 + lr8) * K
                                     : Bt + (size_t)(nBase + wb * 32 + lr8) * K)
                              + kStart + sgran * 8;
    unsigned short* S0 = (w < 4 ? As0 : Bs0) + (wb * 32) * 64;
    unsigned short* S1 = (w < 4 ? As1 : Bs1) + (wb * 32) * 64;
    const size_t r8 = (size_t)8 * K;           // 8 rows in global

    const int rg0 = (quad ^ (l16 & 7)) * 8;        // ks=0 read granule offset (elements)
    const int rg1 = ((4 + quad) ^ (l16 & 7)) * 8;  // ks=1

    auto stage = [&](unsigned short* S, int t) {
        const unsigned short* g = G + (size_t)t * 64;
#pragma unroll
        for (int i = 0; i < 4; i++)
            gl_lds16(g + (size_t)i * r8, S + i * 8 * 64);
    };
    auto compute = [&](const unsigned short* Asb, const unsigned short* Bsb) {
#pragma unroll
        for (int ks = 0; ks < 2; ks++) {
            const int rg = ks ? rg1 : rg0;
            bf16x8 af[4], bfv[2];
#pragma unroll
            for (int i = 0; i < 4; i++)
                af[i] = *(const bf16x8*)&Asb[(wm + i * 16 + l16) * 64 + rg];
#pragma unroll
            for (int j = 0; j < 2; j++)
                bfv[j] = *(const bf16x8*)&Bsb[(wn + j * 16 + l16) * 64 + rg];
#pragma unroll
            for (int i = 0; i < 4; i++)
#pragma unroll
                for (int j = 0; j < 2; j++)
                    acc[i][j] = __builtin_amdgcn_mfma_f32_16x16x32_bf16(af[i], bfv[j], acc[i][j], 0, 0, 0);
        }
    };

    stage(S0, 0);  // prologue
    for (int t = 0; t < NT; t += 2) {
        stage(S1, t + 1);
        wait_vm4();       // my tile-t loads landed (4 newest = tile t+1, in flight)
        barrier_sync();   // everyone's tile-t loads landed
        compute(As0, Bs0);
        barrier_sync();   // reads of buf0 done -> may overwrite
        if (t + 2 < NT) {
            stage(S0, t + 2);
            wait_vm4();
        } else {
            wait_vm0();
        }
        barrier_sync();
        compute(As1, Bs1);
        barrier_sync();
    }

    const size_t slabOff = (MODE == 3) ? (size_t)blockIdx.z * M * N : 0;
#pragma unroll
    for (int i = 0; i < 4; i++) {
#pragma unroll
        for (int j = 0; j < 2; j++) {
#pragma unroll
            for (int r = 0; r < 4; r++) {
                int m = mBase + wm + i * 16 + quad * 4 + r;
                int n = nBase + wn + j * 16 + l16;
                float v = acc[i][j][r];
                size_t idx = (size_t)m * N + n;
                if (MODE == 0) {
                    Cbf[idx] = f2bf(v);
                } else if (MODE == 1) {
                    if (SPLITK > 1) {
                        if (blockIdx.z == 0) v += bf2f(bias[n]);
                        atomicAdd(&Cres[idx], v);
                    } else {
                        Cres[idx] += v + bf2f(bias[n]);
                    }
                } else if (MODE == 2) {
                    float t2 = v + bf2f(bias[n]);
                    float gg = 0.5f * t2 * (1.f + erff(t2 * 0.70710678118f));
                    Cbf[idx] = f2bf(gg);
                } else {
                    Cres[slabOff + idx] = v;
                }
            }
        }
    }
}

// ---------------- MFMA flash attention (swapped-QK, in-register P) ----------------
__global__ __launch_bounds__(256) void attn_mfma(const unsigned short* __restrict__ qkv,
                                                 const unsigned short* __restrict__ vt,
                                                 const unsigned long long* __restrict__ mbits,
                                                 unsigned short* __restrict__ o) {
    __shared__ __align__(16) unsigned short Ks[64 * 72];
    __shared__ __align__(16) unsigned short Vs[64 * 72];

    const int tid = threadIdx.x, w = tid >> 6, lane = tid & 63;
    const int quad = lane >> 4, l16 = lane & 15;
    const int qt = blockIdx.x, h = blockIdx.y, b = blockIdx.z;

    const size_t qrow = (size_t)(b * NSEQ + qt * 64 + w * 16 + l16) * 3072 + h * 64;
    bf16x8 qf[2];
    qf[0] = *(const bf16x8*)(qkv + qrow + quad * 8);
    qf[1] = *(const bf16x8*)(qkv + qrow + 32 + quad * 8);

    const int srow = tid >> 2, scol = (tid & 3) * 16;
    const unsigned short* kg_base = qkv + (size_t)(b * NSEQ) * 3072 + 1024 + h * 64;
    const unsigned short* vg_base = vt + (size_t)((b * HEADSN + h) * 64 + srow) * 1024;

    f32x4 oacc[4];
#pragma unroll
    for (int j = 0; j < 4; j++) oacc[j] = (f32x4){0.f, 0.f, 0.f, 0.f};
    float m_run = -1e30f, l_run = 0.f;

    const unsigned long long* mb = mbits + ((size_t)(b * NSEQ + qt * 64 + w * 16 + l16)) * 16;

    for (int kt = 0; kt < 16; kt++) {
        __syncthreads();
        {
            const unsigned short* kg = kg_base + (size_t)(kt * 64 + srow) * 3072 + scol;
            uint4 k0 = *(const uint4*)kg;
            uint4 k1 = *(const uint4*)(kg + 8);
            const unsigned short* vg = vg_base + kt * 64 + scol;
            uint4 v0 = *(const uint4*)vg;
            uint4 v1 = *(const uint4*)(vg + 8);
            *(uint4*)&Ks[srow * 72 + scol]     = k0;
            *(uint4*)&Ks[srow * 72 + scol + 8] = k1;
            *(uint4*)&Vs[srow * 72 + scol]     = v0;
            *(uint4*)&Vs[srow * 72 + scol + 8] = v1;
        }
        __syncthreads();

        f32x4 sacc[4];
#pragma unroll
        for (int j = 0; j < 4; j++) sacc[j] = (f32x4){0.f, 0.f, 0.f, 0.f};
#pragma unroll
        for (int ks = 0; ks < 2; ks++) {
#pragma unroll
            for (int j = 0; j < 4; j++) {
                bf16x8 kf = *(const bf16x8*)&Ks[(j * 16 + l16) * 72 + ks * 32 + quad * 8];
                sacc[j] = __builtin_amdgcn_mfma_f32_16x16x32_bf16(kf, qf[ks], sacc[j], 0, 0, 0);
            }
        }

        const unsigned long long mw = mb[kt];

        float t[4][4];
        float mxj[4];
#pragma unroll
        for (int j = 0; j < 4; j++) {
            unsigned nib = (unsigned)(mw >> (quad * 4 + j * 16)) & 0xFu;
#pragma unroll
            for (int r = 0; r < 4; r++) {
                float s = sacc[j][r] * 0.125f;
                t[j][r] = ((nib >> r) & 1u) ? s : -1e30f;
            }
            mxj[j] = fmaxf(fmaxf(t[j][0], t[j][1]), fmaxf(t[j][2], t[j][3]));
        }
        float mx = fmaxf(fmaxf(mxj[0], mxj[1]), fmaxf(mxj[2], mxj[3]));
        mx = fmaxf(mx, __shfl_xor(mx, 16, 64));
        mx = fmaxf(mx, __shfl_xor(mx, 32, 64));

        if (!__all(mx <= m_run)) {
            float m_new = fmaxf(m_run, mx);
            float alpha = __expf(m_run - m_new);
            m_run = m_new;
            l_run *= alpha;
            float al[4];
#pragma unroll
            for (int r = 0; r < 4; r++) al[r] = __shfl(alpha, quad * 4 + r, 64);
#pragma unroll
            for (int j = 0; j < 4; j++)
#pragma unroll
                for (int r = 0; r < 4; r++) oacc[j][r] *= al[r];
        }

        float p[4][4];
        float psj[4];
#pragma unroll
        for (int j = 0; j < 4; j++) {
#pragma unroll
            for (int r = 0; r < 4; r++) p[j][r] = __expf(t[j][r] - m_run);
            psj[j] = (p[j][0] + p[j][1]) + (p[j][2] + p[j][3]);
        }
        float ps = (psj[0] + psj[1]) + (psj[2] + psj[3]);
        ps += __shfl_xor(ps, 16, 64);
        ps += __shfl_xor(ps, 32, 64);
        l_run += ps;

        union { uint32_t u[4]; bf16x8 v; } pa[2];
#pragma unroll
        for (int ks = 0; ks < 2; ks++) {
            pa[ks].u[0] = cvt_pk_bf16(p[2 * ks][0],     p[2 * ks][1]);
            pa[ks].u[1] = cvt_pk_bf16(p[2 * ks][2],     p[2 * ks][3]);
            pa[ks].u[2] = cvt_pk_bf16(p[2 * ks + 1][0], p[2 * ks + 1][1]);
            pa[ks].u[3] = cvt_pk_bf16(p[2 * ks + 1][2], p[2 * ks + 1][3]);
        }

#pragma unroll
        for (int ks = 0; ks < 2; ks++) {
#pragma unroll
            for (int j = 0; j < 4; j++) {
                union { ushort4 u[2]; bf16x8 v; } vf;
                const unsigned short* vp = &Vs[(j * 16 + l16) * 72 + ks * 32 + quad * 4];
                vf.u[0] = *(const ushort4*)vp;
                vf.u[1] = *(const ushort4*)(vp + 16);
                oacc[j] = __builtin_amdgcn_mfma_f32_16x16x32_bf16(pa[ks].v, vf.v, oacc[j], 0, 0, 0);
            }
        }
    }

    float inv[4];
#pragma unroll
    for (int r = 0; r < 4; r++) {
        float lr = __shfl(l_run, quad * 4 + r, 64);
        inv[r] = 1.f / lr;
    }
#pragma unroll
    for (int j = 0; j < 4; j++) {
#pragma unroll
        for (int r = 0; r < 4; r++) {
            size_t row = (size_t)(b * NSEQ + qt * 64 + w * 16 + quad * 4 + r);
            o[row * 1024 + h * 64 + j * 16 + l16] = f2bf(oacc[j][r] * inv[r]);
        }
    }
}

extern "C" void kernel_launch(void* const* d_in, const int* in_sizes, int n_in,
                              void* d_out, int out_size, void* d_ws, size_t ws_size,
                              hipStream_t stream) {
    const void* x     = d_in[0];
    const int*  mask  = (const int*)d_in[1];
    const void* ln1_g = d_in[2];
    const void* ln1_b = d_in[3];
    const void* qkv_w = d_in[4];
    const void* out_w = d_in[5];
    const void* out_b = d_in[6];
    const void* ln2_g = d_in[7];
    const void* ln2_b = d_in[8];
    const void* ff1_w = d_in[9];
    const void* ff1_b = d_in[10];
    const void* ff2_w = d_in[11];
    const void* ff2_b = d_in[12];

    char* ws = (char*)d_ws;
    float*          xf     = (float*)ws;                            // 8 MB fp32 residual
    unsigned short* h_bf   = (unsigned short*)(ws + (8u  << 20));   // 4 MB LN out
    unsigned short* qkv_bf = (unsigned short*)(ws + (12u << 20));   // 12 MB (attn half)
    unsigned short* ff_bf  = (unsigned short*)(ws + (12u << 20));   // 16 MB (ff half, reuses qkv+vt)
    unsigned short* vt_bf  = (unsigned short*)(ws + (24u << 20));   // 4 MB V^T (attn half)
    unsigned short* o_bf   = (unsigned short*)(ws + (28u << 20));   // 4 MB
    unsigned short* wT     = (unsigned short*)(ws + (32u << 20));   // 8 MB transposed weight
    unsigned short* vecs   = (unsigned short*)(ws + (40u << 20));   // 80 KB canonical vecs
    int*            flag   = (int*)(ws + (40u << 20) + (128u << 10));
    unsigned long long* mbits = (unsigned long long*)(ws + (40u << 20) + (192u << 10)); // 256 KB
    float*          slab   = (float*)(ws + (41u << 20));            // up to 32 MB split-K slabs

    const bool slabs_ok = ws_size >= (74ull << 20);

    sniff_kernel<<<1, 256, 0, stream>>>((const unsigned short*)x, flag);

    conv_all<<<dim3(64, 7), 256, 0, stream>>>(ln1_g, ln1_b, out_b, ln2_g, ln2_b, ff2_b, ff1_b,
                                              vecs, flag);
    mask_pack<<<512, 256, 0, stream>>>(mask, mbits);

    // fused cvt_x + first pre-attn LN (layer 0)
    ln_raw<<<MROWS, 256, 0, stream>>>(x, xf, vecs + 0, vecs + 1024, h_bf, flag);

    const int nx = MROWS * DIMM;  // 2M

    for (int l = 0; l < DEPTHN; l++) {
        const unsigned short* lv = vecs + l * VSTR;
        const unsigned short* lvn = vecs + (l + 1) * VSTR;  // next layer's vecs (l<3)

        // --- attention half ---
        transpose_attn<<<4096, dim3(32, 8), 0, stream>>>(qkv_w, out_w, l, wT, flag);
        gemm_bt<0, 1><<<dim3(3072 / 128, MROWS / 128), 512, 0, stream>>>(
            h_bf, wT, nullptr, qkv_bf, nullptr, MROWS, 3072, 1024);
        vt_kernel<<<dim3(32, 32, BB), dim3(32, 8), 0, stream>>>(qkv_bf, vt_bf);
        attn_mfma<<<dim3(NSEQ / 64, HEADSN, BB), 256, 0, stream>>>(qkv_bf, vt_bf, mbits, o_bf);
        if (slabs_ok) {
            gemm_bt<3, 2><<<dim3(1024 / 128, MROWS / 128, 2), 512, 0, stream>>>(
                o_bf, wT + 3 * 1024 * 1024, nullptr, nullptr, slab, MROWS, 1024, 1024);
            reduce_ln<2, 1><<<MROWS, 256, 0, stream>>>(
                slab, lv + 2048, xf, lv + 3072, lv + 4096, h_bf);
        } else {
            gemm_bt<1, 2><<<dim3(1024 / 128, MROWS / 128, 2), 512, 0, stream>>>(
                o_bf, wT + 3 * 1024 * 1024, lv + 2048, nullptr, xf, MROWS, 1024, 1024);
            ln_kernel<<<MROWS, 256, 0, stream>>>(xf, lv + 3072, lv + 4096, h_bf);
        }

        // --- feedforward half ---
        transpose_conv<<<dim3(4096 / 32, 1024 / 32), dim3(32, 8), 0, stream>>>(
            ff1_w, (size_t)l * 1024 * 4096, wT, 1024, 4096, flag);
        gemm_bt<2, 1><<<dim3(4096 / 128, MROWS / 128), 512, 0, stream>>>(
            h_bf, wT, lv + 6144, ff_bf, nullptr, MROWS, 4096, 1024);
        transpose_conv<<<dim3(1024 / 32, 4096 / 32), dim3(32, 8), 0, stream>>>(
            ff2_w, (size_t)l * 4096 * 1024, wT, 4096, 1024, flag);
        if (slabs_ok) {
            gemm_bt<3, 4><<<dim3(1024 / 128, MROWS / 128, 4), 512, 0, stream>>>(
                ff_bf, wT, nullptr, nullptr, slab, MROWS, 1024, 4096);
            if (l < DEPTHN - 1)
                reduce_ln<4, 1><<<MROWS, 256, 0, stream>>>(
                    slab, lv + 5120, xf, lvn + 0, lvn + 1024, h_bf);
            else
                reduce_ln<4, 0><<<MROWS, 256, 0, stream>>>(
                    slab, lv + 5120, xf, nullptr, nullptr, nullptr);
        } else {
            gemm_bt<1, 4><<<dim3(1024 / 128, MROWS / 128, 4), 512, 0, stream>>>(
                ff_bf, wT, lv + 5120, nullptr, xf, MROWS, 1024, 4096);
            if (l < DEPTHN - 1)
                ln_kernel<<<MROWS, 256, 0, stream>>>(xf, lvn + 0, lvn + 1024, h_bf);
        }
    }

    store_out<<<nx / 256, 256, 0, stream>>>(xf, d_out, flag);
}

// Round 6
// 827.873 us; speedup vs baseline: 1.2583x; 1.0188x over previous
//
#include <hip/hip_runtime.h>
#include <stdint.h>

#define DIMM 1024
#define NSEQ 1024
#define BB 2
#define HEADSN 16
#define MLPD 4096
#define DEPTHN 4
#define MROWS (BB*NSEQ)  // 2048
#define VSTR 10240       // canonical per-layer vec stride (elements)

typedef __bf16 bf16x8 __attribute__((ext_vector_type(8)));
typedef float f32x4 __attribute__((ext_vector_type(4)));

__device__ __forceinline__ float bf2f(unsigned short u) {
    union { uint32_t i; float f; } x; x.i = ((uint32_t)u) << 16; return x.f;
}
__device__ __forceinline__ unsigned short f2bf(float f) {
    union { uint32_t i; float f; } x; x.f = f;
    uint32_t r = x.i + 0x7fffu + ((x.i >> 16) & 1u);
    return (unsigned short)(r >> 16);
}
__device__ __forceinline__ float loadf(const void* p, size_t i, int f32) {
    return f32 ? ((const float*)p)[i] : bf2f(((const unsigned short*)p)[i]);
}
// packed f32x2 -> bf16x2 (RNE), single HW instruction on gfx950
__device__ __forceinline__ uint32_t cvt_pk_bf16(float lo, float hi) {
    uint32_t r;
    asm("v_cvt_pk_bf16_f32 %0, %1, %2" : "=v"(r) : "v"(lo), "v"(hi));
    return r;
}

// async global->LDS, 16B per lane; LDS dest = wave-uniform base + lane*16
__device__ __forceinline__ void gl_lds16(const unsigned short* g, unsigned short* l) {
    __builtin_amdgcn_global_load_lds(
        (const __attribute__((address_space(1))) uint32_t*)g,
        (__attribute__((address_space(3))) uint32_t*)l,
        16, 0, 0);
}

// counted vmcnt waits (keep next-tile loads in flight across barriers)
__device__ __forceinline__ void wait_vm4() { asm volatile("s_waitcnt vmcnt(4)" ::: "memory"); }
__device__ __forceinline__ void wait_vm0() { asm volatile("s_waitcnt vmcnt(0)" ::: "memory"); }
// raw barrier fenced so the compiler can't move LDS ops across it
__device__ __forceinline__ void barrier_sync() {
    asm volatile("" ::: "memory");
    __builtin_amdgcn_s_barrier();
    asm volatile("" ::: "memory");
}

// ---------------- dtype sniff ----------------
__global__ __launch_bounds__(256) void sniff_kernel(const unsigned short* __restrict__ x,
                                                    int* __restrict__ flag) {
    __shared__ int cnt[256];
    int tid = threadIdx.x;
    int c = 0;
    for (int i = tid * 2; i < 65536; i += 512) {
        int e = (x[i] >> 7) & 0xFF;
        if (e >= 0x8A) c++;
    }
    cnt[tid] = c;
    __syncthreads();
    for (int s = 128; s > 0; s >>= 1) {
        if (tid < s) cnt[tid] += cnt[tid + s];
        __syncthreads();
    }
    if (tid == 0) flag[0] = (cnt[0] > 32) ? 1 : 0;
}

// ---------------- converts ----------------
__global__ __launch_bounds__(256) void store_out(const float* __restrict__ xf, void* __restrict__ out,
                                                 const int* __restrict__ flag) {
    int f = flag[0];
    int i = blockIdx.x * 256 + threadIdx.x;
    float v = xf[i];
    if (f) ((float*)out)[i] = v;
    else   ((unsigned short*)out)[i] = f2bf(v);
}
// all 7 small vectors in one launch; grid (64, 7)
__global__ __launch_bounds__(256) void conv_all(const void* s0, const void* s1, const void* s2,
                                                const void* s3, const void* s4, const void* s5,
                                                const void* s6, unsigned short* __restrict__ dst,
                                                const int* __restrict__ flag) {
    int f = flag[0];
    const void* src; int len, off;
    switch (blockIdx.y) {
        case 0: src = s0; len = 1024; off = 0;    break;
        case 1: src = s1; len = 1024; off = 1024; break;
        case 2: src = s2; len = 1024; off = 2048; break;
        case 3: src = s3; len = 1024; off = 3072; break;
        case 4: src = s4; len = 1024; off = 4096; break;
        case 5: src = s5; len = 1024; off = 5120; break;
        default: src = s6; len = 4096; off = 6144; break;
    }
    int i = blockIdx.x * 256 + threadIdx.x;
    if (i < DEPTHN * len) {
        int l = i / len, o = i - l * len;
        dst[l * VSTR + off + o] = f2bf(loadf(src, i, f));
    }
}

// ---------------- transpose+convert: src[srcOffE + k*N + n] -> bf16 out[n*K + k] ----------------
__global__ __launch_bounds__(256) void transpose_conv(const void* __restrict__ in, size_t srcOffE,
                                                      unsigned short* __restrict__ out,
                                                      int K, int N, const int* __restrict__ flag) {
    int f = flag[0];
    __shared__ unsigned short t[32][33];
    int n0 = blockIdx.x * 32, k0 = blockIdx.y * 32;
    int tx = threadIdx.x, ty = threadIdx.y;  // 32 x 8
#pragma unroll
    for (int i = 0; i < 4; i++) {
        int k = k0 + ty + i * 8;
        t[ty + i * 8][tx] = f2bf(loadf(in, srcOffE + (size_t)k * N + n0 + tx, f));
    }
    __syncthreads();
#pragma unroll
    for (int i = 0; i < 4; i++) {
        int n = n0 + ty + i * 8;
        out[(size_t)n * K + k0 + tx] = t[tx][ty + i * 8];
    }
}

// ---------------- batched attn-half transpose (fallback path) ----------------
__global__ __launch_bounds__(256) void transpose_attn(const void* __restrict__ qkvw,
                                                      const void* __restrict__ outw,
                                                      int layer, unsigned short* __restrict__ wT,
                                                      const int* __restrict__ flag) {
    int f = flag[0];
    __shared__ unsigned short t[32][33];
    int id = blockIdx.x;
    const void* src; int N; size_t soff; unsigned short* dst; int bx, by;
    if (id < 3072) {
        N = 3072; bx = id % 96; by = id / 96;
        src = qkvw; soff = (size_t)layer * 1024 * 3072; dst = wT;
    } else {
        id -= 3072; N = 1024; bx = id % 32; by = id / 32;
        src = outw; soff = (size_t)layer * 1024 * 1024; dst = wT + 3 * 1024 * 1024;
    }
    int n0 = bx * 32, k0 = by * 32;
    int tx = threadIdx.x, ty = threadIdx.y;  // 32 x 8
#pragma unroll
    for (int i = 0; i < 4; i++) {
        int k = k0 + ty + i * 8;
        t[ty + i * 8][tx] = f2bf(loadf(src, soff + (size_t)k * N + n0 + tx, f));
    }
    __syncthreads();
#pragma unroll
    for (int i = 0; i < 4; i++) {
        int n = n0 + ty + i * 8;
        dst[(size_t)n * 1024 + k0 + tx] = t[tx][ty + i * 8];
    }
}

// ---------------- ALL weight transposes for ALL layers in one launch ----------------
// grid (12288, 4): per layer ids: [0,3072) qkv_w, [3072,4096) out_w, [4096,8192) ff1_w,
// [8192,12288) ff2_w.  Per-layer arena stride 12M elements:
//   qkvT @0 (3072x1024), outT @3M (1024x1024), ff1T @4M (4096x1024), ff2T @8M (1024x4096)
__global__ __launch_bounds__(256) void transpose_all(const void* __restrict__ qkvw,
                                                     const void* __restrict__ outw,
                                                     const void* __restrict__ ff1w,
                                                     const void* __restrict__ ff2w,
                                                     unsigned short* __restrict__ wTall,
                                                     const int* __restrict__ flag) {
    int f = flag[0];
    __shared__ unsigned short t[32][33];
    int id = blockIdx.x;
    int l = blockIdx.y;
    unsigned short* base = wTall + (size_t)l * (12u * 1024 * 1024);
    const void* src; int K, N; size_t soff; unsigned short* dst;
    if (id < 3072)      { src = qkvw; K = 1024; N = 3072; soff = (size_t)l * 1024 * 3072; dst = base; }
    else if (id < 4096) { id -= 3072; src = outw; K = 1024; N = 1024; soff = (size_t)l * 1024 * 1024; dst = base + 3 * 1024 * 1024; }
    else if (id < 8192) { id -= 4096; src = ff1w; K = 1024; N = 4096; soff = (size_t)l * 1024 * 4096; dst = base + 4 * 1024 * 1024; }
    else                { id -= 8192; src = ff2w; K = 4096; N = 1024; soff = (size_t)l * 4096 * 1024; dst = base + 8 * 1024 * 1024; }
    int nb = N >> 5;
    int by = id / nb, bx = id - by * nb;
    int n0 = bx * 32, k0 = by * 32;
    int tx = threadIdx.x, ty = threadIdx.y;  // 32 x 8
#pragma unroll
    for (int i = 0; i < 4; i++) {
        int k = k0 + ty + i * 8;
        t[ty + i * 8][tx] = f2bf(loadf(src, soff + (size_t)k * N + n0 + tx, f));
    }
    __syncthreads();
#pragma unroll
    for (int i = 0; i < 4; i++) {
        int n = n0 + ty + i * 8;
        dst[(size_t)n * K + k0 + tx] = t[tx][ty + i * 8];
    }
}

// ---------------- V^T per layer ----------------
__global__ __launch_bounds__(256) void vt_kernel(const unsigned short* __restrict__ qkv,
                                                 unsigned short* __restrict__ vt) {
    __shared__ unsigned short t[32][33];
    int b = blockIdx.z;
    int c0 = blockIdx.x * 32, k0 = blockIdx.y * 32;
    int tx = threadIdx.x, ty = threadIdx.y;  // 32 x 8
#pragma unroll
    for (int i = 0; i < 4; i++) {
        int k = k0 + ty + i * 8;
        t[ty + i * 8][tx] = qkv[(size_t)(b * 1024 + k) * 3072 + 2048 + c0 + tx];
    }
    __syncthreads();
#pragma unroll
    for (int i = 0; i < 4; i++) {
        int c = c0 + ty + i * 8;
        vt[(size_t)(b * 1024 + c) * 1024 + k0 + tx] = t[tx][ty + i * 8];
    }
}

// ---------------- mask -> bitmask u64 words ----------------
__global__ __launch_bounds__(256) void mask_pack(const int* __restrict__ mask,
                                                 unsigned long long* __restrict__ bits) {
    int wid = (blockIdx.x * 256 + threadIdx.x) >> 6;
    int lane = threadIdx.x & 63;
#pragma unroll
    for (int i = 0; i < 16; i++) {
        int w = wid * 16 + i;
        int mv = mask[(size_t)w * 64 + lane];
        unsigned long long bl = __ballot(mv != 0);
        if (lane == 0) bits[w] = bl;
    }
}

// ---------------- fused cvt + LayerNorm from raw x (first pre-attn LN) ----------------
__global__ __launch_bounds__(256) void ln_raw(const void* __restrict__ x, float* __restrict__ xf,
                                              const unsigned short* __restrict__ g,
                                              const unsigned short* __restrict__ bta,
                                              unsigned short* __restrict__ out,
                                              const int* __restrict__ flag) {
    int f = flag[0];
    int row = blockIdx.x, tid = threadIdx.x;
    size_t base = (size_t)row * DIMM;
    float v[4]; float s = 0.f, s2 = 0.f;
#pragma unroll
    for (int i = 0; i < 4; i++) {
        int c = tid + i * 256;
        v[i] = loadf(x, base + c, f);
        xf[base + c] = v[i];
        s += v[i]; s2 += v[i] * v[i];
    }
#pragma unroll
    for (int off = 32; off >= 1; off >>= 1) {
        s  += __shfl_down(s, off, 64);
        s2 += __shfl_down(s2, off, 64);
    }
    __shared__ float rs[4], rs2[4];
    int wv = tid >> 6;
    if ((tid & 63) == 0) { rs[wv] = s; rs2[wv] = s2; }
    __syncthreads();
    s  = rs[0] + rs[1] + rs[2] + rs[3];
    s2 = rs2[0] + rs2[1] + rs2[2] + rs2[3];
    float mu  = s * (1.f / DIMM);
    float var = s2 * (1.f / DIMM) - mu * mu;
    float rr  = rsqrtf(var + 1e-5f);
#pragma unroll
    for (int i = 0; i < 4; i++) {
        int c = tid + i * 256;
        float y = (v[i] - mu) * rr * bf2f(g[c]) + bf2f(bta[c]);
        out[base + c] = f2bf(y);
    }
}

// ---------------- LayerNorm (standalone fallback) ----------------
__global__ __launch_bounds__(256) void ln_kernel(const float* __restrict__ x,
                                                 const unsigned short* __restrict__ g,
                                                 const unsigned short* __restrict__ bta,
                                                 unsigned short* __restrict__ out) {
    int row = blockIdx.x, tid = threadIdx.x;
    const float* xr = x + (size_t)row * DIMM;
    float v[4]; float s = 0.f, s2 = 0.f;
#pragma unroll
    for (int i = 0; i < 4; i++) { v[i] = xr[tid + i * 256]; s += v[i]; s2 += v[i] * v[i]; }
#pragma unroll
    for (int off = 32; off >= 1; off >>= 1) {
        s  += __shfl_down(s, off, 64);
        s2 += __shfl_down(s2, off, 64);
    }
    __shared__ float rs[4], rs2[4];
    int wv = tid >> 6;
    if ((tid & 63) == 0) { rs[wv] = s; rs2[wv] = s2; }
    __syncthreads();
    s  = rs[0] + rs[1] + rs[2] + rs[3];
    s2 = rs2[0] + rs2[1] + rs2[2] + rs2[3];
    float mu  = s * (1.f / DIMM);
    float var = s2 * (1.f / DIMM) - mu * mu;
    float rr  = rsqrtf(var + 1e-5f);
#pragma unroll
    for (int i = 0; i < 4; i++) {
        int c = tid + i * 256;
        float y = (v[i] - mu) * rr * bf2f(g[c]) + bf2f(bta[c]);
        out[(size_t)row * DIMM + c] = f2bf(y);
    }
}

// ---------------- split-K slab reduce + residual update (+ optional fused LN) ----------------
template <int S, int HAS_LN>
__global__ __launch_bounds__(256) void reduce_ln(const float* __restrict__ slab,
                                                 const unsigned short* __restrict__ bias,
                                                 float* __restrict__ xf,
                                                 const unsigned short* __restrict__ g,
                                                 const unsigned short* __restrict__ bta,
                                                 unsigned short* __restrict__ out) {
    const size_t SL = (size_t)MROWS * DIMM;
    int row = blockIdx.x, tid = threadIdx.x;
    float v[4]; float s = 0.f, s2 = 0.f;
#pragma unroll
    for (int i = 0; i < 4; i++) {
        int c = tid + i * 256;
        size_t idx = (size_t)row * DIMM + c;
        float t = xf[idx] + bf2f(bias[c]);
#pragma unroll
        for (int z = 0; z < S; z++) t += slab[z * SL + idx];
        xf[idx] = t;
        v[i] = t; s += t; s2 += t * t;
    }
    if (HAS_LN) {
#pragma unroll
        for (int off = 32; off >= 1; off >>= 1) {
            s  += __shfl_down(s, off, 64);
            s2 += __shfl_down(s2, off, 64);
        }
        __shared__ float rs[4], rs2[4];
        int wv = tid >> 6;
        if ((tid & 63) == 0) { rs[wv] = s; rs2[wv] = s2; }
        __syncthreads();
        s  = rs[0] + rs[1] + rs[2] + rs[3];
        s2 = rs2[0] + rs2[1] + rs2[2] + rs2[3];
        float mu  = s * (1.f / DIMM);
        float var = s2 * (1.f / DIMM) - mu * mu;
        float rr  = rsqrtf(var + 1e-5f);
#pragma unroll
        for (int i = 0; i < 4; i++) {
            int c = tid + i * 256;
            float y = (v[i] - mu) * rr * bf2f(g[c]) + bf2f(bta[c]);
            out[(size_t)row * DIMM + c] = f2bf(y);
        }
    }
}

// ---------------- GEMM (8-wave 128x128 tile, BK=64, dbuf + counted vmcnt) ----------------
// (unchanged from R3 BK=64 version; see comments there)
template <int MODE, int SPLITK>
__global__ __launch_bounds__(512) void gemm_bt(const unsigned short* __restrict__ A,
                                               const unsigned short* __restrict__ Bt,
                                               const unsigned short* __restrict__ bias,
                                               unsigned short* __restrict__ Cbf,
                                               float* __restrict__ Cres,
                                               int M, int N, int K) {
    __shared__ __align__(16) unsigned short As0[128 * 64];
    __shared__ __align__(16) unsigned short Bs0[128 * 64];
    __shared__ __align__(16) unsigned short As1[128 * 64];
    __shared__ __align__(16) unsigned short Bs1[128 * 64];
    const int tid = threadIdx.x;
    const int mBase = blockIdx.y * 128, nBase = blockIdx.x * 128;
    const int w = tid >> 6, lane = tid & 63;
    const int wm = (w >> 2) * 64, wn = (w & 3) * 32;
    const int quad = lane >> 4, l16 = lane & 15;
    const int kLen = K / SPLITK;
    const int kStart = (SPLITK > 1) ? blockIdx.z * kLen : 0;
    const int NT = kLen / 64;

    f32x4 acc[4][2];
#pragma unroll
    for (int i = 0; i < 4; i++)
#pragma unroll
        for (int j = 0; j < 2; j++) acc[i][j] = (f32x4){0.f, 0.f, 0.f, 0.f};

    const int wb = w & 3;
    const int lr8 = lane >> 3;
    const int sgran = (lane & 7) ^ lr8;
    const unsigned short* G = (w < 4 ? A  + (size_t)(mBase + wb * 32 + lr8) * K
                                     : Bt + (size_t)(nBase + wb * 32 + lr8) * K)
                              + kStart + sgran * 8;
    unsigned short* S0 = (w < 4 ? As0 : Bs0) + (wb * 32) * 64;
    unsigned short* S1 = (w < 4 ? As1 : Bs1) + (wb * 32) * 64;
    const size_t r8 = (size_t)8 * K;

    const int rg0 = (quad ^ (l16 & 7)) * 8;
    const int rg1 = ((4 + quad) ^ (l16 & 7)) * 8;

    auto stage = [&](unsigned short* S, int t) {
        const unsigned short* g = G + (size_t)t * 64;
#pragma unroll
        for (int i = 0; i < 4; i++)
            gl_lds16(g + (size_t)i * r8, S + i * 8 * 64);
    };
    auto compute = [&](const unsigned short* Asb, const unsigned short* Bsb) {
#pragma unroll
        for (int ks = 0; ks < 2; ks++) {
            const int rg = ks ? rg1 : rg0;
            bf16x8 af[4], bfv[2];
#pragma unroll
            for (int i = 0; i < 4; i++)
                af[i] = *(const bf16x8*)&Asb[(wm + i * 16 + l16) * 64 + rg];
#pragma unroll
            for (int j = 0; j < 2; j++)
                bfv[j] = *(const bf16x8*)&Bsb[(wn + j * 16 + l16) * 64 + rg];
#pragma unroll
            for (int i = 0; i < 4; i++)
#pragma unroll
                for (int j = 0; j < 2; j++)
                    acc[i][j] = __builtin_amdgcn_mfma_f32_16x16x32_bf16(af[i], bfv[j], acc[i][j], 0, 0, 0);
        }
    };

    stage(S0, 0);
    for (int t = 0; t < NT; t += 2) {
        stage(S1, t + 1);
        wait_vm4();
        barrier_sync();
        compute(As0, Bs0);
        barrier_sync();
        if (t + 2 < NT) {
            stage(S0, t + 2);
            wait_vm4();
        } else {
            wait_vm0();
        }
        barrier_sync();
        compute(As1, Bs1);
        barrier_sync();
    }

    const size_t slabOff = (MODE == 3) ? (size_t)blockIdx.z * M * N : 0;
#pragma unroll
    for (int i = 0; i < 4; i++) {
#pragma unroll
        for (int j = 0; j < 2; j++) {
#pragma unroll
            for (int r = 0; r < 4; r++) {
                int m = mBase + wm + i * 16 + quad * 4 + r;
                int n = nBase + wn + j * 16 + l16;
                float v = acc[i][j][r];
                size_t idx = (size_t)m * N + n;
                if (MODE == 0) {
                    Cbf[idx] = f2bf(v);
                } else if (MODE == 1) {
                    if (SPLITK > 1) {
                        if (blockIdx.z == 0) v += bf2f(bias[n]);
                        atomicAdd(&Cres[idx], v);
                    } else {
                        Cres[idx] += v + bf2f(bias[n]);
                    }
                } else if (MODE == 2) {
                    float t2 = v + bf2f(bias[n]);
                    float gg = 0.5f * t2 * (1.f + erff(t2 * 0.70710678118f));
                    Cbf[idx] = f2bf(gg);
                } else {
                    Cres[slabOff + idx] = v;
                }
            }
        }
    }
}

// ---------------- MFMA flash attention (swapped-QK, in-register P, dbuf K/V pipeline) ----------------
// Double-buffered K/V LDS: ONE __syncthreads per kt-tile.  kt+1's global loads issue
// right after the sync (T14 issue-early) and are written to buf[cur^1] after compute
// (write-late).  Safety: iter-kt's top sync orders all of iter-(kt-1)'s reads of
// buf[cur^1] before any thread writes it in iter kt.  s_setprio(1) wraps both MFMA
// clusters (T5; attn has the wave role-diversity that makes it pay, m191).
__global__ __launch_bounds__(256) void attn_mfma(const unsigned short* __restrict__ qkv,
                                                 const unsigned short* __restrict__ vt,
                                                 const unsigned long long* __restrict__ mbits,
                                                 unsigned short* __restrict__ o) {
    __shared__ __align__(16) unsigned short Ks[2][64 * 72];
    __shared__ __align__(16) unsigned short Vs[2][64 * 72];

    const int tid = threadIdx.x, w = tid >> 6, lane = tid & 63;
    const int quad = lane >> 4, l16 = lane & 15;
    const int qt = blockIdx.x, h = blockIdx.y, b = blockIdx.z;

    const size_t qrow = (size_t)(b * NSEQ + qt * 64 + w * 16 + l16) * 3072 + h * 64;
    bf16x8 qf[2];
    qf[0] = *(const bf16x8*)(qkv + qrow + quad * 8);
    qf[1] = *(const bf16x8*)(qkv + qrow + 32 + quad * 8);

    const int srow = tid >> 2, scol = (tid & 3) * 16;
    const unsigned short* kg0 = qkv + (size_t)(b * NSEQ) * 3072 + 1024 + h * 64
                                + (size_t)srow * 3072 + scol;
    const unsigned short* vg0 = vt + (size_t)((b * HEADSN + h) * 64 + srow) * 1024 + scol;

    f32x4 oacc[4];
#pragma unroll
    for (int j = 0; j < 4; j++) oacc[j] = (f32x4){0.f, 0.f, 0.f, 0.f};
    float m_run = -1e30f, l_run = 0.f;

    const unsigned long long* mb = mbits + ((size_t)(b * NSEQ + qt * 64 + w * 16 + l16)) * 16;

    // prologue: stage kt=0 into buf 0
    uint4 ka = *(const uint4*)kg0;
    uint4 kb = *(const uint4*)(kg0 + 8);
    uint4 va = *(const uint4*)vg0;
    uint4 vb = *(const uint4*)(vg0 + 8);
    *(uint4*)&Ks[0][srow * 72 + scol]     = ka;
    *(uint4*)&Ks[0][srow * 72 + scol + 8] = kb;
    *(uint4*)&Vs[0][srow * 72 + scol]     = va;
    *(uint4*)&Vs[0][srow * 72 + scol + 8] = vb;
    unsigned long long mw = mb[0];
    int cur = 0;

    for (int kt = 0; kt < 16; kt++) {
        __syncthreads();  // buf[cur] writes visible; prior iter's reads of buf[cur^1] done

        unsigned long long mw_n = 0;
        if (kt < 15) {  // issue kt+1 loads now; consumed (LDS-written) after compute
            const unsigned short* kg = kg0 + (size_t)(kt + 1) * 64 * 3072;
            ka = *(const uint4*)kg;
            kb = *(const uint4*)(kg + 8);
            const unsigned short* vg = vg0 + (kt + 1) * 64;
            va = *(const uint4*)vg;
            vb = *(const uint4*)(vg + 8);
            mw_n = mb[kt + 1];
        }

        // S^T: sacc[j][r] = S[q=l16][k = j*16 + quad*4 + r]
        f32x4 sacc[4];
#pragma unroll
        for (int j = 0; j < 4; j++) sacc[j] = (f32x4){0.f, 0.f, 0.f, 0.f};
        __builtin_amdgcn_s_setprio(1);
#pragma unroll
        for (int ks = 0; ks < 2; ks++) {
#pragma unroll
            for (int j = 0; j < 4; j++) {
                bf16x8 kf = *(const bf16x8*)&Ks[cur][(j * 16 + l16) * 72 + ks * 32 + quad * 8];
                sacc[j] = __builtin_amdgcn_mfma_f32_16x16x32_bf16(kf, qf[ks], sacc[j], 0, 0, 0);
            }
        }
        __builtin_amdgcn_s_setprio(0);

        float t[4][4];
        float mxj[4];
#pragma unroll
        for (int j = 0; j < 4; j++) {
            unsigned nib = (unsigned)(mw >> (quad * 4 + j * 16)) & 0xFu;
#pragma unroll
            for (int r = 0; r < 4; r++) {
                float s = sacc[j][r] * 0.125f;
                t[j][r] = ((nib >> r) & 1u) ? s : -1e30f;
            }
            mxj[j] = fmaxf(fmaxf(t[j][0], t[j][1]), fmaxf(t[j][2], t[j][3]));
        }
        float mx = fmaxf(fmaxf(mxj[0], mxj[1]), fmaxf(mxj[2], mxj[3]));
        mx = fmaxf(mx, __shfl_xor(mx, 16, 64));
        mx = fmaxf(mx, __shfl_xor(mx, 32, 64));

        if (!__all(mx <= m_run)) {
            float m_new = fmaxf(m_run, mx);
            float alpha = __expf(m_run - m_new);
            m_run = m_new;
            l_run *= alpha;
            float al[4];
#pragma unroll
            for (int r = 0; r < 4; r++) al[r] = __shfl(alpha, quad * 4 + r, 64);
#pragma unroll
            for (int j = 0; j < 4; j++)
#pragma unroll
                for (int r = 0; r < 4; r++) oacc[j][r] *= al[r];
        }

        float p[4][4];
        float psj[4];
#pragma unroll
        for (int j = 0; j < 4; j++) {
#pragma unroll
            for (int r = 0; r < 4; r++) p[j][r] = __expf(t[j][r] - m_run);
            psj[j] = (p[j][0] + p[j][1]) + (p[j][2] + p[j][3]);
        }
        float ps = (psj[0] + psj[1]) + (psj[2] + psj[3]);
        ps += __shfl_xor(ps, 16, 64);
        ps += __shfl_xor(ps, 32, 64);
        l_run += ps;

        union { uint32_t u[4]; bf16x8 v; } pa[2];
#pragma unroll
        for (int ks = 0; ks < 2; ks++) {
            pa[ks].u[0] = cvt_pk_bf16(p[2 * ks][0],     p[2 * ks][1]);
            pa[ks].u[1] = cvt_pk_bf16(p[2 * ks][2],     p[2 * ks][3]);
            pa[ks].u[2] = cvt_pk_bf16(p[2 * ks + 1][0], p[2 * ks + 1][1]);
            pa[ks].u[3] = cvt_pk_bf16(p[2 * ks + 1][2], p[2 * ks + 1][3]);
        }

        __builtin_amdgcn_s_setprio(1);
#pragma unroll
        for (int ks = 0; ks < 2; ks++) {
#pragma unroll
            for (int j = 0; j < 4; j++) {
                union { ushort4 u[2]; bf16x8 v; } vf;
                const unsigned short* vp = &Vs[cur][(j * 16 + l16) * 72 + ks * 32 + quad * 4];
                vf.u[0] = *(const ushort4*)vp;
                vf.u[1] = *(const ushort4*)(vp + 16);
                oacc[j] = __builtin_amdgcn_mfma_f32_16x16x32_bf16(pa[ks].v, vf.v, oacc[j], 0, 0, 0);
            }
        }
        __builtin_amdgcn_s_setprio(0);

        if (kt < 15) {  // write-late: land kt+1 into the other buffer
            *(uint4*)&Ks[cur ^ 1][srow * 72 + scol]     = ka;
            *(uint4*)&Ks[cur ^ 1][srow * 72 + scol + 8] = kb;
            *(uint4*)&Vs[cur ^ 1][srow * 72 + scol]     = va;
            *(uint4*)&Vs[cur ^ 1][srow * 72 + scol + 8] = vb;
            mw = mw_n;
            cur ^= 1;
        }
    }

    float inv[4];
#pragma unroll
    for (int r = 0; r < 4; r++) {
        float lr = __shfl(l_run, quad * 4 + r, 64);
        inv[r] = 1.f / lr;
    }
#pragma unroll
    for (int j = 0; j < 4; j++) {
#pragma unroll
        for (int r = 0; r < 4; r++) {
            size_t row = (size_t)(b * NSEQ + qt * 64 + w * 16 + quad * 4 + r);
            o[row * 1024 + h * 64 + j * 16 + l16] = f2bf(oacc[j][r] * inv[r]);
        }
    }
}

extern "C" void kernel_launch(void* const* d_in, const int* in_sizes, int n_in,
                              void* d_out, int out_size, void* d_ws, size_t ws_size,
                              hipStream_t stream) {
    const void* x     = d_in[0];
    const int*  mask  = (const int*)d_in[1];
    const void* ln1_g = d_in[2];
    const void* ln1_b = d_in[3];
    const void* qkv_w = d_in[4];
    const void* out_w = d_in[5];
    const void* out_b = d_in[6];
    const void* ln2_g = d_in[7];
    const void* ln2_b = d_in[8];
    const void* ff1_w = d_in[9];
    const void* ff1_b = d_in[10];
    const void* ff2_w = d_in[11];
    const void* ff2_b = d_in[12];

    char* ws = (char*)d_ws;
    float*          xf     = (float*)ws;                            // 8 MB fp32 residual
    unsigned short* h_bf   = (unsigned short*)(ws + (8u  << 20));   // 4 MB LN out
    unsigned short* qkv_bf = (unsigned short*)(ws + (12u << 20));   // 12 MB (attn half)
    unsigned short* ff_bf  = (unsigned short*)(ws + (12u << 20));   // 16 MB (ff half)
    unsigned short* vt_bf  = (unsigned short*)(ws + (24u << 20));   // 4 MB V^T (attn half)
    unsigned short* o_bf   = (unsigned short*)(ws + (28u << 20));   // 4 MB
    unsigned short* wT     = (unsigned short*)(ws + (32u << 20));   // 8 MB transposed weight (fallback)
    unsigned short* vecs   = (unsigned short*)(ws + (40u << 20));   // 80 KB canonical vecs
    int*            flag   = (int*)(ws + (40u << 20) + (128u << 10));
    unsigned long long* mbits = (unsigned long long*)(ws + (40u << 20) + (192u << 10)); // 256 KB
    float*          slab   = (float*)(ws + (41u << 20));            // up to 32 MB split-K slabs
    unsigned short* wTall  = (unsigned short*)(ws + (73ull << 20)); // 96 MB all-layer weights

    const bool slabs_ok = ws_size >= (74ull << 20);
    const bool bigws    = ws_size >= (170ull << 20);

    sniff_kernel<<<1, 256, 0, stream>>>((const unsigned short*)x, flag);

    conv_all<<<dim3(64, 7), 256, 0, stream>>>(ln1_g, ln1_b, out_b, ln2_g, ln2_b, ff2_b, ff1_b,
                                              vecs, flag);
    mask_pack<<<512, 256, 0, stream>>>(mask, mbits);

    // fused cvt_x + first pre-attn LN (layer 0)
    ln_raw<<<MROWS, 256, 0, stream>>>(x, xf, vecs + 0, vecs + 1024, h_bf, flag);

    if (bigws)  // all 16 weight transposes in one launch
        transpose_all<<<dim3(12288, 4), dim3(32, 8), 0, stream>>>(
            qkv_w, out_w, ff1_w, ff2_w, wTall, flag);

    const int nx = MROWS * DIMM;  // 2M

    for (int l = 0; l < DEPTHN; l++) {
        const unsigned short* lv = vecs + l * VSTR;
        const unsigned short* lvn = vecs + (l + 1) * VSTR;  // next layer's vecs (l<3)

        const unsigned short* lbase = bigws ? wTall + (size_t)l * (12u * 1024 * 1024) : wT;
        const unsigned short* qkvT = lbase;
        const unsigned short* outT = lbase + 3 * 1024 * 1024;
        const unsigned short* ff1T = bigws ? lbase + 4 * 1024 * 1024 : wT;
        const unsigned short* ff2T = bigws ? lbase + 8 * 1024 * 1024 : wT;

        // --- attention half ---
        if (!bigws)
            transpose_attn<<<4096, dim3(32, 8), 0, stream>>>(qkv_w, out_w, l, wT, flag);
        gemm_bt<0, 1><<<dim3(3072 / 128, MROWS / 128), 512, 0, stream>>>(
            h_bf, qkvT, nullptr, qkv_bf, nullptr, MROWS, 3072, 1024);
        vt_kernel<<<dim3(32, 32, BB), dim3(32, 8), 0, stream>>>(qkv_bf, vt_bf);
        attn_mfma<<<dim3(NSEQ / 64, HEADSN, BB), 256, 0, stream>>>(qkv_bf, vt_bf, mbits, o_bf);
        if (slabs_ok) {
            gemm_bt<3, 2><<<dim3(1024 / 128, MROWS / 128, 2), 512, 0, stream>>>(
                o_bf, outT, nullptr, nullptr, slab, MROWS, 1024, 1024);
            reduce_ln<2, 1><<<MROWS, 256, 0, stream>>>(
                slab, lv + 2048, xf, lv + 3072, lv + 4096, h_bf);
        } else {
            gemm_bt<1, 2><<<dim3(1024 / 128, MROWS / 128, 2), 512, 0, stream>>>(
                o_bf, outT, lv + 2048, nullptr, xf, MROWS, 1024, 1024);
            ln_kernel<<<MROWS, 256, 0, stream>>>(xf, lv + 3072, lv + 4096, h_bf);
        }

        // --- feedforward half ---
        if (!bigws)
            transpose_conv<<<dim3(4096 / 32, 1024 / 32), dim3(32, 8), 0, stream>>>(
                ff1_w, (size_t)l * 1024 * 4096, wT, 1024, 4096, flag);
        gemm_bt<2, 1><<<dim3(4096 / 128, MROWS / 128), 512, 0, stream>>>(
            h_bf, ff1T, lv + 6144, ff_bf, nullptr, MROWS, 4096, 1024);
        if (!bigws)
            transpose_conv<<<dim3(1024 / 32, 4096 / 32), dim3(32, 8), 0, stream>>>(
                ff2_w, (size_t)l * 4096 * 1024, wT, 4096, 1024, flag);
        if (slabs_ok) {
            gemm_bt<3, 4><<<dim3(1024 / 128, MROWS / 128, 4), 512, 0, stream>>>(
                ff_bf, ff2T, nullptr, nullptr, slab, MROWS, 1024, 4096);
            if (l < DEPTHN - 1)
                reduce_ln<4, 1><<<MROWS, 256, 0, stream>>>(
                    slab, lv + 5120, xf, lvn + 0, lvn + 1024, h_bf);
            else
                reduce_ln<4, 0><<<MROWS, 256, 0, stream>>>(
                    slab, lv + 5120, xf, nullptr, nullptr, nullptr);
        } else {
            gemm_bt<1, 4><<<dim3(1024 / 128, MROWS / 128, 4), 512, 0, stream>>>(
                ff_bf, ff2T, lv + 5120, nullptr, xf, MROWS, 1024, 4096);
            if (l < DEPTHN - 1)
                ln_kernel<<<MROWS, 256, 0, stream>>>(xf, lvn + 0, lvn + 1024, h_bf);
        }
    }

    store_out<<<nx / 256, 256, 0, stream>>>(xf, d_out, flag);
}

// Round 7
// 812.751 us; speedup vs baseline: 1.2817x; 1.0186x over previous
//
#include <hip/hip_runtime.h>
#include <stdint.h>

#define DIMM 1024
#define NSEQ 1024
#define BB 2
#define HEADSN 16
#define MLPD 4096
#define DEPTHN 4
#define MROWS (BB*NSEQ)  // 2048
#define VSTR 10240       // canonical per-layer vec stride (elements)

typedef __bf16 bf16x8 __attribute__((ext_vector_type(8)));
typedef float f32x4 __attribute__((ext_vector_type(4)));

__device__ __forceinline__ float bf2f(unsigned short u) {
    union { uint32_t i; float f; } x; x.i = ((uint32_t)u) << 16; return x.f;
}
__device__ __forceinline__ unsigned short f2bf(float f) {
    union { uint32_t i; float f; } x; x.f = f;
    uint32_t r = x.i + 0x7fffu + ((x.i >> 16) & 1u);
    return (unsigned short)(r >> 16);
}
__device__ __forceinline__ float loadf(const void* p, size_t i, int f32) {
    return f32 ? ((const float*)p)[i] : bf2f(((const unsigned short*)p)[i]);
}
// packed f32x2 -> bf16x2 (RNE), single HW instruction on gfx950
__device__ __forceinline__ uint32_t cvt_pk_bf16(float lo, float hi) {
    uint32_t r;
    asm("v_cvt_pk_bf16_f32 %0, %1, %2" : "=v"(r) : "v"(lo), "v"(hi));
    return r;
}

// async global->LDS, 16B per lane; LDS dest = wave-uniform base + lane*16
__device__ __forceinline__ void gl_lds16(const unsigned short* g, unsigned short* l) {
    __builtin_amdgcn_global_load_lds(
        (const __attribute__((address_space(1))) uint32_t*)g,
        (__attribute__((address_space(3))) uint32_t*)l,
        16, 0, 0);
}

// counted vmcnt waits (keep next-tile loads in flight across barriers)
__device__ __forceinline__ void wait_vm4() { asm volatile("s_waitcnt vmcnt(4)" ::: "memory"); }
__device__ __forceinline__ void wait_vm0() { asm volatile("s_waitcnt vmcnt(0)" ::: "memory"); }
// raw barrier fenced so the compiler can't move LDS ops across it
__device__ __forceinline__ void barrier_sync() {
    asm volatile("" ::: "memory");
    __builtin_amdgcn_s_barrier();
    asm volatile("" ::: "memory");
}

// ---------------- dtype sniff ----------------
__global__ __launch_bounds__(256) void sniff_kernel(const unsigned short* __restrict__ x,
                                                    int* __restrict__ flag) {
    __shared__ int cnt[256];
    int tid = threadIdx.x;
    int c = 0;
    for (int i = tid * 2; i < 65536; i += 512) {
        int e = (x[i] >> 7) & 0xFF;
        if (e >= 0x8A) c++;
    }
    cnt[tid] = c;
    __syncthreads();
    for (int s = 128; s > 0; s >>= 1) {
        if (tid < s) cnt[tid] += cnt[tid + s];
        __syncthreads();
    }
    if (tid == 0) flag[0] = (cnt[0] > 32) ? 1 : 0;
}

// ---------------- converts ----------------
__global__ __launch_bounds__(256) void store_out(const float* __restrict__ xf, void* __restrict__ out,
                                                 const int* __restrict__ flag) {
    int f = flag[0];
    int i = blockIdx.x * 256 + threadIdx.x;
    float v = xf[i];
    if (f) ((float*)out)[i] = v;
    else   ((unsigned short*)out)[i] = f2bf(v);
}
// all 7 small vectors in one launch; grid (64, 7)
__global__ __launch_bounds__(256) void conv_all(const void* s0, const void* s1, const void* s2,
                                                const void* s3, const void* s4, const void* s5,
                                                const void* s6, unsigned short* __restrict__ dst,
                                                const int* __restrict__ flag) {
    int f = flag[0];
    const void* src; int len, off;
    switch (blockIdx.y) {
        case 0: src = s0; len = 1024; off = 0;    break;
        case 1: src = s1; len = 1024; off = 1024; break;
        case 2: src = s2; len = 1024; off = 2048; break;
        case 3: src = s3; len = 1024; off = 3072; break;
        case 4: src = s4; len = 1024; off = 4096; break;
        case 5: src = s5; len = 1024; off = 5120; break;
        default: src = s6; len = 4096; off = 6144; break;
    }
    int i = blockIdx.x * 256 + threadIdx.x;
    if (i < DEPTHN * len) {
        int l = i / len, o = i - l * len;
        dst[l * VSTR + off + o] = f2bf(loadf(src, i, f));
    }
}

// ---------------- transpose+convert (scalar fallback) ----------------
__global__ __launch_bounds__(256) void transpose_conv(const void* __restrict__ in, size_t srcOffE,
                                                      unsigned short* __restrict__ out,
                                                      int K, int N, const int* __restrict__ flag) {
    int f = flag[0];
    __shared__ unsigned short t[32][33];
    int n0 = blockIdx.x * 32, k0 = blockIdx.y * 32;
    int tx = threadIdx.x, ty = threadIdx.y;  // 32 x 8
#pragma unroll
    for (int i = 0; i < 4; i++) {
        int k = k0 + ty + i * 8;
        t[ty + i * 8][tx] = f2bf(loadf(in, srcOffE + (size_t)k * N + n0 + tx, f));
    }
    __syncthreads();
#pragma unroll
    for (int i = 0; i < 4; i++) {
        int n = n0 + ty + i * 8;
        out[(size_t)n * K + k0 + tx] = t[tx][ty + i * 8];
    }
}

// ---------------- batched attn-half transpose (scalar fallback path) ----------------
__global__ __launch_bounds__(256) void transpose_attn(const void* __restrict__ qkvw,
                                                      const void* __restrict__ outw,
                                                      int layer, unsigned short* __restrict__ wT,
                                                      const int* __restrict__ flag) {
    int f = flag[0];
    __shared__ unsigned short t[32][33];
    int id = blockIdx.x;
    const void* src; int N; size_t soff; unsigned short* dst; int bx, by;
    if (id < 3072) {
        N = 3072; bx = id % 96; by = id / 96;
        src = qkvw; soff = (size_t)layer * 1024 * 3072; dst = wT;
    } else {
        id -= 3072; N = 1024; bx = id % 32; by = id / 32;
        src = outw; soff = (size_t)layer * 1024 * 1024; dst = wT + 3 * 1024 * 1024;
    }
    int n0 = bx * 32, k0 = by * 32;
    int tx = threadIdx.x, ty = threadIdx.y;  // 32 x 8
#pragma unroll
    for (int i = 0; i < 4; i++) {
        int k = k0 + ty + i * 8;
        t[ty + i * 8][tx] = f2bf(loadf(src, soff + (size_t)k * N + n0 + tx, f));
    }
    __syncthreads();
#pragma unroll
    for (int i = 0; i < 4; i++) {
        int n = n0 + ty + i * 8;
        dst[(size_t)n * 1024 + k0 + tx] = t[tx][ty + i * 8];
    }
}

// ---------------- ALL weight transposes, vectorized 64x64 tiles ----------------
// grid (3072, 4).  Per-layer block ids: [0,768) qkv (16k x 48n tiles), [768,1024) out (16x16),
// [1024,2048) ff1 (16x64), [2048,3072) ff2 (64x16).  Per-layer arena stride 12M elements:
//   qkvT @0 (3072x1024), outT @3M (1024x1024), ff1T @4M (4096x1024), ff2T @8M (1024x4096).
// Phase 1: float4 loads (256 B/row coalesced) + cvt_pk -> u32 LDS writes, [64][70] stride
// (70 -> phase-2 column gather is 2 lanes/bank = free; all accesses 4/8 B aligned).
// Phase 2: 4x u16 gather + ushort4 store (128 B/row coalesced).
__global__ __launch_bounds__(256) void transpose_all(const void* __restrict__ qkvw,
                                                     const void* __restrict__ outw,
                                                     const void* __restrict__ ff1w,
                                                     const void* __restrict__ ff2w,
                                                     unsigned short* __restrict__ wTall,
                                                     const int* __restrict__ flag) {
    int f = flag[0];
    __shared__ unsigned short t[64 * 70];
    int id = blockIdx.x;
    int l = blockIdx.y;
    unsigned short* base = wTall + (size_t)l * (12u * 1024 * 1024);
    const void* src; int K, N; size_t soff; unsigned short* dst;
    if (id < 768)       { src = qkvw; K = 1024; N = 3072; soff = (size_t)l * 1024 * 3072; dst = base; }
    else if (id < 1024) { id -= 768;  src = outw; K = 1024; N = 1024; soff = (size_t)l * 1024 * 1024; dst = base + 3 * 1024 * 1024; }
    else if (id < 2048) { id -= 1024; src = ff1w; K = 1024; N = 4096; soff = (size_t)l * 1024 * 4096; dst = base + 4 * 1024 * 1024; }
    else                { id -= 2048; src = ff2w; K = 4096; N = 1024; soff = (size_t)l * 4096 * 1024; dst = base + 8 * 1024 * 1024; }
    int nb = N >> 6;
    int by = id / nb, bx = id - by * nb;
    int n0 = bx * 64, k0 = by * 64;
    int tid = threadIdx.x;
    int tx = tid & 15, ty = tid >> 4;  // 16 x 16
#pragma unroll
    for (int i = 0; i < 4; i++) {
        int r = ty + i * 16;
        size_t s = soff + (size_t)(k0 + r) * N + n0 + tx * 4;
        uint32_t w0, w1;
        if (f) {
            float4 v = *(const float4*)((const float*)src + s);
            w0 = cvt_pk_bf16(v.x, v.y);
            w1 = cvt_pk_bf16(v.z, v.w);
        } else {
            uint2 v = *(const uint2*)((const unsigned short*)src + s);
            w0 = v.x; w1 = v.y;
        }
        *(uint32_t*)&t[r * 70 + tx * 4]     = w0;
        *(uint32_t*)&t[r * 70 + tx * 4 + 2] = w1;
    }
    __syncthreads();
#pragma unroll
    for (int i = 0; i < 4; i++) {
        int n = ty + i * 16;
        ushort4 o;
        o.x = t[(tx * 4 + 0) * 70 + n];
        o.y = t[(tx * 4 + 1) * 70 + n];
        o.z = t[(tx * 4 + 2) * 70 + n];
        o.w = t[(tx * 4 + 3) * 70 + n];
        *(ushort4*)&dst[(size_t)(n0 + n) * K + k0 + tx * 4] = o;
    }
}

// ---------------- V^T per layer, vectorized 64x64 tiles; grid (16, 16, 2) ----------------
__global__ __launch_bounds__(256) void vt_kernel(const unsigned short* __restrict__ qkv,
                                                 unsigned short* __restrict__ vt) {
    __shared__ unsigned short t[64 * 70];
    int b = blockIdx.z;
    int c0 = blockIdx.x * 64, k0 = blockIdx.y * 64;
    int tid = threadIdx.x;
    int tx = tid & 15, ty = tid >> 4;  // 16 x 16
#pragma unroll
    for (int i = 0; i < 4; i++) {
        int r = ty + i * 16;
        uint2 v = *(const uint2*)&qkv[(size_t)(b * 1024 + k0 + r) * 3072 + 2048 + c0 + tx * 4];
        *(uint32_t*)&t[r * 70 + tx * 4]     = v.x;
        *(uint32_t*)&t[r * 70 + tx * 4 + 2] = v.y;
    }
    __syncthreads();
#pragma unroll
    for (int i = 0; i < 4; i++) {
        int c = ty + i * 16;
        ushort4 o;
        o.x = t[(tx * 4 + 0) * 70 + c];
        o.y = t[(tx * 4 + 1) * 70 + c];
        o.z = t[(tx * 4 + 2) * 70 + c];
        o.w = t[(tx * 4 + 3) * 70 + c];
        *(ushort4*)&vt[(size_t)(b * 1024 + c0 + c) * 1024 + k0 + tx * 4] = o;
    }
}

// ---------------- mask -> bitmask u64 words ----------------
__global__ __launch_bounds__(256) void mask_pack(const int* __restrict__ mask,
                                                 unsigned long long* __restrict__ bits) {
    int wid = (blockIdx.x * 256 + threadIdx.x) >> 6;
    int lane = threadIdx.x & 63;
#pragma unroll
    for (int i = 0; i < 16; i++) {
        int w = wid * 16 + i;
        int mv = mask[(size_t)w * 64 + lane];
        unsigned long long bl = __ballot(mv != 0);
        if (lane == 0) bits[w] = bl;
    }
}

// ---------------- fused cvt + LayerNorm from raw x (first pre-attn LN) ----------------
__global__ __launch_bounds__(256) void ln_raw(const void* __restrict__ x, float* __restrict__ xf,
                                              const unsigned short* __restrict__ g,
                                              const unsigned short* __restrict__ bta,
                                              unsigned short* __restrict__ out,
                                              const int* __restrict__ flag) {
    int f = flag[0];
    int row = blockIdx.x, tid = threadIdx.x;
    size_t base = (size_t)row * DIMM;
    float v[4]; float s = 0.f, s2 = 0.f;
#pragma unroll
    for (int i = 0; i < 4; i++) {
        int c = tid + i * 256;
        v[i] = loadf(x, base + c, f);
        xf[base + c] = v[i];
        s += v[i]; s2 += v[i] * v[i];
    }
#pragma unroll
    for (int off = 32; off >= 1; off >>= 1) {
        s  += __shfl_down(s, off, 64);
        s2 += __shfl_down(s2, off, 64);
    }
    __shared__ float rs[4], rs2[4];
    int wv = tid >> 6;
    if ((tid & 63) == 0) { rs[wv] = s; rs2[wv] = s2; }
    __syncthreads();
    s  = rs[0] + rs[1] + rs[2] + rs[3];
    s2 = rs2[0] + rs2[1] + rs2[2] + rs2[3];
    float mu  = s * (1.f / DIMM);
    float var = s2 * (1.f / DIMM) - mu * mu;
    float rr  = rsqrtf(var + 1e-5f);
#pragma unroll
    for (int i = 0; i < 4; i++) {
        int c = tid + i * 256;
        float y = (v[i] - mu) * rr * bf2f(g[c]) + bf2f(bta[c]);
        out[base + c] = f2bf(y);
    }
}

// ---------------- LayerNorm (standalone fallback) ----------------
__global__ __launch_bounds__(256) void ln_kernel(const float* __restrict__ x,
                                                 const unsigned short* __restrict__ g,
                                                 const unsigned short* __restrict__ bta,
                                                 unsigned short* __restrict__ out) {
    int row = blockIdx.x, tid = threadIdx.x;
    const float* xr = x + (size_t)row * DIMM;
    float v[4]; float s = 0.f, s2 = 0.f;
#pragma unroll
    for (int i = 0; i < 4; i++) { v[i] = xr[tid + i * 256]; s += v[i]; s2 += v[i] * v[i]; }
#pragma unroll
    for (int off = 32; off >= 1; off >>= 1) {
        s  += __shfl_down(s, off, 64);
        s2 += __shfl_down(s2, off, 64);
    }
    __shared__ float rs[4], rs2[4];
    int wv = tid >> 6;
    if ((tid & 63) == 0) { rs[wv] = s; rs2[wv] = s2; }
    __syncthreads();
    s  = rs[0] + rs[1] + rs[2] + rs[3];
    s2 = rs2[0] + rs2[1] + rs2[2] + rs2[3];
    float mu  = s * (1.f / DIMM);
    float var = s2 * (1.f / DIMM) - mu * mu;
    float rr  = rsqrtf(var + 1e-5f);
#pragma unroll
    for (int i = 0; i < 4; i++) {
        int c = tid + i * 256;
        float y = (v[i] - mu) * rr * bf2f(g[c]) + bf2f(bta[c]);
        out[(size_t)row * DIMM + c] = f2bf(y);
    }
}

// ---------------- split-K slab reduce + residual update (+ optional fused LN) ----------------
template <int S, int HAS_LN>
__global__ __launch_bounds__(256) void reduce_ln(const float* __restrict__ slab,
                                                 const unsigned short* __restrict__ bias,
                                                 float* __restrict__ xf,
                                                 const unsigned short* __restrict__ g,
                                                 const unsigned short* __restrict__ bta,
                                                 unsigned short* __restrict__ out) {
    const size_t SL = (size_t)MROWS * DIMM;
    int row = blockIdx.x, tid = threadIdx.x;
    float v[4]; float s = 0.f, s2 = 0.f;
#pragma unroll
    for (int i = 0; i < 4; i++) {
        int c = tid + i * 256;
        size_t idx = (size_t)row * DIMM + c;
        float t = xf[idx] + bf2f(bias[c]);
#pragma unroll
        for (int z = 0; z < S; z++) t += slab[z * SL + idx];
        xf[idx] = t;
        v[i] = t; s += t; s2 += t * t;
    }
    if (HAS_LN) {
#pragma unroll
        for (int off = 32; off >= 1; off >>= 1) {
            s  += __shfl_down(s, off, 64);
            s2 += __shfl_down(s2, off, 64);
        }
        __shared__ float rs[4], rs2[4];
        int wv = tid >> 6;
        if ((tid & 63) == 0) { rs[wv] = s; rs2[wv] = s2; }
        __syncthreads();
        s  = rs[0] + rs[1] + rs[2] + rs[3];
        s2 = rs2[0] + rs2[1] + rs2[2] + rs2[3];
        float mu  = s * (1.f / DIMM);
        float var = s2 * (1.f / DIMM) - mu * mu;
        float rr  = rsqrtf(var + 1e-5f);
#pragma unroll
        for (int i = 0; i < 4; i++) {
            int c = tid + i * 256;
            float y = (v[i] - mu) * rr * bf2f(g[c]) + bf2f(bta[c]);
            out[(size_t)row * DIMM + c] = f2bf(y);
        }
    }
}

// ---------------- GEMM (8-wave 128x128 tile, BK=64, dbuf + counted vmcnt) ----------------
// (unchanged from R3 BK=64 version; see comments there)
template <int MODE, int SPLITK>
__global__ __launch_bounds__(512) void gemm_bt(const unsigned short* __restrict__ A,
                                               const unsigned short* __restrict__ Bt,
                                               const unsigned short* __restrict__ bias,
                                               unsigned short* __restrict__ Cbf,
                                               float* __restrict__ Cres,
                                               int M, int N, int K) {
    __shared__ __align__(16) unsigned short As0[128 * 64];
    __shared__ __align__(16) unsigned short Bs0[128 * 64];
    __shared__ __align__(16) unsigned short As1[128 * 64];
    __shared__ __align__(16) unsigned short Bs1[128 * 64];
    const int tid = threadIdx.x;
    const int mBase = blockIdx.y * 128, nBase = blockIdx.x * 128;
    const int w = tid >> 6, lane = tid & 63;
    const int wm = (w >> 2) * 64, wn = (w & 3) * 32;
    const int quad = lane >> 4, l16 = lane & 15;
    const int kLen = K / SPLITK;
    const int kStart = (SPLITK > 1) ? blockIdx.z * kLen : 0;
    const int NT = kLen / 64;

    f32x4 acc[4][2];
#pragma unroll
    for (int i = 0; i < 4; i++)
#pragma unroll
        for (int j = 0; j < 2; j++) acc[i][j] = (f32x4){0.f, 0.f, 0.f, 0.f};

    const int wb = w & 3;
    const int lr8 = lane >> 3;
    const int sgran = (lane & 7) ^ lr8;
    const unsigned short* G = (w < 4 ? A  + (size_t)(mBase + wb * 32 + lr8) * K
                                     : Bt + (size_t)(nBase + wb * 32 + lr8) * K)
                              + kStart + sgran * 8;
    unsigned short* S0 = (w < 4 ? As0 : Bs0) + (wb * 32) * 64;
    unsigned short* S1 = (w < 4 ? As1 : Bs1) + (wb * 32) * 64;
    const size_t r8 = (size_t)8 * K;

    const int rg0 = (quad ^ (l16 & 7)) * 8;
    const int rg1 = ((4 + quad) ^ (l16 & 7)) * 8;

    auto stage = [&](unsigned short* S, int t) {
        const unsigned short* g = G + (size_t)t * 64;
#pragma unroll
        for (int i = 0; i < 4; i++)
            gl_lds16(g + (size_t)i * r8, S + i * 8 * 64);
    };
    auto compute = [&](const unsigned short* Asb, const unsigned short* Bsb) {
#pragma unroll
        for (int ks = 0; ks < 2; ks++) {
            const int rg = ks ? rg1 : rg0;
            bf16x8 af[4], bfv[2];
#pragma unroll
            for (int i = 0; i < 4; i++)
                af[i] = *(const bf16x8*)&Asb[(wm + i * 16 + l16) * 64 + rg];
#pragma unroll
            for (int j = 0; j < 2; j++)
                bfv[j] = *(const bf16x8*)&Bsb[(wn + j * 16 + l16) * 64 + rg];
#pragma unroll
            for (int i = 0; i < 4; i++)
#pragma unroll
                for (int j = 0; j < 2; j++)
                    acc[i][j] = __builtin_amdgcn_mfma_f32_16x16x32_bf16(af[i], bfv[j], acc[i][j], 0, 0, 0);
        }
    };

    stage(S0, 0);
    for (int t = 0; t < NT; t += 2) {
        stage(S1, t + 1);
        wait_vm4();
        barrier_sync();
        compute(As0, Bs0);
        barrier_sync();
        if (t + 2 < NT) {
            stage(S0, t + 2);
            wait_vm4();
        } else {
            wait_vm0();
        }
        barrier_sync();
        compute(As1, Bs1);
        barrier_sync();
    }

    const size_t slabOff = (MODE == 3) ? (size_t)blockIdx.z * M * N : 0;
#pragma unroll
    for (int i = 0; i < 4; i++) {
#pragma unroll
        for (int j = 0; j < 2; j++) {
#pragma unroll
            for (int r = 0; r < 4; r++) {
                int m = mBase + wm + i * 16 + quad * 4 + r;
                int n = nBase + wn + j * 16 + l16;
                float v = acc[i][j][r];
                size_t idx = (size_t)m * N + n;
                if (MODE == 0) {
                    Cbf[idx] = f2bf(v);
                } else if (MODE == 1) {
                    if (SPLITK > 1) {
                        if (blockIdx.z == 0) v += bf2f(bias[n]);
                        atomicAdd(&Cres[idx], v);
                    } else {
                        Cres[idx] += v + bf2f(bias[n]);
                    }
                } else if (MODE == 2) {
                    float t2 = v + bf2f(bias[n]);
                    float gg = 0.5f * t2 * (1.f + erff(t2 * 0.70710678118f));
                    Cbf[idx] = f2bf(gg);
                } else {
                    Cres[slabOff + idx] = v;
                }
            }
        }
    }
}

// ---------------- MFMA flash attention (swapped-QK, in-register P, dbuf K/V pipeline) ----------------
__global__ __launch_bounds__(256) void attn_mfma(const unsigned short* __restrict__ qkv,
                                                 const unsigned short* __restrict__ vt,
                                                 const unsigned long long* __restrict__ mbits,
                                                 unsigned short* __restrict__ o) {
    __shared__ __align__(16) unsigned short Ks[2][64 * 72];
    __shared__ __align__(16) unsigned short Vs[2][64 * 72];

    const int tid = threadIdx.x, w = tid >> 6, lane = tid & 63;
    const int quad = lane >> 4, l16 = lane & 15;
    const int qt = blockIdx.x, h = blockIdx.y, b = blockIdx.z;

    const size_t qrow = (size_t)(b * NSEQ + qt * 64 + w * 16 + l16) * 3072 + h * 64;
    bf16x8 qf[2];
    qf[0] = *(const bf16x8*)(qkv + qrow + quad * 8);
    qf[1] = *(const bf16x8*)(qkv + qrow + 32 + quad * 8);

    const int srow = tid >> 2, scol = (tid & 3) * 16;
    const unsigned short* kg0 = qkv + (size_t)(b * NSEQ) * 3072 + 1024 + h * 64
                                + (size_t)srow * 3072 + scol;
    const unsigned short* vg0 = vt + (size_t)((b * HEADSN + h) * 64 + srow) * 1024 + scol;

    f32x4 oacc[4];
#pragma unroll
    for (int j = 0; j < 4; j++) oacc[j] = (f32x4){0.f, 0.f, 0.f, 0.f};
    float m_run = -1e30f, l_run = 0.f;

    const unsigned long long* mb = mbits + ((size_t)(b * NSEQ + qt * 64 + w * 16 + l16)) * 16;

    // prologue: stage kt=0 into buf 0
    uint4 ka = *(const uint4*)kg0;
    uint4 kb = *(const uint4*)(kg0 + 8);
    uint4 va = *(const uint4*)vg0;
    uint4 vb = *(const uint4*)(vg0 + 8);
    *(uint4*)&Ks[0][srow * 72 + scol]     = ka;
    *(uint4*)&Ks[0][srow * 72 + scol + 8] = kb;
    *(uint4*)&Vs[0][srow * 72 + scol]     = va;
    *(uint4*)&Vs[0][srow * 72 + scol + 8] = vb;
    unsigned long long mw = mb[0];
    int cur = 0;

    for (int kt = 0; kt < 16; kt++) {
        __syncthreads();  // buf[cur] writes visible; prior iter's reads of buf[cur^1] done

        unsigned long long mw_n = 0;
        if (kt < 15) {  // issue kt+1 loads now; consumed (LDS-written) after compute
            const unsigned short* kg = kg0 + (size_t)(kt + 1) * 64 * 3072;
            ka = *(const uint4*)kg;
            kb = *(const uint4*)(kg + 8);
            const unsigned short* vg = vg0 + (kt + 1) * 64;
            va = *(const uint4*)vg;
            vb = *(const uint4*)(vg + 8);
            mw_n = mb[kt + 1];
        }

        // S^T: sacc[j][r] = S[q=l16][k = j*16 + quad*4 + r]
        f32x4 sacc[4];
#pragma unroll
        for (int j = 0; j < 4; j++) sacc[j] = (f32x4){0.f, 0.f, 0.f, 0.f};
        __builtin_amdgcn_s_setprio(1);
#pragma unroll
        for (int ks = 0; ks < 2; ks++) {
#pragma unroll
            for (int j = 0; j < 4; j++) {
                bf16x8 kf = *(const bf16x8*)&Ks[cur][(j * 16 + l16) * 72 + ks * 32 + quad * 8];
                sacc[j] = __builtin_amdgcn_mfma_f32_16x16x32_bf16(kf, qf[ks], sacc[j], 0, 0, 0);
            }
        }
        __builtin_amdgcn_s_setprio(0);

        float t[4][4];
        float mxj[4];
#pragma unroll
        for (int j = 0; j < 4; j++) {
            unsigned nib = (unsigned)(mw >> (quad * 4 + j * 16)) & 0xFu;
#pragma unroll
            for (int r = 0; r < 4; r++) {
                float s = sacc[j][r] * 0.125f;
                t[j][r] = ((nib >> r) & 1u) ? s : -1e30f;
            }
            mxj[j] = fmaxf(fmaxf(t[j][0], t[j][1]), fmaxf(t[j][2], t[j][3]));
        }
        float mx = fmaxf(fmaxf(mxj[0], mxj[1]), fmaxf(mxj[2], mxj[3]));
        mx = fmaxf(mx, __shfl_xor(mx, 16, 64));
        mx = fmaxf(mx, __shfl_xor(mx, 32, 64));

        if (!__all(mx <= m_run)) {
            float m_new = fmaxf(m_run, mx);
            float alpha = __expf(m_run - m_new);
            m_run = m_new;
            l_run *= alpha;
            float al[4];
#pragma unroll
            for (int r = 0; r < 4; r++) al[r] = __shfl(alpha, quad * 4 + r, 64);
#pragma unroll
            for (int j = 0; j < 4; j++)
#pragma unroll
                for (int r = 0; r < 4; r++) oacc[j][r] *= al[r];
        }

        float p[4][4];
        float psj[4];
#pragma unroll
        for (int j = 0; j < 4; j++) {
#pragma unroll
            for (int r = 0; r < 4; r++) p[j][r] = __expf(t[j][r] - m_run);
            psj[j] = (p[j][0] + p[j][1]) + (p[j][2] + p[j][3]);
        }
        float ps = (psj[0] + psj[1]) + (psj[2] + psj[3]);
        ps += __shfl_xor(ps, 16, 64);
        ps += __shfl_xor(ps, 32, 64);
        l_run += ps;

        union { uint32_t u[4]; bf16x8 v; } pa[2];
#pragma unroll
        for (int ks = 0; ks < 2; ks++) {
            pa[ks].u[0] = cvt_pk_bf16(p[2 * ks][0],     p[2 * ks][1]);
            pa[ks].u[1] = cvt_pk_bf16(p[2 * ks][2],     p[2 * ks][3]);
            pa[ks].u[2] = cvt_pk_bf16(p[2 * ks + 1][0], p[2 * ks + 1][1]);
            pa[ks].u[3] = cvt_pk_bf16(p[2 * ks + 1][2], p[2 * ks + 1][3]);
        }

        __builtin_amdgcn_s_setprio(1);
#pragma unroll
        for (int ks = 0; ks < 2; ks++) {
#pragma unroll
            for (int j = 0; j < 4; j++) {
                union { ushort4 u[2]; bf16x8 v; } vf;
                const unsigned short* vp = &Vs[cur][(j * 16 + l16) * 72 + ks * 32 + quad * 4];
                vf.u[0] = *(const ushort4*)vp;
                vf.u[1] = *(const ushort4*)(vp + 16);
                oacc[j] = __builtin_amdgcn_mfma_f32_16x16x32_bf16(pa[ks].v, vf.v, oacc[j], 0, 0, 0);
            }
        }
        __builtin_amdgcn_s_setprio(0);

        if (kt < 15) {  // write-late: land kt+1 into the other buffer
            *(uint4*)&Ks[cur ^ 1][srow * 72 + scol]     = ka;
            *(uint4*)&Ks[cur ^ 1][srow * 72 + scol + 8] = kb;
            *(uint4*)&Vs[cur ^ 1][srow * 72 + scol]     = va;
            *(uint4*)&Vs[cur ^ 1][srow * 72 + scol + 8] = vb;
            mw = mw_n;
            cur ^= 1;
        }
    }

    float inv[4];
#pragma unroll
    for (int r = 0; r < 4; r++) {
        float lr = __shfl(l_run, quad * 4 + r, 64);
        inv[r] = 1.f / lr;
    }
#pragma unroll
    for (int j = 0; j < 4; j++) {
#pragma unroll
        for (int r = 0; r < 4; r++) {
            size_t row = (size_t)(b * NSEQ + qt * 64 + w * 16 + quad * 4 + r);
            o[row * 1024 + h * 64 + j * 16 + l16] = f2bf(oacc[j][r] * inv[r]);
        }
    }
}

extern "C" void kernel_launch(void* const* d_in, const int* in_sizes, int n_in,
                              void* d_out, int out_size, void* d_ws, size_t ws_size,
                              hipStream_t stream) {
    const void* x     = d_in[0];
    const int*  mask  = (const int*)d_in[1];
    const void* ln1_g = d_in[2];
    const void* ln1_b = d_in[3];
    const void* qkv_w = d_in[4];
    const void* out_w = d_in[5];
    const void* out_b = d_in[6];
    const void* ln2_g = d_in[7];
    const void* ln2_b = d_in[8];
    const void* ff1_w = d_in[9];
    const void* ff1_b = d_in[10];
    const void* ff2_w = d_in[11];
    const void* ff2_b = d_in[12];

    char* ws = (char*)d_ws;
    float*          xf     = (float*)ws;                            // 8 MB fp32 residual
    unsigned short* h_bf   = (unsigned short*)(ws + (8u  << 20));   // 4 MB LN out
    unsigned short* qkv_bf = (unsigned short*)(ws + (12u << 20));   // 12 MB (attn half)
    unsigned short* ff_bf  = (unsigned short*)(ws + (12u << 20));   // 16 MB (ff half)
    unsigned short* vt_bf  = (unsigned short*)(ws + (24u << 20));   // 4 MB V^T (attn half)
    unsigned short* o_bf   = (unsigned short*)(ws + (28u << 20));   // 4 MB
    unsigned short* wT     = (unsigned short*)(ws + (32u << 20));   // 8 MB transposed weight (fallback)
    unsigned short* vecs   = (unsigned short*)(ws + (40u << 20));   // 80 KB canonical vecs
    int*            flag   = (int*)(ws + (40u << 20) + (128u << 10));
    unsigned long long* mbits = (unsigned long long*)(ws + (40u << 20) + (192u << 10)); // 256 KB
    float*          slab   = (float*)(ws + (41u << 20));            // up to 32 MB split-K slabs
    unsigned short* wTall  = (unsigned short*)(ws + (73ull << 20)); // 96 MB all-layer weights

    const bool slabs_ok = ws_size >= (74ull << 20);
    const bool bigws    = ws_size >= (170ull << 20);

    sniff_kernel<<<1, 256, 0, stream>>>((const unsigned short*)x, flag);

    conv_all<<<dim3(64, 7), 256, 0, stream>>>(ln1_g, ln1_b, out_b, ln2_g, ln2_b, ff2_b, ff1_b,
                                              vecs, flag);
    mask_pack<<<512, 256, 0, stream>>>(mask, mbits);

    // fused cvt_x + first pre-attn LN (layer 0)
    ln_raw<<<MROWS, 256, 0, stream>>>(x, xf, vecs + 0, vecs + 1024, h_bf, flag);

    if (bigws)  // all 16 weight transposes in one vectorized launch
        transpose_all<<<dim3(3072, 4), 256, 0, stream>>>(
            qkv_w, out_w, ff1_w, ff2_w, wTall, flag);

    const int nx = MROWS * DIMM;  // 2M

    for (int l = 0; l < DEPTHN; l++) {
        const unsigned short* lv = vecs + l * VSTR;
        const unsigned short* lvn = vecs + (l + 1) * VSTR;  // next layer's vecs (l<3)

        const unsigned short* lbase = bigws ? wTall + (size_t)l * (12u * 1024 * 1024) : wT;
        const unsigned short* qkvT = lbase;
        const unsigned short* outT = lbase + 3 * 1024 * 1024;
        const unsigned short* ff1T = bigws ? lbase + 4 * 1024 * 1024 : wT;
        const unsigned short* ff2T = bigws ? lbase + 8 * 1024 * 1024 : wT;

        // --- attention half ---
        if (!bigws)
            transpose_attn<<<4096, dim3(32, 8), 0, stream>>>(qkv_w, out_w, l, wT, flag);
        gemm_bt<0, 1><<<dim3(3072 / 128, MROWS / 128), 512, 0, stream>>>(
            h_bf, qkvT, nullptr, qkv_bf, nullptr, MROWS, 3072, 1024);
        vt_kernel<<<dim3(16, 16, BB), 256, 0, stream>>>(qkv_bf, vt_bf);
        attn_mfma<<<dim3(NSEQ / 64, HEADSN, BB), 256, 0, stream>>>(qkv_bf, vt_bf, mbits, o_bf);
        if (slabs_ok) {
            gemm_bt<3, 2><<<dim3(1024 / 128, MROWS / 128, 2), 512, 0, stream>>>(
                o_bf, outT, nullptr, nullptr, slab, MROWS, 1024, 1024);
            reduce_ln<2, 1><<<MROWS, 256, 0, stream>>>(
                slab, lv + 2048, xf, lv + 3072, lv + 4096, h_bf);
        } else {
            gemm_bt<1, 2><<<dim3(1024 / 128, MROWS / 128, 2), 512, 0, stream>>>(
                o_bf, outT, lv + 2048, nullptr, xf, MROWS, 1024, 1024);
            ln_kernel<<<MROWS, 256, 0, stream>>>(xf, lv + 3072, lv + 4096, h_bf);
        }

        // --- feedforward half ---
        if (!bigws)
            transpose_conv<<<dim3(4096 / 32, 1024 / 32), dim3(32, 8), 0, stream>>>(
                ff1_w, (size_t)l * 1024 * 4096, wT, 1024, 4096, flag);
        gemm_bt<2, 1><<<dim3(4096 / 128, MROWS / 128), 512, 0, stream>>>(
            h_bf, ff1T, lv + 6144, ff_bf, nullptr, MROWS, 4096, 1024);
        if (!bigws)
            transpose_conv<<<dim3(1024 / 32, 4096 / 32), dim3(32, 8), 0, stream>>>(
                ff2_w, (size_t)l * 4096 * 1024, wT, 4096, 1024, flag);
        if (slabs_ok) {
            gemm_bt<3, 4><<<dim3(1024 / 128, MROWS / 128, 4), 512, 0, stream>>>(
                ff_bf, ff2T, nullptr, nullptr, slab, MROWS, 1024, 4096);
            if (l < DEPTHN - 1)
                reduce_ln<4, 1><<<MROWS, 256, 0, stream>>>(
                    slab, lv + 5120, xf, lvn + 0, lvn + 1024, h_bf);
            else
                reduce_ln<4, 0><<<MROWS, 256, 0, stream>>>(
                    slab, lv + 5120, xf, nullptr, nullptr, nullptr);
        } else {
            gemm_bt<1, 4><<<dim3(1024 / 128, MROWS / 128, 4), 512, 0, stream>>>(
                ff_bf, ff2T, lv + 5120, nullptr, xf, MROWS, 1024, 4096);
            if (l < DEPTHN - 1)
                ln_kernel<<<MROWS, 256, 0, stream>>>(xf, lvn + 0, lvn + 1024, h_bf);
        }
    }

    store_out<<<nx / 256, 256, 0, stream>>>(xf, d_out, flag);
}

// Round 8
// 812.680 us; speedup vs baseline: 1.2818x; 1.0001x over previous
//
#include <hip/hip_runtime.h>
#include <stdint.h>

#define DIMM 1024
#define NSEQ 1024
#define BB 2
#define HEADSN 16
#define MLPD 4096
#define DEPTHN 4
#define MROWS (BB*NSEQ)  // 2048
#define VSTR 10240       // canonical per-layer vec stride (elements)

typedef __bf16 bf16x8 __attribute__((ext_vector_type(8)));
typedef float f32x4 __attribute__((ext_vector_type(4)));
typedef unsigned short u16x8 __attribute__((ext_vector_type(8)));

__device__ __forceinline__ float bf2f(unsigned short u) {
    union { uint32_t i; float f; } x; x.i = ((uint32_t)u) << 16; return x.f;
}
__device__ __forceinline__ unsigned short f2bf(float f) {
    union { uint32_t i; float f; } x; x.f = f;
    uint32_t r = x.i + 0x7fffu + ((x.i >> 16) & 1u);
    return (unsigned short)(r >> 16);
}
__device__ __forceinline__ float loadf(const void* p, size_t i, int f32) {
    return f32 ? ((const float*)p)[i] : bf2f(((const unsigned short*)p)[i]);
}
// packed f32x2 -> bf16x2 (RNE), single HW instruction on gfx950
__device__ __forceinline__ uint32_t cvt_pk_bf16(float lo, float hi) {
    uint32_t r;
    asm("v_cvt_pk_bf16_f32 %0, %1, %2" : "=v"(r) : "v"(lo), "v"(hi));
    return r;
}

// async global->LDS, 16B per lane; LDS dest = wave-uniform base + lane*16
__device__ __forceinline__ void gl_lds16(const unsigned short* g, unsigned short* l) {
    __builtin_amdgcn_global_load_lds(
        (const __attribute__((address_space(1))) uint32_t*)g,
        (__attribute__((address_space(3))) uint32_t*)l,
        16, 0, 0);
}

// counted vmcnt waits (keep next-tile loads in flight across barriers)
__device__ __forceinline__ void wait_vm4() { asm volatile("s_waitcnt vmcnt(4)" ::: "memory"); }
__device__ __forceinline__ void wait_vm0() { asm volatile("s_waitcnt vmcnt(0)" ::: "memory"); }
// raw barrier fenced so the compiler can't move LDS ops across it
__device__ __forceinline__ void barrier_sync() {
    asm volatile("" ::: "memory");
    __builtin_amdgcn_s_barrier();
    asm volatile("" ::: "memory");
}

// ---------------- dtype sniff ----------------
__global__ __launch_bounds__(256) void sniff_kernel(const unsigned short* __restrict__ x,
                                                    int* __restrict__ flag) {
    __shared__ int cnt[256];
    int tid = threadIdx.x;
    int c = 0;
    for (int i = tid * 2; i < 65536; i += 512) {
        int e = (x[i] >> 7) & 0xFF;
        if (e >= 0x8A) c++;
    }
    cnt[tid] = c;
    __syncthreads();
    for (int s = 128; s > 0; s >>= 1) {
        if (tid < s) cnt[tid] += cnt[tid + s];
        __syncthreads();
    }
    if (tid == 0) flag[0] = (cnt[0] > 32) ? 1 : 0;
}

// ---------------- converts ----------------
__global__ __launch_bounds__(256) void store_out(const float* __restrict__ xf, void* __restrict__ out,
                                                 const int* __restrict__ flag) {
    int f = flag[0];
    int i = blockIdx.x * 256 + threadIdx.x;
    float v = xf[i];
    if (f) ((float*)out)[i] = v;
    else   ((unsigned short*)out)[i] = f2bf(v);
}
// all 7 small vectors in one launch; grid (64, 7)
__global__ __launch_bounds__(256) void conv_all(const void* s0, const void* s1, const void* s2,
                                                const void* s3, const void* s4, const void* s5,
                                                const void* s6, unsigned short* __restrict__ dst,
                                                const int* __restrict__ flag) {
    int f = flag[0];
    const void* src; int len, off;
    switch (blockIdx.y) {
        case 0: src = s0; len = 1024; off = 0;    break;
        case 1: src = s1; len = 1024; off = 1024; break;
        case 2: src = s2; len = 1024; off = 2048; break;
        case 3: src = s3; len = 1024; off = 3072; break;
        case 4: src = s4; len = 1024; off = 4096; break;
        case 5: src = s5; len = 1024; off = 5120; break;
        default: src = s6; len = 4096; off = 6144; break;
    }
    int i = blockIdx.x * 256 + threadIdx.x;
    if (i < DEPTHN * len) {
        int l = i / len, o = i - l * len;
        dst[l * VSTR + off + o] = f2bf(loadf(src, i, f));
    }
}

// ---------------- transpose+convert (scalar fallback) ----------------
__global__ __launch_bounds__(256) void transpose_conv(const void* __restrict__ in, size_t srcOffE,
                                                      unsigned short* __restrict__ out,
                                                      int K, int N, const int* __restrict__ flag) {
    int f = flag[0];
    __shared__ unsigned short t[32][33];
    int n0 = blockIdx.x * 32, k0 = blockIdx.y * 32;
    int tx = threadIdx.x, ty = threadIdx.y;  // 32 x 8
#pragma unroll
    for (int i = 0; i < 4; i++) {
        int k = k0 + ty + i * 8;
        t[ty + i * 8][tx] = f2bf(loadf(in, srcOffE + (size_t)k * N + n0 + tx, f));
    }
    __syncthreads();
#pragma unroll
    for (int i = 0; i < 4; i++) {
        int n = n0 + ty + i * 8;
        out[(size_t)n * K + k0 + tx] = t[tx][ty + i * 8];
    }
}

// ---------------- batched attn-half transpose (scalar fallback path) ----------------
__global__ __launch_bounds__(256) void transpose_attn(const void* __restrict__ qkvw,
                                                      const void* __restrict__ outw,
                                                      int layer, unsigned short* __restrict__ wT,
                                                      const int* __restrict__ flag) {
    int f = flag[0];
    __shared__ unsigned short t[32][33];
    int id = blockIdx.x;
    const void* src; int N; size_t soff; unsigned short* dst; int bx, by;
    if (id < 3072) {
        N = 3072; bx = id % 96; by = id / 96;
        src = qkvw; soff = (size_t)layer * 1024 * 3072; dst = wT;
    } else {
        id -= 3072; N = 1024; bx = id % 32; by = id / 32;
        src = outw; soff = (size_t)layer * 1024 * 1024; dst = wT + 3 * 1024 * 1024;
    }
    int n0 = bx * 32, k0 = by * 32;
    int tx = threadIdx.x, ty = threadIdx.y;  // 32 x 8
#pragma unroll
    for (int i = 0; i < 4; i++) {
        int k = k0 + ty + i * 8;
        t[ty + i * 8][tx] = f2bf(loadf(src, soff + (size_t)k * N + n0 + tx, f));
    }
    __syncthreads();
#pragma unroll
    for (int i = 0; i < 4; i++) {
        int n = n0 + ty + i * 8;
        dst[(size_t)n * 1024 + k0 + tx] = t[tx][ty + i * 8];
    }
}

// ---------------- V^T from V-part of qkv (fallback path only) ----------------
__global__ __launch_bounds__(256) void vt_kernel(const unsigned short* __restrict__ qkv,
                                                 unsigned short* __restrict__ vt) {
    __shared__ unsigned short t[64 * 70];
    int b = blockIdx.z;
    int c0 = blockIdx.x * 64, k0 = blockIdx.y * 64;
    int tid = threadIdx.x;
    int tx = tid & 15, ty = tid >> 4;  // 16 x 16
#pragma unroll
    for (int i = 0; i < 4; i++) {
        int r = ty + i * 16;
        uint2 v = *(const uint2*)&qkv[(size_t)(b * 1024 + k0 + r) * 3072 + 2048 + c0 + tx * 4];
        *(uint32_t*)&t[r * 70 + tx * 4]     = v.x;
        *(uint32_t*)&t[r * 70 + tx * 4 + 2] = v.y;
    }
    __syncthreads();
#pragma unroll
    for (int i = 0; i < 4; i++) {
        int c = ty + i * 16;
        ushort4 o;
        o.x = t[(tx * 4 + 0) * 70 + c];
        o.y = t[(tx * 4 + 1) * 70 + c];
        o.z = t[(tx * 4 + 2) * 70 + c];
        o.w = t[(tx * 4 + 3) * 70 + c];
        *(ushort4*)&vt[(size_t)(b * 1024 + c0 + c) * 1024 + k0 + tx * 4] = o;
    }
}

// ---------------- ALL weight transposes, vectorized 64x64 tiles, u16x8 stores ----------------
// grid (3072, 4).  Per-layer block ids: [0,768) qkv, [768,1024) out, [1024,2048) ff1,
// [2048,3072) ff2.  Per-layer arena stride 12M elements.
// Phase 1: float4 loads (256 B/row coalesced) + cvt_pk -> u32 LDS writes, [64][70] stride.
// Phase 2: 8x32 threads; 16 u16 gathers -> two 16 B stores per thread (128 B/row segments).
__global__ __launch_bounds__(256) void transpose_all(const void* __restrict__ qkvw,
                                                     const void* __restrict__ outw,
                                                     const void* __restrict__ ff1w,
                                                     const void* __restrict__ ff2w,
                                                     unsigned short* __restrict__ wTall,
                                                     const int* __restrict__ flag) {
    int f = flag[0];
    __shared__ unsigned short t[64 * 70];
    int id = blockIdx.x;
    int l = blockIdx.y;
    unsigned short* base = wTall + (size_t)l * (12u * 1024 * 1024);
    const void* src; int K, N; size_t soff; unsigned short* dst;
    if (id < 768)       { src = qkvw; K = 1024; N = 3072; soff = (size_t)l * 1024 * 3072; dst = base; }
    else if (id < 1024) { id -= 768;  src = outw; K = 1024; N = 1024; soff = (size_t)l * 1024 * 1024; dst = base + 3 * 1024 * 1024; }
    else if (id < 2048) { id -= 1024; src = ff1w; K = 1024; N = 4096; soff = (size_t)l * 1024 * 4096; dst = base + 4 * 1024 * 1024; }
    else                { id -= 2048; src = ff2w; K = 4096; N = 1024; soff = (size_t)l * 4096 * 1024; dst = base + 8 * 1024 * 1024; }
    int nb = N >> 6;
    int by = id / nb, bx = id - by * nb;
    int n0 = bx * 64, k0 = by * 64;
    int tid = threadIdx.x;
    int tx = tid & 15, ty = tid >> 4;  // 16 x 16
#pragma unroll
    for (int i = 0; i < 4; i++) {
        int r = ty + i * 16;
        size_t s = soff + (size_t)(k0 + r) * N + n0 + tx * 4;
        uint32_t w0, w1;
        if (f) {
            float4 v = *(const float4*)((const float*)src + s);
            w0 = cvt_pk_bf16(v.x, v.y);
            w1 = cvt_pk_bf16(v.z, v.w);
        } else {
            uint2 v = *(const uint2*)((const unsigned short*)src + s);
            w0 = v.x; w1 = v.y;
        }
        *(uint32_t*)&t[r * 70 + tx * 4]     = w0;
        *(uint32_t*)&t[r * 70 + tx * 4 + 2] = w1;
    }
    __syncthreads();
    int tx2 = tid & 7, ty2 = tid >> 3;  // 8 x 32
#pragma unroll
    for (int i = 0; i < 2; i++) {
        int n = ty2 + i * 32;
        u16x8 o;
#pragma unroll
        for (int j = 0; j < 8; j++) o[j] = t[(tx2 * 8 + j) * 70 + n];
        *(u16x8*)&dst[(size_t)(n0 + n) * K + k0 + tx2 * 8] = o;
    }
}

// ---------------- mask -> bitmask u64 words ----------------
__global__ __launch_bounds__(256) void mask_pack(const int* __restrict__ mask,
                                                 unsigned long long* __restrict__ bits) {
    int wid = (blockIdx.x * 256 + threadIdx.x) >> 6;
    int lane = threadIdx.x & 63;
#pragma unroll
    for (int i = 0; i < 16; i++) {
        int w = wid * 16 + i;
        int mv = mask[(size_t)w * 64 + lane];
        unsigned long long bl = __ballot(mv != 0);
        if (lane == 0) bits[w] = bl;
    }
}

// ---------------- fused cvt + LayerNorm from raw x (first pre-attn LN) ----------------
__global__ __launch_bounds__(256) void ln_raw(const void* __restrict__ x, float* __restrict__ xf,
                                              const unsigned short* __restrict__ g,
                                              const unsigned short* __restrict__ bta,
                                              unsigned short* __restrict__ out,
                                              const int* __restrict__ flag) {
    int f = flag[0];
    int row = blockIdx.x, tid = threadIdx.x;
    size_t base = (size_t)row * DIMM;
    float v[4]; float s = 0.f, s2 = 0.f;
#pragma unroll
    for (int i = 0; i < 4; i++) {
        int c = tid + i * 256;
        v[i] = loadf(x, base + c, f);
        xf[base + c] = v[i];
        s += v[i]; s2 += v[i] * v[i];
    }
#pragma unroll
    for (int off = 32; off >= 1; off >>= 1) {
        s  += __shfl_down(s, off, 64);
        s2 += __shfl_down(s2, off, 64);
    }
    __shared__ float rs[4], rs2[4];
    int wv = tid >> 6;
    if ((tid & 63) == 0) { rs[wv] = s; rs2[wv] = s2; }
    __syncthreads();
    s  = rs[0] + rs[1] + rs[2] + rs[3];
    s2 = rs2[0] + rs2[1] + rs2[2] + rs2[3];
    float mu  = s * (1.f / DIMM);
    float var = s2 * (1.f / DIMM) - mu * mu;
    float rr  = rsqrtf(var + 1e-5f);
#pragma unroll
    for (int i = 0; i < 4; i++) {
        int c = tid + i * 256;
        float y = (v[i] - mu) * rr * bf2f(g[c]) + bf2f(bta[c]);
        out[base + c] = f2bf(y);
    }
}

// ---------------- LayerNorm (standalone fallback) ----------------
__global__ __launch_bounds__(256) void ln_kernel(const float* __restrict__ x,
                                                 const unsigned short* __restrict__ g,
                                                 const unsigned short* __restrict__ bta,
                                                 unsigned short* __restrict__ out) {
    int row = blockIdx.x, tid = threadIdx.x;
    const float* xr = x + (size_t)row * DIMM;
    float v[4]; float s = 0.f, s2 = 0.f;
#pragma unroll
    for (int i = 0; i < 4; i++) { v[i] = xr[tid + i * 256]; s += v[i]; s2 += v[i] * v[i]; }
#pragma unroll
    for (int off = 32; off >= 1; off >>= 1) {
        s  += __shfl_down(s, off, 64);
        s2 += __shfl_down(s2, off, 64);
    }
    __shared__ float rs[4], rs2[4];
    int wv = tid >> 6;
    if ((tid & 63) == 0) { rs[wv] = s; rs2[wv] = s2; }
    __syncthreads();
    s  = rs[0] + rs[1] + rs[2] + rs[3];
    s2 = rs2[0] + rs2[1] + rs2[2] + rs2[3];
    float mu  = s * (1.f / DIMM);
    float var = s2 * (1.f / DIMM) - mu * mu;
    float rr  = rsqrtf(var + 1e-5f);
#pragma unroll
    for (int i = 0; i < 4; i++) {
        int c = tid + i * 256;
        float y = (v[i] - mu) * rr * bf2f(g[c]) + bf2f(bta[c]);
        out[(size_t)row * DIMM + c] = f2bf(y);
    }
}

// ---------------- split-K slab reduce + residual update (+ optional fused LN) ----------------
template <int S, int HAS_LN>
__global__ __launch_bounds__(256) void reduce_ln(const float* __restrict__ slab,
                                                 const unsigned short* __restrict__ bias,
                                                 float* __restrict__ xf,
                                                 const unsigned short* __restrict__ g,
                                                 const unsigned short* __restrict__ bta,
                                                 unsigned short* __restrict__ out) {
    const size_t SL = (size_t)MROWS * DIMM;
    int row = blockIdx.x, tid = threadIdx.x;
    float v[4]; float s = 0.f, s2 = 0.f;
#pragma unroll
    for (int i = 0; i < 4; i++) {
        int c = tid + i * 256;
        size_t idx = (size_t)row * DIMM + c;
        float t = xf[idx] + bf2f(bias[c]);
#pragma unroll
        for (int z = 0; z < S; z++) t += slab[z * SL + idx];
        xf[idx] = t;
        v[i] = t; s += t; s2 += t * t;
    }
    if (HAS_LN) {
#pragma unroll
        for (int off = 32; off >= 1; off >>= 1) {
            s  += __shfl_down(s, off, 64);
            s2 += __shfl_down(s2, off, 64);
        }
        __shared__ float rs[4], rs2[4];
        int wv = tid >> 6;
        if ((tid & 63) == 0) { rs[wv] = s; rs2[wv] = s2; }
        __syncthreads();
        s  = rs[0] + rs[1] + rs[2] + rs[3];
        s2 = rs2[0] + rs2[1] + rs2[2] + rs2[3];
        float mu  = s * (1.f / DIMM);
        float var = s2 * (1.f / DIMM) - mu * mu;
        float rr  = rsqrtf(var + 1e-5f);
#pragma unroll
        for (int i = 0; i < 4; i++) {
            int c = tid + i * 256;
            float y = (v[i] - mu) * rr * bf2f(g[c]) + bf2f(bta[c]);
            out[(size_t)row * DIMM + c] = f2bf(y);
        }
    }
}

// ---------------- GEMM (8-wave 128x128 tile, BK=64, dbuf + counted vmcnt) ----------------
// K-loop unchanged from R3 BK=64 version.  NEW: for MODE 0 with VtOut != nullptr and
// nBase >= 2048 (the V third of the qkv GEMM), the epilogue writes V^T directly:
// acc -> LDS tile T[128n][136m] (u16, stride-136 -> 2-way bank = free; row stride 272 B
// = 16-aligned), barrier, coalesced u16x8 row reads -> 256 B-contiguous vt stores.
// Replaces the separate vt_kernel pass (bit-identical values).  LDS is one flat array
// so T can overlay the staging buffers after the loop's final barrier.
template <int MODE, int SPLITK>
__global__ __launch_bounds__(512) void gemm_bt(const unsigned short* __restrict__ A,
                                               const unsigned short* __restrict__ Bt,
                                               const unsigned short* __restrict__ bias,
                                               unsigned short* __restrict__ Cbf,
                                               float* __restrict__ Cres,
                                               unsigned short* __restrict__ VtOut,
                                               int M, int N, int K) {
    __shared__ __align__(16) unsigned short LDSbuf[4 * 128 * 64];
    unsigned short* As0 = LDSbuf;
    unsigned short* Bs0 = LDSbuf + 8192;
    unsigned short* As1 = LDSbuf + 16384;
    unsigned short* Bs1 = LDSbuf + 24576;
    const int tid = threadIdx.x;
    const int mBase = blockIdx.y * 128, nBase = blockIdx.x * 128;
    const int w = tid >> 6, lane = tid & 63;
    const int wm = (w >> 2) * 64, wn = (w & 3) * 32;
    const int quad = lane >> 4, l16 = lane & 15;
    const int kLen = K / SPLITK;
    const int kStart = (SPLITK > 1) ? blockIdx.z * kLen : 0;
    const int NT = kLen / 64;

    f32x4 acc[4][2];
#pragma unroll
    for (int i = 0; i < 4; i++)
#pragma unroll
        for (int j = 0; j < 2; j++) acc[i][j] = (f32x4){0.f, 0.f, 0.f, 0.f};

    const int wb = w & 3;
    const int lr8 = lane >> 3;
    const int sgran = (lane & 7) ^ lr8;
    const unsigned short* G = (w < 4 ? A  + (size_t)(mBase + wb * 32 + lr8) * K
                                     : Bt + (size_t)(nBase + wb * 32 + lr8) * K)
                              + kStart + sgran * 8;
    unsigned short* S0 = (w < 4 ? As0 : Bs0) + (wb * 32) * 64;
    unsigned short* S1 = (w < 4 ? As1 : Bs1) + (wb * 32) * 64;
    const size_t r8 = (size_t)8 * K;

    const int rg0 = (quad ^ (l16 & 7)) * 8;
    const int rg1 = ((4 + quad) ^ (l16 & 7)) * 8;

    auto stage = [&](unsigned short* S, int t) {
        const unsigned short* g = G + (size_t)t * 64;
#pragma unroll
        for (int i = 0; i < 4; i++)
            gl_lds16(g + (size_t)i * r8, S + i * 8 * 64);
    };
    auto compute = [&](const unsigned short* Asb, const unsigned short* Bsb) {
#pragma unroll
        for (int ks = 0; ks < 2; ks++) {
            const int rg = ks ? rg1 : rg0;
            bf16x8 af[4], bfv[2];
#pragma unroll
            for (int i = 0; i < 4; i++)
                af[i] = *(const bf16x8*)&Asb[(wm + i * 16 + l16) * 64 + rg];
#pragma unroll
            for (int j = 0; j < 2; j++)
                bfv[j] = *(const bf16x8*)&Bsb[(wn + j * 16 + l16) * 64 + rg];
#pragma unroll
            for (int i = 0; i < 4; i++)
#pragma unroll
                for (int j = 0; j < 2; j++)
                    acc[i][j] = __builtin_amdgcn_mfma_f32_16x16x32_bf16(af[i], bfv[j], acc[i][j], 0, 0, 0);
        }
    };

    stage(S0, 0);
    for (int t = 0; t < NT; t += 2) {
        stage(S1, t + 1);
        wait_vm4();
        barrier_sync();
        compute(As0, Bs0);
        barrier_sync();
        if (t + 2 < NT) {
            stage(S0, t + 2);
            wait_vm4();
        } else {
            wait_vm0();
        }
        barrier_sync();
        compute(As1, Bs1);
        barrier_sync();
    }

    // fused V^T epilogue (qkv GEMM, V third) — whole block takes this path uniformly
    if (MODE == 0 && VtOut != nullptr && nBase >= 2048) {
        unsigned short* T = LDSbuf;  // 128 x 136 u16 = 34816 B <= 64 KB
#pragma unroll
        for (int i = 0; i < 4; i++)
#pragma unroll
            for (int j = 0; j < 2; j++)
#pragma unroll
                for (int r = 0; r < 4; r++)
                    T[(wn + j * 16 + l16) * 136 + (wm + i * 16 + quad * 4 + r)] =
                        f2bf(acc[i][j][r]);
        barrier_sync();
        const int b = mBase >> 10, kk = mBase & 1023;
        const int tx = tid & 15, ty = tid >> 4;  // 16 x 32
#pragma unroll
        for (int p = 0; p < 4; p++) {
            int c = ty + p * 32;
            u16x8 val = *(const u16x8*)&T[c * 136 + tx * 8];
            *(u16x8*)&VtOut[(size_t)(b * 1024 + (nBase - 2048) + c) * 1024 + kk + tx * 8] = val;
        }
        return;
    }

    const size_t slabOff = (MODE == 3) ? (size_t)blockIdx.z * M * N : 0;
#pragma unroll
    for (int i = 0; i < 4; i++) {
#pragma unroll
        for (int j = 0; j < 2; j++) {
#pragma unroll
            for (int r = 0; r < 4; r++) {
                int m = mBase + wm + i * 16 + quad * 4 + r;
                int n = nBase + wn + j * 16 + l16;
                float v = acc[i][j][r];
                size_t idx = (size_t)m * N + n;
                if (MODE == 0) {
                    Cbf[idx] = f2bf(v);
                } else if (MODE == 1) {
                    if (SPLITK > 1) {
                        if (blockIdx.z == 0) v += bf2f(bias[n]);
                        atomicAdd(&Cres[idx], v);
                    } else {
                        Cres[idx] += v + bf2f(bias[n]);
                    }
                } else if (MODE == 2) {
                    float t2 = v + bf2f(bias[n]);
                    float gg = 0.5f * t2 * (1.f + erff(t2 * 0.70710678118f));
                    Cbf[idx] = f2bf(gg);
                } else {
                    Cres[slabOff + idx] = v;
                }
            }
        }
    }
}

// ---------------- MFMA flash attention (swapped-QK, in-register P, dbuf K/V pipeline) ----------------
__global__ __launch_bounds__(256) void attn_mfma(const unsigned short* __restrict__ qkv,
                                                 const unsigned short* __restrict__ vt,
                                                 const unsigned long long* __restrict__ mbits,
                                                 unsigned short* __restrict__ o) {
    __shared__ __align__(16) unsigned short Ks[2][64 * 72];
    __shared__ __align__(16) unsigned short Vs[2][64 * 72];

    const int tid = threadIdx.x, w = tid >> 6, lane = tid & 63;
    const int quad = lane >> 4, l16 = lane & 15;
    const int qt = blockIdx.x, h = blockIdx.y, b = blockIdx.z;

    const size_t qrow = (size_t)(b * NSEQ + qt * 64 + w * 16 + l16) * 3072 + h * 64;
    bf16x8 qf[2];
    qf[0] = *(const bf16x8*)(qkv + qrow + quad * 8);
    qf[1] = *(const bf16x8*)(qkv + qrow + 32 + quad * 8);

    const int srow = tid >> 2, scol = (tid & 3) * 16;
    const unsigned short* kg0 = qkv + (size_t)(b * NSEQ) * 3072 + 1024 + h * 64
                                + (size_t)srow * 3072 + scol;
    const unsigned short* vg0 = vt + (size_t)((b * HEADSN + h) * 64 + srow) * 1024 + scol;

    f32x4 oacc[4];
#pragma unroll
    for (int j = 0; j < 4; j++) oacc[j] = (f32x4){0.f, 0.f, 0.f, 0.f};
    float m_run = -1e30f, l_run = 0.f;

    const unsigned long long* mb = mbits + ((size_t)(b * NSEQ + qt * 64 + w * 16 + l16)) * 16;

    // prologue: stage kt=0 into buf 0
    uint4 ka = *(const uint4*)kg0;
    uint4 kb = *(const uint4*)(kg0 + 8);
    uint4 va = *(const uint4*)vg0;
    uint4 vb = *(const uint4*)(vg0 + 8);
    *(uint4*)&Ks[0][srow * 72 + scol]     = ka;
    *(uint4*)&Ks[0][srow * 72 + scol + 8] = kb;
    *(uint4*)&Vs[0][srow * 72 + scol]     = va;
    *(uint4*)&Vs[0][srow * 72 + scol + 8] = vb;
    unsigned long long mw = mb[0];
    int cur = 0;

    for (int kt = 0; kt < 16; kt++) {
        __syncthreads();  // buf[cur] writes visible; prior iter's reads of buf[cur^1] done

        unsigned long long mw_n = 0;
        if (kt < 15) {  // issue kt+1 loads now; consumed (LDS-written) after compute
            const unsigned short* kg = kg0 + (size_t)(kt + 1) * 64 * 3072;
            ka = *(const uint4*)kg;
            kb = *(const uint4*)(kg + 8);
            const unsigned short* vg = vg0 + (kt + 1) * 64;
            va = *(const uint4*)vg;
            vb = *(const uint4*)(vg + 8);
            mw_n = mb[kt + 1];
        }

        // S^T: sacc[j][r] = S[q=l16][k = j*16 + quad*4 + r]
        f32x4 sacc[4];
#pragma unroll
        for (int j = 0; j < 4; j++) sacc[j] = (f32x4){0.f, 0.f, 0.f, 0.f};
        __builtin_amdgcn_s_setprio(1);
#pragma unroll
        for (int ks = 0; ks < 2; ks++) {
#pragma unroll
            for (int j = 0; j < 4; j++) {
                bf16x8 kf = *(const bf16x8*)&Ks[cur][(j * 16 + l16) * 72 + ks * 32 + quad * 8];
                sacc[j] = __builtin_amdgcn_mfma_f32_16x16x32_bf16(kf, qf[ks], sacc[j], 0, 0, 0);
            }
        }
        __builtin_amdgcn_s_setprio(0);

        float t[4][4];
        float mxj[4];
#pragma unroll
        for (int j = 0; j < 4; j++) {
            unsigned nib = (unsigned)(mw >> (quad * 4 + j * 16)) & 0xFu;
#pragma unroll
            for (int r = 0; r < 4; r++) {
                float s = sacc[j][r] * 0.125f;
                t[j][r] = ((nib >> r) & 1u) ? s : -1e30f;
            }
            mxj[j] = fmaxf(fmaxf(t[j][0], t[j][1]), fmaxf(t[j][2], t[j][3]));
        }
        float mx = fmaxf(fmaxf(mxj[0], mxj[1]), fmaxf(mxj[2], mxj[3]));
        mx = fmaxf(mx, __shfl_xor(mx, 16, 64));
        mx = fmaxf(mx, __shfl_xor(mx, 32, 64));

        if (!__all(mx <= m_run)) {
            float m_new = fmaxf(m_run, mx);
            float alpha = __expf(m_run - m_new);
            m_run = m_new;
            l_run *= alpha;
            float al[4];
#pragma unroll
            for (int r = 0; r < 4; r++) al[r] = __shfl(alpha, quad * 4 + r, 64);
#pragma unroll
            for (int j = 0; j < 4; j++)
#pragma unroll
                for (int r = 0; r < 4; r++) oacc[j][r] *= al[r];
        }

        float p[4][4];
        float psj[4];
#pragma unroll
        for (int j = 0; j < 4; j++) {
#pragma unroll
            for (int r = 0; r < 4; r++) p[j][r] = __expf(t[j][r] - m_run);
            psj[j] = (p[j][0] + p[j][1]) + (p[j][2] + p[j][3]);
        }
        float ps = (psj[0] + psj[1]) + (psj[2] + psj[3]);
        ps += __shfl_xor(ps, 16, 64);
        ps += __shfl_xor(ps, 32, 64);
        l_run += ps;

        union { uint32_t u[4]; bf16x8 v; } pa[2];
#pragma unroll
        for (int ks = 0; ks < 2; ks++) {
            pa[ks].u[0] = cvt_pk_bf16(p[2 * ks][0],     p[2 * ks][1]);
            pa[ks].u[1] = cvt_pk_bf16(p[2 * ks][2],     p[2 * ks][3]);
            pa[ks].u[2] = cvt_pk_bf16(p[2 * ks + 1][0], p[2 * ks + 1][1]);
            pa[ks].u[3] = cvt_pk_bf16(p[2 * ks + 1][2], p[2 * ks + 1][3]);
        }

        __builtin_amdgcn_s_setprio(1);
#pragma unroll
        for (int ks = 0; ks < 2; ks++) {
#pragma unroll
            for (int j = 0; j < 4; j++) {
                union { ushort4 u[2]; bf16x8 v; } vf;
                const unsigned short* vp = &Vs[cur][(j * 16 + l16) * 72 + ks * 32 + quad * 4];
                vf.u[0] = *(const ushort4*)vp;
                vf.u[1] = *(const ushort4*)(vp + 16);
                oacc[j] = __builtin_amdgcn_mfma_f32_16x16x32_bf16(pa[ks].v, vf.v, oacc[j], 0, 0, 0);
            }
        }
        __builtin_amdgcn_s_setprio(0);

        if (kt < 15) {  // write-late: land kt+1 into the other buffer
            *(uint4*)&Ks[cur ^ 1][srow * 72 + scol]     = ka;
            *(uint4*)&Ks[cur ^ 1][srow * 72 + scol + 8] = kb;
            *(uint4*)&Vs[cur ^ 1][srow * 72 + scol]     = va;
            *(uint4*)&Vs[cur ^ 1][srow * 72 + scol + 8] = vb;
            mw = mw_n;
            cur ^= 1;
        }
    }

    float inv[4];
#pragma unroll
    for (int r = 0; r < 4; r++) {
        float lr = __shfl(l_run, quad * 4 + r, 64);
        inv[r] = 1.f / lr;
    }
#pragma unroll
    for (int j = 0; j < 4; j++) {
#pragma unroll
        for (int r = 0; r < 4; r++) {
            size_t row = (size_t)(b * NSEQ + qt * 64 + w * 16 + quad * 4 + r);
            o[row * 1024 + h * 64 + j * 16 + l16] = f2bf(oacc[j][r] * inv[r]);
        }
    }
}

extern "C" void kernel_launch(void* const* d_in, const int* in_sizes, int n_in,
                              void* d_out, int out_size, void* d_ws, size_t ws_size,
                              hipStream_t stream) {
    const void* x     = d_in[0];
    const int*  mask  = (const int*)d_in[1];
    const void* ln1_g = d_in[2];
    const void* ln1_b = d_in[3];
    const void* qkv_w = d_in[4];
    const void* out_w = d_in[5];
    const void* out_b = d_in[6];
    const void* ln2_g = d_in[7];
    const void* ln2_b = d_in[8];
    const void* ff1_w = d_in[9];
    const void* ff1_b = d_in[10];
    const void* ff2_w = d_in[11];
    const void* ff2_b = d_in[12];

    char* ws = (char*)d_ws;
    float*          xf     = (float*)ws;                            // 8 MB fp32 residual
    unsigned short* h_bf   = (unsigned short*)(ws + (8u  << 20));   // 4 MB LN out
    unsigned short* qkv_bf = (unsigned short*)(ws + (12u << 20));   // 12 MB (attn half)
    unsigned short* ff_bf  = (unsigned short*)(ws + (12u << 20));   // 16 MB (ff half)
    unsigned short* vt_bf  = (unsigned short*)(ws + (24u << 20));   // 4 MB V^T (attn half)
    unsigned short* o_bf   = (unsigned short*)(ws + (28u << 20));   // 4 MB
    unsigned short* wT     = (unsigned short*)(ws + (32u << 20));   // 8 MB transposed weight (fallback)
    unsigned short* vecs   = (unsigned short*)(ws + (40u << 20));   // 80 KB canonical vecs
    int*            flag   = (int*)(ws + (40u << 20) + (128u << 10));
    unsigned long long* mbits = (unsigned long long*)(ws + (40u << 20) + (192u << 10)); // 256 KB
    float*          slab   = (float*)(ws + (41u << 20));            // up to 32 MB split-K slabs
    unsigned short* wTall  = (unsigned short*)(ws + (73ull << 20)); // 96 MB all-layer weights

    const bool slabs_ok = ws_size >= (74ull << 20);
    const bool bigws    = ws_size >= (170ull << 20);

    sniff_kernel<<<1, 256, 0, stream>>>((const unsigned short*)x, flag);

    conv_all<<<dim3(64, 7), 256, 0, stream>>>(ln1_g, ln1_b, out_b, ln2_g, ln2_b, ff2_b, ff1_b,
                                              vecs, flag);
    mask_pack<<<512, 256, 0, stream>>>(mask, mbits);

    // fused cvt_x + first pre-attn LN (layer 0)
    ln_raw<<<MROWS, 256, 0, stream>>>(x, xf, vecs + 0, vecs + 1024, h_bf, flag);

    if (bigws)  // all 16 weight transposes in one vectorized launch
        transpose_all<<<dim3(3072, 4), 256, 0, stream>>>(
            qkv_w, out_w, ff1_w, ff2_w, wTall, flag);

    const int nx = MROWS * DIMM;  // 2M

    for (int l = 0; l < DEPTHN; l++) {
        const unsigned short* lv = vecs + l * VSTR;
        const unsigned short* lvn = vecs + (l + 1) * VSTR;  // next layer's vecs (l<3)

        const unsigned short* lbase = bigws ? wTall + (size_t)l * (12u * 1024 * 1024) : wT;
        const unsigned short* qkvT = lbase;
        const unsigned short* outT = lbase + 3 * 1024 * 1024;
        const unsigned short* ff1T = bigws ? lbase + 4 * 1024 * 1024 : wT;
        const unsigned short* ff2T = bigws ? lbase + 8 * 1024 * 1024 : wT;

        // --- attention half ---
        if (!bigws)
            transpose_attn<<<4096, dim3(32, 8), 0, stream>>>(qkv_w, out_w, l, wT, flag);
        // qkv GEMM with fused V^T epilogue (V-blocks write vt_bf directly)
        gemm_bt<0, 1><<<dim3(3072 / 128, MROWS / 128), 512, 0, stream>>>(
            h_bf, qkvT, nullptr, qkv_bf, nullptr, vt_bf, MROWS, 3072, 1024);
        attn_mfma<<<dim3(NSEQ / 64, HEADSN, BB), 256, 0, stream>>>(qkv_bf, vt_bf, mbits, o_bf);
        if (slabs_ok) {
            gemm_bt<3, 2><<<dim3(1024 / 128, MROWS / 128, 2), 512, 0, stream>>>(
                o_bf, outT, nullptr, nullptr, slab, nullptr, MROWS, 1024, 1024);
            reduce_ln<2, 1><<<MROWS, 256, 0, stream>>>(
                slab, lv + 2048, xf, lv + 3072, lv + 4096, h_bf);
        } else {
            gemm_bt<1, 2><<<dim3(1024 / 128, MROWS / 128, 2), 512, 0, stream>>>(
                o_bf, outT, lv + 2048, nullptr, xf, nullptr, MROWS, 1024, 1024);
            ln_kernel<<<MROWS, 256, 0, stream>>>(xf, lv + 3072, lv + 4096, h_bf);
        }

        // --- feedforward half ---
        if (!bigws)
            transpose_conv<<<dim3(4096 / 32, 1024 / 32), dim3(32, 8), 0, stream>>>(
                ff1_w, (size_t)l * 1024 * 4096, wT, 1024, 4096, flag);
        gemm_bt<2, 1><<<dim3(4096 / 128, MROWS / 128), 512, 0, stream>>>(
            h_bf, ff1T, lv + 6144, ff_bf, nullptr, nullptr, MROWS, 4096, 1024);
        if (!bigws)
            transpose_conv<<<dim3(1024 / 32, 4096 / 32), dim3(32, 8), 0, stream>>>(
                ff2_w, (size_t)l * 4096 * 1024, wT, 4096, 1024, flag);
        if (slabs_ok) {
            gemm_bt<3, 4><<<dim3(1024 / 128, MROWS / 128, 4), 512, 0, stream>>>(
                ff_bf, ff2T, nullptr, nullptr, slab, nullptr, MROWS, 1024, 4096);
            if (l < DEPTHN - 1)
                reduce_ln<4, 1><<<MROWS, 256, 0, stream>>>(
                    slab, lv + 5120, xf, lvn + 0, lvn + 1024, h_bf);
            else
                reduce_ln<4, 0><<<MROWS, 256, 0, stream>>>(
                    slab, lv + 5120, xf, nullptr, nullptr, nullptr);
        } else {
            gemm_bt<1, 4><<<dim3(1024 / 128, MROWS / 128, 4), 512, 0, stream>>>(
                ff_bf, ff2T, lv + 5120, nullptr, xf, nullptr, MROWS, 1024, 4096);
            if (l < DEPTHN - 1)
                ln_kernel<<<MROWS, 256, 0, stream>>>(xf, lvn + 0, lvn + 1024, h_bf);
        }
    }

    store_out<<<nx / 256, 256, 0, stream>>>(xf, d_out, flag);
}